// Round 1
// baseline (22268.680 us; speedup 1.0000x reference)
//
#include <hip/hip_runtime.h>
#include <math.h>

#define BATCH 64
#define CIN 3
#define IMH 512
#define IMW 512
#define PSZ 16
#define DIM 256
#define GHN 32
#define GWN 32
#define NPAT 1024
#define NTOK 1025
#define HID 1024
#define NLAYER 6
#define NCLS 1000
#define LN_EPS 1e-5f

// workspace offsets (in floats)
#define T_OFF   0ULL
#define H_OFF   16793600ULL
#define HC_OFF  33587200ULL
#define HS_OFF  50380800ULL
#define C1_OFF  67174400ULL
#define S1_OFF  68225028ULL
#define C2_OFF  69275656ULL
#define S2_OFF  69341192ULL
#define WT_OFF  69406728ULL
// total: 69,603,336 floats = 278.4 MB

// ---------------------------------------------------------------------------
// DFT matrix generation: C1/S1 (1025x1025), C2/S2 (256x256). All symmetric.
__global__ __launch_bounds__(256) void gen_dft(float* __restrict__ C1, float* __restrict__ S1,
                                               float* __restrict__ C2, float* __restrict__ S2) {
    int idx = blockIdx.x * 256 + threadIdx.x;
    if (idx < NTOK * NTOK) {
        int k = idx / NTOK, n = idx - k * NTOK;
        int r = (k * n) % NTOK;  // max k*n = 1024*1024 fits int
        float ang = (float)(6.283185307179586 * (double)r / (double)NTOK);
        C1[idx] = cosf(ang);
        S1[idx] = sinf(ang);
    }
    if (idx < 256 * 256) {
        int k = idx >> 8, n = idx & 255;
        int r = (k * n) & 255;
        float ang = (float)(6.283185307179586 * (double)r / 256.0);
        C2[idx] = cosf(ang);
        S2[idx] = sinf(ang);
    }
}

// ---------------------------------------------------------------------------
// transpose conv_w (256 x 768) -> Wt (768 x 256) for coalesced patch-embed reads
__global__ __launch_bounds__(256) void transpose_w(const float* __restrict__ w, float* __restrict__ wt) {
    int idx = blockIdx.x * 256 + threadIdx.x;
    if (idx < DIM * 768) {
        int d = idx / 768, k = idx - d * 768;
        wt[k * DIM + d] = w[idx];
    }
}

// ---------------------------------------------------------------------------
// t[b,0,:] = cls + pos[0,:]
__global__ __launch_bounds__(256) void cls_init(const float* __restrict__ cls, const float* __restrict__ pos,
                                                float* __restrict__ t) {
    int b = blockIdx.x, tid = threadIdx.x;
    t[(size_t)b * NTOK * DIM + tid] = cls[tid] + pos[tid];
}

// ---------------------------------------------------------------------------
// patch embed: block handles 8 patches (same b, gh; gw0 = blockIdx.x*8)
// t[b, 1+gh*32+gw, d] = sum_k patch[k]*Wt[k][d] + conv_b[d] + pos[tok][d]
__global__ __launch_bounds__(256) void patch_embed(const float* __restrict__ x, const float* __restrict__ wt,
                                                   const float* __restrict__ cb, const float* __restrict__ pos,
                                                   float* __restrict__ t) {
    __shared__ __align__(16) float lds[8 * 768];
    int b = blockIdx.z, gh = blockIdx.y, g4 = blockIdx.x;
    int tid = threadIdx.x;
    const float* xb = x + (size_t)b * CIN * IMH * IMW;
#pragma unroll
    for (int i = 0; i < 24; i++) {
        int e = tid + i * 256;                 // 6144 pixels = 8 patches * 768
        int c = e >> 11, rem = e & 2047, p = rem >> 7, q128 = rem & 127;
        float val = xb[(c * IMH + gh * PSZ + p) * IMW + g4 * 128 + q128];
        lds[(q128 >> 4) * 768 + c * 256 + p * PSZ + (q128 & 15)] = val;
    }
    __syncthreads();
    int grp = tid >> 6;            // wave id: handles patches 2*grp, 2*grp+1
    int dl = (tid & 63) << 2;      // 4 consecutive d per lane
    float4 a0 = {0.f, 0.f, 0.f, 0.f}, a1 = {0.f, 0.f, 0.f, 0.f};
    const float* l0 = &lds[(2 * grp) * 768];
    const float* l1 = &lds[(2 * grp + 1) * 768];
    for (int k = 0; k < 768; k++) {
        float4 w4 = *(const float4*)&wt[k * DIM + dl];
        float h0 = l0[k], h1 = l1[k];
        a0.x += h0 * w4.x; a0.y += h0 * w4.y; a0.z += h0 * w4.z; a0.w += h0 * w4.w;
        a1.x += h1 * w4.x; a1.y += h1 * w4.y; a1.z += h1 * w4.z; a1.w += h1 * w4.w;
    }
    float4 cb4 = *(const float4*)&cb[dl];
    int tokbase = 1 + gh * GWN + g4 * 8 + 2 * grp;
    float4 p0 = *(const float4*)&pos[(size_t)tokbase * DIM + dl];
    float4 p1 = *(const float4*)&pos[(size_t)(tokbase + 1) * DIM + dl];
    float4 o0 = {a0.x + cb4.x + p0.x, a0.y + cb4.y + p0.y, a0.z + cb4.z + p0.z, a0.w + cb4.w + p0.w};
    float4 o1 = {a1.x + cb4.x + p1.x, a1.y + cb4.y + p1.y, a1.z + cb4.z + p1.z, a1.w + cb4.w + p1.w};
    *(float4*)&t[((size_t)b * NTOK + tokbase) * DIM + dl] = o0;
    *(float4*)&t[((size_t)b * NTOK + tokbase + 1) * DIM + dl] = o1;
}

// ---------------------------------------------------------------------------
// LayerNorm over DIM=256: one token per wave, 4 tokens per block (two-pass).
__global__ __launch_bounds__(256) void ln_kernel(const float* __restrict__ t, float* __restrict__ h,
                                                 const float* __restrict__ s, const float* __restrict__ bb) {
    int wave = threadIdx.x >> 6, lane = threadIdx.x & 63;
    int m = blockIdx.x * 4 + wave;     // < 65600 exactly
    const float* row = t + (size_t)m * DIM;
    float4 v = *(const float4*)(row + lane * 4);
    float sum = v.x + v.y + v.z + v.w;
#pragma unroll
    for (int off = 32; off; off >>= 1) sum += __shfl_xor(sum, off);
    float mean = sum * (1.f / 256.f);
    float dx = v.x - mean, dy = v.y - mean, dz = v.z - mean, dw = v.w - mean;
    float sq = dx * dx + dy * dy + dz * dz + dw * dw;
#pragma unroll
    for (int off = 32; off; off >>= 1) sq += __shfl_xor(sq, off);
    float rstd = rsqrtf(sq * (1.f / 256.f) + LN_EPS);
    float4 s4 = *(const float4*)(s + lane * 4);
    float4 b4 = *(const float4*)(bb + lane * 4);
    float4 o = {dx * rstd * s4.x + b4.x, dy * rstd * s4.y + b4.y,
                dz * rstd * s4.z + b4.z, dw * rstd * s4.w + b4.w};
    *(float4*)(h + (size_t)m * DIM + lane * 4) = o;
}

// ---------------------------------------------------------------------------
// Hc = h @ C2 ; Hs = h @ S2   (M=65600 flat, K=256, N=256). 64x64 tiles.
__global__ __launch_bounds__(256) void fft_small(const float* __restrict__ h, const float* __restrict__ C2,
                                                 const float* __restrict__ S2, float* __restrict__ Hc,
                                                 float* __restrict__ Hs) {
    __shared__ __align__(16) float As[32][68];
    __shared__ __align__(16) float Bc[32 * 64];
    __shared__ __align__(16) float Bs[32 * 64];
    int m0 = blockIdx.x * 64, n0 = blockIdx.y * 64;
    int tid = threadIdx.x, ty = tid >> 4, tx = tid & 15;
    float accC[4][4] = {}, accS[4][4] = {};
    for (int k0 = 0; k0 < 256; k0 += 32) {
#pragma unroll
        for (int i = 0; i < 8; i++) {
            int e = tid + i * 256;
            int row = e >> 5, kk = e & 31;
            As[kk][row] = h[(size_t)(m0 + row) * DIM + k0 + kk];
        }
#pragma unroll
        for (int i = 0; i < 8; i++) {
            int e = tid + i * 256;
            int kk = e >> 6, col = e & 63;
            Bc[kk * 64 + col] = C2[(k0 + kk) * DIM + n0 + col];
            Bs[kk * 64 + col] = S2[(k0 + kk) * DIM + n0 + col];
        }
        __syncthreads();
        for (int kk = 0; kk < 32; kk++) {
            float4 a4 = *(const float4*)&As[kk][ty * 4];
            float4 c4 = *(const float4*)&Bc[kk * 64 + tx * 4];
            float4 s4 = *(const float4*)&Bs[kk * 64 + tx * 4];
            float ai[4] = {a4.x, a4.y, a4.z, a4.w};
            float cj[4] = {c4.x, c4.y, c4.z, c4.w};
            float sj[4] = {s4.x, s4.y, s4.z, s4.w};
#pragma unroll
            for (int i = 0; i < 4; i++)
#pragma unroll
                for (int j = 0; j < 4; j++) {
                    accC[i][j] += ai[i] * cj[j];
                    accS[i][j] += ai[i] * sj[j];
                }
        }
        __syncthreads();
    }
#pragma unroll
    for (int i = 0; i < 4; i++) {
        int m = m0 + ty * 4 + i;
        float4 vc = {accC[i][0], accC[i][1], accC[i][2], accC[i][3]};
        float4 vs = {accS[i][0], accS[i][1], accS[i][2], accS[i][3]};
        *(float4*)&Hc[(size_t)m * DIM + n0 + tx * 4] = vc;
        *(float4*)&Hs[(size_t)m * DIM + n0 + tx * 4] = vs;
    }
}

// ---------------------------------------------------------------------------
// t[b] += C1 @ Hc[b] - S1 @ Hs[b]   (M=1025, K=1025, N=256), 64x64 tiles.
__global__ __launch_bounds__(256) void fft_big(const float* __restrict__ C1m, const float* __restrict__ S1m,
                                               const float* __restrict__ Hc, const float* __restrict__ Hs,
                                               float* __restrict__ t) {
    __shared__ __align__(16) float Ac[32][68];
    __shared__ __align__(16) float An[32][68];
    __shared__ __align__(16) float Bc[32 * 64];
    __shared__ __align__(16) float Bs[32 * 64];
    int m0 = blockIdx.x * 64, n0 = blockIdx.y * 64, b = blockIdx.z;
    const float* HcB = Hc + (size_t)b * NTOK * DIM;
    const float* HsB = Hs + (size_t)b * NTOK * DIM;
    int tid = threadIdx.x, ty = tid >> 4, tx = tid & 15;
    float acc[4][4] = {};
    for (int k0 = 0; k0 < NTOK; k0 += 32) {
#pragma unroll
        for (int i = 0; i < 8; i++) {
            int e = tid + i * 256;
            int row = e >> 5, kk = e & 31;
            int m = m0 + row, k = k0 + kk;
            float vc = 0.f, vs = 0.f;
            if (m < NTOK && k < NTOK) {
                size_t idx = (size_t)m * NTOK + k;
                vc = C1m[idx];
                vs = S1m[idx];
            }
            Ac[kk][row] = vc;
            An[kk][row] = vs;
        }
#pragma unroll
        for (int i = 0; i < 8; i++) {
            int e = tid + i * 256;
            int kk = e >> 6, col = e & 63;
            int k = k0 + kk;
            float vc = 0.f, vs = 0.f;
            if (k < NTOK) {
                size_t idx = (size_t)k * DIM + n0 + col;
                vc = HcB[idx];
                vs = HsB[idx];
            }
            Bc[kk * 64 + col] = vc;
            Bs[kk * 64 + col] = vs;
        }
        __syncthreads();
        for (int kk = 0; kk < 32; kk++) {
            float4 a4 = *(const float4*)&Ac[kk][ty * 4];
            float4 n4 = *(const float4*)&An[kk][ty * 4];
            float4 c4 = *(const float4*)&Bc[kk * 64 + tx * 4];
            float4 s4 = *(const float4*)&Bs[kk * 64 + tx * 4];
            float ai[4] = {a4.x, a4.y, a4.z, a4.w};
            float ni[4] = {n4.x, n4.y, n4.z, n4.w};
            float cj[4] = {c4.x, c4.y, c4.z, c4.w};
            float sj[4] = {s4.x, s4.y, s4.z, s4.w};
#pragma unroll
            for (int i = 0; i < 4; i++)
#pragma unroll
                for (int j = 0; j < 4; j++) {
                    acc[i][j] += ai[i] * cj[j];
                    acc[i][j] -= ni[i] * sj[j];
                }
        }
        __syncthreads();
    }
#pragma unroll
    for (int i = 0; i < 4; i++) {
        int m = m0 + ty * 4 + i;
        if (m < NTOK) {
            float* dst = t + ((size_t)b * NTOK + m) * DIM + n0 + tx * 4;
            float4 cur = *(float4*)dst;
            cur.x += acc[i][0]; cur.y += acc[i][1]; cur.z += acc[i][2]; cur.w += acc[i][3];
            *(float4*)dst = cur;
        }
    }
}

// ---------------------------------------------------------------------------
// Fused FFN: t += leaky(h@w1+b1)@w2 + b2, 8 tokens per block, hidden in LDS.
__global__ __launch_bounds__(256) void ffn_fused(const float* __restrict__ h, float* __restrict__ t,
                                                 const float* __restrict__ w1, const float* __restrict__ b1,
                                                 const float* __restrict__ w2, const float* __restrict__ b2) {
    __shared__ __align__(16) float hin[8 * 256];
    __shared__ __align__(16) float hid[8 * 1024];
    int tk0 = blockIdx.x * 8;
    int tid = threadIdx.x;
#pragma unroll
    for (int i = 0; i < 8; i++) hin[tid + i * 256] = h[(size_t)tk0 * DIM + tid + i * 256];
    __syncthreads();
    float acc[8][4] = {};
    for (int k = 0; k < 256; k++) {
        const float* w1r = w1 + k * HID + tid;
        float wa = w1r[0], wb = w1r[256], wc = w1r[512], wd = w1r[768];
#pragma unroll
        for (int tok = 0; tok < 8; tok++) {
            float hv = hin[tok * 256 + k];
            acc[tok][0] += hv * wa;
            acc[tok][1] += hv * wb;
            acc[tok][2] += hv * wc;
            acc[tok][3] += hv * wd;
        }
    }
#pragma unroll
    for (int jj = 0; jj < 4; jj++) {
        float bias = b1[tid + jj * 256];
#pragma unroll
        for (int tok = 0; tok < 8; tok++) {
            float v = acc[tok][jj] + bias;
            hid[tok * HID + tid + jj * 256] = v > 0.f ? v : 0.01f * v;
        }
    }
    __syncthreads();
    float outv[8] = {};
    for (int jh = 0; jh < HID; jh += 4) {
        const float* w2r = w2 + jh * DIM + tid;
        float wa = w2r[0], wb = w2r[256], wc = w2r[512], wd = w2r[768];
#pragma unroll
        for (int tok = 0; tok < 8; tok++) {
            float4 hv = *(const float4*)&hid[tok * HID + jh];
            outv[tok] += hv.x * wa + hv.y * wb + hv.z * wc + hv.w * wd;
        }
    }
    float bias2 = b2[tid];
#pragma unroll
    for (int tok = 0; tok < 8; tok++) {
        size_t idx = ((size_t)tk0 + tok) * DIM + tid;
        t[idx] += outv[tok] + bias2;
    }
}

// ---------------------------------------------------------------------------
// head: pooled mean -> LN -> logits -> softmax. One block per batch element.
__global__ __launch_bounds__(256) void head_kernel(const float* __restrict__ t,
                                                   const float* __restrict__ hs, const float* __restrict__ hb,
                                                   const float* __restrict__ hw, const float* __restrict__ hbias,
                                                   float* __restrict__ out) {
    __shared__ float red[256];
    __shared__ float lnv[256];
    int b = blockIdx.x, tid = threadIdx.x;
    const float* tb = t + (size_t)b * NTOK * DIM;
    float s = 0.f;
    for (int m = 0; m < NTOK; m++) s += tb[m * DIM + tid];
    s *= (1.f / 1025.f);
    red[tid] = s;
    __syncthreads();
    for (int off = 128; off; off >>= 1) {
        if (tid < off) red[tid] += red[tid + off];
        __syncthreads();
    }
    float mean = red[0] * (1.f / 256.f);
    __syncthreads();
    float d = s - mean;
    red[tid] = d * d;
    __syncthreads();
    for (int off = 128; off; off >>= 1) {
        if (tid < off) red[tid] += red[tid + off];
        __syncthreads();
    }
    float rstd = rsqrtf(red[0] * (1.f / 256.f) + LN_EPS);
    __syncthreads();
    lnv[tid] = d * rstd * hs[tid] + hb[tid];
    __syncthreads();
    float lo[4];
#pragma unroll
    for (int jj = 0; jj < 4; jj++) {
        int n = tid + jj * 256;
        float a = -1e30f;
        if (n < NCLS) {
            a = hbias[n];
            for (int dd = 0; dd < DIM; dd++) a += lnv[dd] * hw[dd * NCLS + n];
        }
        lo[jj] = a;
    }
    float mx = fmaxf(fmaxf(lo[0], lo[1]), fmaxf(lo[2], lo[3]));
    red[tid] = mx;
    __syncthreads();
    for (int off = 128; off; off >>= 1) {
        if (tid < off) red[tid] = fmaxf(red[tid], red[tid + off]);
        __syncthreads();
    }
    float gmax = red[0];
    __syncthreads();
    float ev[4];
    float es = 0.f;
#pragma unroll
    for (int jj = 0; jj < 4; jj++) {
        int n = tid + jj * 256;
        ev[jj] = 0.f;
        if (n < NCLS) {
            ev[jj] = expf(lo[jj] - gmax);
            es += ev[jj];
        }
    }
    red[tid] = es;
    __syncthreads();
    for (int off = 128; off; off >>= 1) {
        if (tid < off) red[tid] += red[tid + off];
        __syncthreads();
    }
    float inv = 1.f / red[0];
#pragma unroll
    for (int jj = 0; jj < 4; jj++) {
        int n = tid + jj * 256;
        if (n < NCLS) out[(size_t)b * NCLS + n] = ev[jj] * inv;
    }
}

// ---------------------------------------------------------------------------
extern "C" void kernel_launch(void* const* d_in, const int* in_sizes, int n_in,
                              void* d_out, int out_size, void* d_ws, size_t ws_size,
                              hipStream_t stream) {
    const float* x      = (const float*)d_in[0];
    const float* conv_w = (const float*)d_in[1];
    const float* conv_b = (const float*)d_in[2];
    const float* pos    = (const float*)d_in[3];
    const float* cls    = (const float*)d_in[4];
    const float* ln1_s  = (const float*)d_in[5];
    const float* ln1_b  = (const float*)d_in[6];
    const float* ln2_s  = (const float*)d_in[7];
    const float* ln2_b  = (const float*)d_in[8];
    const float* w1     = (const float*)d_in[9];
    const float* b1     = (const float*)d_in[10];
    const float* w2     = (const float*)d_in[11];
    const float* b2     = (const float*)d_in[12];
    const float* hls    = (const float*)d_in[13];
    const float* hlb    = (const float*)d_in[14];
    const float* hw     = (const float*)d_in[15];
    const float* hbias  = (const float*)d_in[16];
    float* out = (float*)d_out;
    float* ws = (float*)d_ws;

    float* t  = ws + T_OFF;
    float* h  = ws + H_OFF;
    float* Hc = ws + HC_OFF;
    float* Hs = ws + HS_OFF;
    float* C1 = ws + C1_OFF;
    float* S1 = ws + S1_OFF;
    float* C2 = ws + C2_OFF;
    float* S2 = ws + S2_OFF;
    float* Wt = ws + WT_OFF;

    hipLaunchKernelGGL(gen_dft, dim3(4105), dim3(256), 0, stream, C1, S1, C2, S2);
    hipLaunchKernelGGL(transpose_w, dim3(768), dim3(256), 0, stream, conv_w, Wt);
    hipLaunchKernelGGL(cls_init, dim3(BATCH), dim3(256), 0, stream, cls, pos, t);
    hipLaunchKernelGGL(patch_embed, dim3(4, GHN, BATCH), dim3(256), 0, stream, x, Wt, conv_b, pos, t);

    for (int l = 0; l < NLAYER; l++) {
        hipLaunchKernelGGL(ln_kernel, dim3(16400), dim3(256), 0, stream,
                           t, h, ln1_s + l * DIM, ln1_b + l * DIM);
        hipLaunchKernelGGL(fft_small, dim3(1025, 4), dim3(256), 0, stream, h, C2, S2, Hc, Hs);
        hipLaunchKernelGGL(fft_big, dim3(17, 4, BATCH), dim3(256), 0, stream, C1, S1, Hc, Hs, t);
        hipLaunchKernelGGL(ln_kernel, dim3(16400), dim3(256), 0, stream,
                           t, h, ln2_s + l * DIM, ln2_b + l * DIM);
        hipLaunchKernelGGL(ffn_fused, dim3(8200), dim3(256), 0, stream,
                           h, t, w1 + (size_t)l * DIM * HID, b1 + (size_t)l * HID,
                           w2 + (size_t)l * HID * DIM, b2 + (size_t)l * DIM);
    }
    hipLaunchKernelGGL(head_kernel, dim3(BATCH), dim3(256), 0, stream, t, hls, hlb, hw, hbias, out);
}

// Round 2
// 3976.834 us; speedup vs baseline: 5.5996x; 5.5996x over previous
//
#include <hip/hip_runtime.h>
#include <math.h>

#define BATCH 64
#define CIN 3
#define IMH 512
#define IMW 512
#define PSZ 16
#define DIM 256
#define GHN 32
#define GWN 32
#define NTOK 1025
#define HID 1024
#define NLAYER 6
#define NCLS 1000
#define LN_EPS 1e-5f

// folded dims: token-fold 513 -> pad 576 ; dim-fold 129 -> pad 192
#define KF 576
#define MF 192

typedef __attribute__((ext_vector_type(8))) short short8;
typedef __attribute__((ext_vector_type(4))) float f32x4;

#define MFMA16(acc, a, b) acc = __builtin_amdgcn_mfma_f32_16x16x32_bf16(a, b, acc, 0, 0, 0)

// ---------------------------------------------------------------------------
__device__ inline unsigned short rne_bf16(float x) {
    unsigned u = __float_as_uint(x);
    return (unsigned short)((u + 0x7FFF + ((u >> 16) & 1)) >> 16);
}
__device__ inline void split_bf16(float x, unsigned short& hi, unsigned short& lo) {
    unsigned short h = rne_bf16(x);
    hi = h;
    float hf = __uint_as_float((unsigned)h << 16);
    lo = rne_bf16(x - hf);
}
__device__ inline float wave_sum(float v) {
#pragma unroll
    for (int off = 32; off; off >>= 1) v += __shfl_xor(v, off);
    return v;
}
// LDS tile: 64 rows x BK bf16, granule(row,g) at row*GPR + (g ^ (row & (GPR-1)))
__device__ inline short8 ld8(const unsigned short* lds, int row, int q, int mask) {
    return *(const short8*)(lds + (row * (mask + 1) + (q ^ (row & mask))) * 8);
}
__device__ inline void stage64(unsigned short* lds, const unsigned short* gptr, int lda, int tid) {
#pragma unroll
    for (int i = 0; i < 2; i++) {
        int lin = tid + i * 256;
        int row = lin >> 3, gc = lin & 7;
        short8 v = *(const short8*)(gptr + (size_t)row * lda + gc * 8);
        *(short8*)(lds + (row * 8 + (gc ^ (row & 7))) * 8) = v;
    }
}
__device__ inline void stage32(unsigned short* lds, const unsigned short* gptr, int lda, int tid) {
    int row = tid >> 2, gc = tid & 3;
    short8 v = *(const short8*)(gptr + (size_t)row * lda + gc * 8);
    *(short8*)(lds + (row * 4 + (gc ^ (row & 3))) * 8) = v;
}

// ---------------------------------------------------------------------------
// DFT matrices as bf16 hi/lo. C1f/S1f: [576][576] zero-padded past 512.
__global__ __launch_bounds__(256) void gen_dft2(unsigned short* C1h, unsigned short* C1l,
                                                unsigned short* S1h, unsigned short* S1l,
                                                unsigned short* C2h, unsigned short* C2l,
                                                unsigned short* S2h, unsigned short* S2l) {
    int idx = blockIdx.x * 256 + threadIdx.x;
    if (idx < KF * KF) {
        int k = idx / KF, n = idx - k * KF;
        float c = 0.f, s = 0.f;
        if (k <= 512 && n <= 512) {
            int r = (k * n) % 1025;
            double ang = 6.283185307179586476925287 * (double)r / 1025.0;
            c = (float)cos(ang); s = (float)sin(ang);
        }
        unsigned short h, l;
        split_bf16(c, h, l); C1h[idx] = h; C1l[idx] = l;
        split_bf16(s, h, l); S1h[idx] = h; S1l[idx] = l;
    }
    if (idx < 256 * 256) {
        int k = idx >> 8, n = idx & 255;
        int r = (k * n) & 255;
        double ang = 6.283185307179586476925287 * (double)r / 256.0;
        float c = (float)cos(ang), s = (float)sin(ang);
        unsigned short h, l;
        split_bf16(c, h, l); C2h[idx] = h; C2l[idx] = l;
        split_bf16(s, h, l); S2h[idx] = h; S2l[idx] = l;
    }
}

// ---------------------------------------------------------------------------
__global__ __launch_bounds__(256) void transpose_w(const float* __restrict__ w, float* __restrict__ wt) {
    int idx = blockIdx.x * 256 + threadIdx.x;
    if (idx < DIM * 768) {
        int d = idx / 768, k = idx - d * 768;
        wt[k * DIM + d] = w[idx];
    }
}
// w1t[l][n:1024][k:256] = bf16(w1[l][k][n])
__global__ __launch_bounds__(256) void conv_w1t(const float* __restrict__ w1, unsigned short* __restrict__ w1t) {
    int idx = blockIdx.x * 256 + threadIdx.x;   // < 6*262144
    int l = idx / 262144, rem = idx - l * 262144;
    int n = rem >> 8, k = rem & 255;
    w1t[idx] = rne_bf16(w1[(size_t)l * 262144 + (size_t)k * 1024 + n]);
}
// w2t[l][n:256][k:1024] = bf16(w2[l][k][n])
__global__ __launch_bounds__(256) void conv_w2t(const float* __restrict__ w2, unsigned short* __restrict__ w2t) {
    int idx = blockIdx.x * 256 + threadIdx.x;
    int l = idx / 262144, rem = idx - l * 262144;
    int n = rem >> 10, k = rem & 1023;
    w2t[idx] = rne_bf16(w2[(size_t)l * 262144 + (size_t)k * 256 + n]);
}

// ---------------------------------------------------------------------------
__global__ __launch_bounds__(256) void cls_init(const float* __restrict__ cls, const float* __restrict__ pos,
                                                float* __restrict__ t) {
    int b = blockIdx.x, tid = threadIdx.x;
    t[(size_t)b * NTOK * DIM + tid] = cls[tid] + pos[tid];
}

// ---------------------------------------------------------------------------
__global__ __launch_bounds__(256) void patch_embed(const float* __restrict__ x, const float* __restrict__ wt,
                                                   const float* __restrict__ cb, const float* __restrict__ pos,
                                                   float* __restrict__ t) {
    __shared__ __align__(16) float lds[8 * 768];
    int b = blockIdx.z, gh = blockIdx.y, g4 = blockIdx.x;
    int tid = threadIdx.x;
    const float* xb = x + (size_t)b * CIN * IMH * IMW;
#pragma unroll
    for (int i = 0; i < 24; i++) {
        int e = tid + i * 256;
        int c = e >> 11, rem = e & 2047, p = rem >> 7, q128 = rem & 127;
        float val = xb[(c * IMH + gh * PSZ + p) * IMW + g4 * 128 + q128];
        lds[(q128 >> 4) * 768 + c * 256 + p * PSZ + (q128 & 15)] = val;
    }
    __syncthreads();
    int grp = tid >> 6;
    int dl = (tid & 63) << 2;
    float4 a0 = {0.f, 0.f, 0.f, 0.f}, a1 = {0.f, 0.f, 0.f, 0.f};
    const float* l0 = &lds[(2 * grp) * 768];
    const float* l1 = &lds[(2 * grp + 1) * 768];
    for (int k = 0; k < 768; k++) {
        float4 w4 = *(const float4*)&wt[k * DIM + dl];
        float h0 = l0[k], h1 = l1[k];
        a0.x += h0 * w4.x; a0.y += h0 * w4.y; a0.z += h0 * w4.z; a0.w += h0 * w4.w;
        a1.x += h1 * w4.x; a1.y += h1 * w4.y; a1.z += h1 * w4.z; a1.w += h1 * w4.w;
    }
    float4 cb4 = *(const float4*)&cb[dl];
    int tokbase = 1 + gh * GWN + g4 * 8 + 2 * grp;
    float4 p0 = *(const float4*)&pos[(size_t)tokbase * DIM + dl];
    float4 p1 = *(const float4*)&pos[(size_t)(tokbase + 1) * DIM + dl];
    float4 o0 = {a0.x + cb4.x + p0.x, a0.y + cb4.y + p0.y, a0.z + cb4.z + p0.z, a0.w + cb4.w + p0.w};
    float4 o1 = {a1.x + cb4.x + p1.x, a1.y + cb4.y + p1.y, a1.z + cb4.z + p1.z, a1.w + cb4.w + p1.w};
    *(float4*)&t[((size_t)b * NTOK + tokbase) * DIM + dl] = o0;
    *(float4*)&t[((size_t)b * NTOK + tokbase + 1) * DIM + dl] = o1;
}

// ---------------------------------------------------------------------------
// LN rows n' and 1025-n', emit Yh+ = hA+hB, Yh- = hA-hB as bf16 hi/lo.
// Rows 513..575 zeroed. One wave per n'.
__global__ __launch_bounds__(256) void ln1fold(const float* __restrict__ t,
                                               const float* __restrict__ s, const float* __restrict__ bb,
                                               unsigned short* __restrict__ Yph, unsigned short* __restrict__ Ypl,
                                               unsigned short* __restrict__ Ymh, unsigned short* __restrict__ Yml) {
    int tid = threadIdx.x, lane = tid & 63, w = tid >> 6;
    int b = blockIdx.y;
    int np = blockIdx.x * 4 + w;
    size_t ybase = ((size_t)b * KF + np) * 256 + lane * 4;
    if (np >= 513) {
        ushort4 z = make_ushort4(0, 0, 0, 0);
        *(ushort4*)(Yph + ybase) = z; *(ushort4*)(Ypl + ybase) = z;
        *(ushort4*)(Ymh + ybase) = z; *(ushort4*)(Yml + ybase) = z;
        return;
    }
    const float* tb = t + (size_t)b * NTOK * DIM;
    float4 va = *(const float4*)(tb + (size_t)np * 256 + lane * 4);
    float sa = wave_sum(va.x + va.y + va.z + va.w) * (1.f / 256.f);
    float dax = va.x - sa, day = va.y - sa, daz = va.z - sa, daw = va.w - sa;
    float qa = wave_sum(dax * dax + day * day + daz * daz + daw * daw);
    float ra = rsqrtf(qa * (1.f / 256.f) + LN_EPS);
    float4 s4 = *(const float4*)(s + lane * 4);
    float4 b4 = *(const float4*)(bb + lane * 4);
    float hax = dax * ra * s4.x + b4.x, hay = day * ra * s4.y + b4.y;
    float haz = daz * ra * s4.z + b4.z, haw = daw * ra * s4.w + b4.w;
    float hbx = 0.f, hby = 0.f, hbz = 0.f, hbw = 0.f;
    if (np >= 1) {
        float4 vb = *(const float4*)(tb + (size_t)(NTOK - np) * 256 + lane * 4);
        float sb = wave_sum(vb.x + vb.y + vb.z + vb.w) * (1.f / 256.f);
        float dbx = vb.x - sb, dby = vb.y - sb, dbz = vb.z - sb, dbw = vb.w - sb;
        float qb = wave_sum(dbx * dbx + dby * dby + dbz * dbz + dbw * dbw);
        float rb = rsqrtf(qb * (1.f / 256.f) + LN_EPS);
        hbx = dbx * rb * s4.x + b4.x; hby = dby * rb * s4.y + b4.y;
        hbz = dbz * rb * s4.z + b4.z; hbw = dbw * rb * s4.w + b4.w;
    }
    ushort4 ph, pl, mh, ml;
    split_bf16(hax + hbx, ph.x, pl.x); split_bf16(hay + hby, ph.y, pl.y);
    split_bf16(haz + hbz, ph.z, pl.z); split_bf16(haw + hbw, ph.w, pl.w);
    split_bf16(hax - hbx, mh.x, ml.x); split_bf16(hay - hby, mh.y, ml.y);
    split_bf16(haz - hbz, mh.z, ml.z); split_bf16(haw - hbw, mh.w, ml.w);
    *(ushort4*)(Yph + ybase) = ph; *(ushort4*)(Ypl + ybase) = pl;
    *(ushort4*)(Ymh + ybase) = mh; *(ushort4*)(Yml + ybase) = ml;
}

// ---------------------------------------------------------------------------
// LN over t -> bf16 h (for FFN). 4 rows/block.
__global__ __launch_bounds__(256) void ln2_bf16(const float* __restrict__ t, unsigned short* __restrict__ hh,
                                                const float* __restrict__ s, const float* __restrict__ bb) {
    int wave = threadIdx.x >> 6, lane = threadIdx.x & 63;
    int m = blockIdx.x * 4 + wave;
    const float* row = t + (size_t)m * DIM;
    float4 v = *(const float4*)(row + lane * 4);
    float mean = wave_sum(v.x + v.y + v.z + v.w) * (1.f / 256.f);
    float dx = v.x - mean, dy = v.y - mean, dz = v.z - mean, dw = v.w - mean;
    float sq = wave_sum(dx * dx + dy * dy + dz * dz + dw * dw);
    float rstd = rsqrtf(sq * (1.f / 256.f) + LN_EPS);
    float4 s4 = *(const float4*)(s + lane * 4);
    float4 b4 = *(const float4*)(bb + lane * 4);
    ushort4 o;
    o.x = rne_bf16(dx * rstd * s4.x + b4.x);
    o.y = rne_bf16(dy * rstd * s4.y + b4.y);
    o.z = rne_bf16(dz * rstd * s4.z + b4.z);
    o.w = rne_bf16(dw * rstd * s4.w + b4.w);
    *(ushort4*)(hh + (size_t)m * DIM + lane * 4) = o;
}

// ---------------------------------------------------------------------------
// Split-bf16 GEMM (3-pass), A[M][256] flat (M=64*576), B[n][256] (symmetric DFT),
// output transposed+split: O[b][c:192][kp:576] (bf16 hi/lo). grid(576,3).
__global__ __launch_bounds__(256) void gemm_splitT(
    const unsigned short* __restrict__ Ahi, const unsigned short* __restrict__ Alo,
    const unsigned short* __restrict__ Bhi, const unsigned short* __restrict__ Blo,
    unsigned short* __restrict__ Ohi, unsigned short* __restrict__ Olo) {
    __shared__ __align__(16) unsigned short sAh[4096], sAl[4096], sBh[4096], sBl[4096];
    int m0 = blockIdx.x * 64, n0 = blockIdx.y * 64;
    int tid = threadIdx.x, lane = tid & 63, w = tid >> 6;
    int wr = (w >> 1) * 32, wc = (w & 1) * 32;
    f32x4 z = {0.f, 0.f, 0.f, 0.f};
    f32x4 acc[2][2] = {{z, z}, {z, z}};
    for (int k0 = 0; k0 < 256; k0 += 64) {
        stage64(sAh, Ahi + (size_t)m0 * 256 + k0, 256, tid);
        stage64(sAl, Alo + (size_t)m0 * 256 + k0, 256, tid);
        stage64(sBh, Bhi + (size_t)n0 * 256 + k0, 256, tid);
        stage64(sBl, Blo + (size_t)n0 * 256 + k0, 256, tid);
        __syncthreads();
#pragma unroll
        for (int kc = 0; kc < 2; kc++) {
            int q = (lane >> 4) + kc * 4;
            short8 ah[2], al[2], bh[2], bl[2];
#pragma unroll
            for (int i = 0; i < 2; i++) {
                int r1 = wr + i * 16 + (lane & 15);
                ah[i] = ld8(sAh, r1, q, 7); al[i] = ld8(sAl, r1, q, 7);
                int r2 = wc + i * 16 + (lane & 15);
                bh[i] = ld8(sBh, r2, q, 7); bl[i] = ld8(sBl, r2, q, 7);
            }
#pragma unroll
            for (int i = 0; i < 2; i++)
#pragma unroll
                for (int j = 0; j < 2; j++) {
                    MFMA16(acc[i][j], ah[i], bh[j]);
                    MFMA16(acc[i][j], ah[i], bl[j]);
                    MFMA16(acc[i][j], al[i], bh[j]);
                }
        }
        __syncthreads();
    }
    int q4 = (lane >> 4) * 4;
#pragma unroll
    for (int i = 0; i < 2; i++) {
        int r = m0 + wr + i * 16 + q4;
        int bidx = r / KF, kp = r - bidx * KF;
#pragma unroll
        for (int j = 0; j < 2; j++) {
            int c = n0 + wc + j * 16 + (lane & 15);
            ushort4 oh, ol;
            split_bf16(acc[i][j][0], oh.x, ol.x);
            split_bf16(acc[i][j][1], oh.y, ol.y);
            split_bf16(acc[i][j][2], oh.z, ol.z);
            split_bf16(acc[i][j][3], oh.w, ol.w);
            size_t off = ((size_t)bidx * MF + c) * KF + kp;
            *(ushort4*)(Ohi + off) = oh;
            *(ushort4*)(Olo + off) = ol;
        }
    }
}

// ---------------------------------------------------------------------------
// Dual split GEMM + butterfly: U = C1f @ Yc, V = S1f @ Ys (per batch),
// t[k][m] += U-V ; t[1025-k][m] += U+V ; t[k][256-m] += U+V ; t[1025-k][256-m] += U-V
// grid(9, 3, 64). A:[576][576], B:[b][192][576].
__global__ __launch_bounds__(256) void fft_big_dual(
    const unsigned short* __restrict__ C1h, const unsigned short* __restrict__ C1l,
    const unsigned short* __restrict__ S1h, const unsigned short* __restrict__ S1l,
    const unsigned short* __restrict__ Ych, const unsigned short* __restrict__ Ycl,
    const unsigned short* __restrict__ Ysh, const unsigned short* __restrict__ Ysl,
    float* __restrict__ t) {
    __shared__ __align__(16) unsigned short sC1h[2048], sC1l[2048], sS1h[2048], sS1l[2048];
    __shared__ __align__(16) unsigned short sYch[2048], sYcl[2048], sYsh[2048], sYsl[2048];
    int k0m = blockIdx.x * 64, n0 = blockIdx.y * 64, b = blockIdx.z;
    int tid = threadIdx.x, lane = tid & 63, w = tid >> 6;
    int wr = (w >> 1) * 32, wc = (w & 1) * 32;
    const unsigned short* ych = Ych + (size_t)b * MF * KF;
    const unsigned short* ycl = Ycl + (size_t)b * MF * KF;
    const unsigned short* ysh = Ysh + (size_t)b * MF * KF;
    const unsigned short* ysl = Ysl + (size_t)b * MF * KF;
    f32x4 z = {0.f, 0.f, 0.f, 0.f};
    f32x4 U[2][2] = {{z, z}, {z, z}}, V[2][2] = {{z, z}, {z, z}};
    for (int kk0 = 0; kk0 < KF; kk0 += 32) {
        stage32(sC1h, C1h + (size_t)k0m * KF + kk0, KF, tid);
        stage32(sC1l, C1l + (size_t)k0m * KF + kk0, KF, tid);
        stage32(sS1h, S1h + (size_t)k0m * KF + kk0, KF, tid);
        stage32(sS1l, S1l + (size_t)k0m * KF + kk0, KF, tid);
        stage32(sYch, ych + (size_t)n0 * KF + kk0, KF, tid);
        stage32(sYcl, ycl + (size_t)n0 * KF + kk0, KF, tid);
        stage32(sYsh, ysh + (size_t)n0 * KF + kk0, KF, tid);
        stage32(sYsl, ysl + (size_t)n0 * KF + kk0, KF, tid);
        __syncthreads();
        int q = lane >> 4;
        short8 c1h[2], c1l[2], s1h[2], s1l[2], ych8[2], ycl8[2], ysh8[2], ysl8[2];
#pragma unroll
        for (int i = 0; i < 2; i++) {
            int r1 = wr + i * 16 + (lane & 15);
            c1h[i] = ld8(sC1h, r1, q, 3); c1l[i] = ld8(sC1l, r1, q, 3);
            s1h[i] = ld8(sS1h, r1, q, 3); s1l[i] = ld8(sS1l, r1, q, 3);
            int r2 = wc + i * 16 + (lane & 15);
            ych8[i] = ld8(sYch, r2, q, 3); ycl8[i] = ld8(sYcl, r2, q, 3);
            ysh8[i] = ld8(sYsh, r2, q, 3); ysl8[i] = ld8(sYsl, r2, q, 3);
        }
#pragma unroll
        for (int i = 0; i < 2; i++)
#pragma unroll
            for (int j = 0; j < 2; j++) {
                MFMA16(U[i][j], c1h[i], ych8[j]);
                MFMA16(U[i][j], c1h[i], ycl8[j]);
                MFMA16(U[i][j], c1l[i], ych8[j]);
                MFMA16(V[i][j], s1h[i], ysh8[j]);
                MFMA16(V[i][j], s1h[i], ysl8[j]);
                MFMA16(V[i][j], s1l[i], ysh8[j]);
            }
        __syncthreads();
    }
    float* tb = t + (size_t)b * NTOK * DIM;
    int q4 = (lane >> 4) * 4;
#pragma unroll
    for (int i = 0; i < 2; i++) {
        int kk = k0m + wr + i * 16 + q4;
#pragma unroll
        for (int j = 0; j < 2; j++) {
            int mm = n0 + wc + j * 16 + (lane & 15);
            if (mm > 128) continue;
#pragma unroll
            for (int g = 0; g < 4; g++) {
                int k = kk + g;
                if (k > 512) continue;
                float u = U[i][j][g], v = V[i][j][g];
                tb[(size_t)k * 256 + mm] += u - v;
                if (mm >= 1 && mm <= 127) tb[(size_t)k * 256 + 256 - mm] += u + v;
                if (k >= 1) {
                    tb[(size_t)(NTOK - k) * 256 + mm] += u + v;
                    if (mm >= 1 && mm <= 127) tb[(size_t)(NTOK - k) * 256 + 256 - mm] += u - v;
                }
            }
        }
    }
}

// ---------------------------------------------------------------------------
// Plain bf16 GEMM: hidden = leaky(h @ w1 + b1). A:[65600][256], B=w1t:[1024][256].
// grid(1025, 16).
__global__ __launch_bounds__(256) void gemm_ffn1(
    const unsigned short* __restrict__ A, const unsigned short* __restrict__ Bt,
    const float* __restrict__ b1, unsigned short* __restrict__ Hid) {
    __shared__ __align__(16) unsigned short sA[4096], sB[4096];
    int m0 = blockIdx.x * 64, n0 = blockIdx.y * 64;
    int tid = threadIdx.x, lane = tid & 63, w = tid >> 6;
    int wr = (w >> 1) * 32, wc = (w & 1) * 32;
    f32x4 z = {0.f, 0.f, 0.f, 0.f};
    f32x4 acc[2][2] = {{z, z}, {z, z}};
    for (int k0 = 0; k0 < 256; k0 += 64) {
        stage64(sA, A + (size_t)m0 * 256 + k0, 256, tid);
        stage64(sB, Bt + (size_t)n0 * 256 + k0, 256, tid);
        __syncthreads();
#pragma unroll
        for (int kc = 0; kc < 2; kc++) {
            int q = (lane >> 4) + kc * 4;
            short8 a8[2], b8[2];
#pragma unroll
            for (int i = 0; i < 2; i++) {
                a8[i] = ld8(sA, wr + i * 16 + (lane & 15), q, 7);
                b8[i] = ld8(sB, wc + i * 16 + (lane & 15), q, 7);
            }
#pragma unroll
            for (int i = 0; i < 2; i++)
#pragma unroll
                for (int j = 0; j < 2; j++) MFMA16(acc[i][j], a8[i], b8[j]);
        }
        __syncthreads();
    }
    int q4 = (lane >> 4) * 4;
#pragma unroll
    for (int i = 0; i < 2; i++) {
        int r = m0 + wr + i * 16 + q4;
#pragma unroll
        for (int j = 0; j < 2; j++) {
            int c = n0 + wc + j * 16 + (lane & 15);
            float bv = b1[c];
#pragma unroll
            for (int g = 0; g < 4; g++) {
                float val = acc[i][j][g] + bv;
                val = val > 0.f ? val : 0.01f * val;
                Hid[(size_t)(r + g) * 1024 + c] = rne_bf16(val);
            }
        }
    }
}

// ---------------------------------------------------------------------------
// Plain bf16 GEMM: t += Hid @ w2 + b2. A:[65600][1024], B=w2t:[256][1024]. grid(1025,4).
__global__ __launch_bounds__(256) void gemm_ffn2(
    const unsigned short* __restrict__ A, const unsigned short* __restrict__ Bt,
    const float* __restrict__ b2, float* __restrict__ t) {
    __shared__ __align__(16) unsigned short sA[4096], sB[4096];
    int m0 = blockIdx.x * 64, n0 = blockIdx.y * 64;
    int tid = threadIdx.x, lane = tid & 63, w = tid >> 6;
    int wr = (w >> 1) * 32, wc = (w & 1) * 32;
    f32x4 z = {0.f, 0.f, 0.f, 0.f};
    f32x4 acc[2][2] = {{z, z}, {z, z}};
    for (int k0 = 0; k0 < 1024; k0 += 64) {
        stage64(sA, A + (size_t)m0 * 1024 + k0, 1024, tid);
        stage64(sB, Bt + (size_t)n0 * 1024 + k0, 1024, tid);
        __syncthreads();
#pragma unroll
        for (int kc = 0; kc < 2; kc++) {
            int q = (lane >> 4) + kc * 4;
            short8 a8[2], b8[2];
#pragma unroll
            for (int i = 0; i < 2; i++) {
                a8[i] = ld8(sA, wr + i * 16 + (lane & 15), q, 7);
                b8[i] = ld8(sB, wc + i * 16 + (lane & 15), q, 7);
            }
#pragma unroll
            for (int i = 0; i < 2; i++)
#pragma unroll
                for (int j = 0; j < 2; j++) MFMA16(acc[i][j], a8[i], b8[j]);
        }
        __syncthreads();
    }
    int q4 = (lane >> 4) * 4;
#pragma unroll
    for (int i = 0; i < 2; i++) {
        int r = m0 + wr + i * 16 + q4;
#pragma unroll
        for (int j = 0; j < 2; j++) {
            int c = n0 + wc + j * 16 + (lane & 15);
            float bv = b2[c];
#pragma unroll
            for (int g = 0; g < 4; g++) {
                size_t idx = (size_t)(r + g) * 256 + c;
                t[idx] += acc[i][j][g] + bv;
            }
        }
    }
}

// ---------------------------------------------------------------------------
__global__ __launch_bounds__(256) void head_kernel(const float* __restrict__ t,
                                                   const float* __restrict__ hs, const float* __restrict__ hb,
                                                   const float* __restrict__ hw, const float* __restrict__ hbias,
                                                   float* __restrict__ out) {
    __shared__ float red[256];
    __shared__ float lnv[256];
    int b = blockIdx.x, tid = threadIdx.x;
    const float* tb = t + (size_t)b * NTOK * DIM;
    float s = 0.f;
    for (int m = 0; m < NTOK; m++) s += tb[m * DIM + tid];
    s *= (1.f / 1025.f);
    red[tid] = s;
    __syncthreads();
    for (int off = 128; off; off >>= 1) {
        if (tid < off) red[tid] += red[tid + off];
        __syncthreads();
    }
    float mean = red[0] * (1.f / 256.f);
    __syncthreads();
    float d = s - mean;
    red[tid] = d * d;
    __syncthreads();
    for (int off = 128; off; off >>= 1) {
        if (tid < off) red[tid] += red[tid + off];
        __syncthreads();
    }
    float rstd = rsqrtf(red[0] * (1.f / 256.f) + LN_EPS);
    __syncthreads();
    lnv[tid] = d * rstd * hs[tid] + hb[tid];
    __syncthreads();
    float lo[4];
#pragma unroll
    for (int jj = 0; jj < 4; jj++) {
        int n = tid + jj * 256;
        float a = -1e30f;
        if (n < NCLS) {
            a = hbias[n];
            for (int dd = 0; dd < DIM; dd++) a += lnv[dd] * hw[dd * NCLS + n];
        }
        lo[jj] = a;
    }
    float mx = fmaxf(fmaxf(lo[0], lo[1]), fmaxf(lo[2], lo[3]));
    red[tid] = mx;
    __syncthreads();
    for (int off = 128; off; off >>= 1) {
        if (tid < off) red[tid] = fmaxf(red[tid], red[tid + off]);
        __syncthreads();
    }
    float gmax = red[0];
    __syncthreads();
    float ev[4];
    float es = 0.f;
#pragma unroll
    for (int jj = 0; jj < 4; jj++) {
        int n = tid + jj * 256;
        ev[jj] = 0.f;
        if (n < NCLS) {
            ev[jj] = expf(lo[jj] - gmax);
            es += ev[jj];
        }
    }
    red[tid] = es;
    __syncthreads();
    for (int off = 128; off; off >>= 1) {
        if (tid < off) red[tid] += red[tid + off];
        __syncthreads();
    }
    float inv = 1.f / red[0];
#pragma unroll
    for (int jj = 0; jj < 4; jj++) {
        int n = tid + jj * 256;
        if (n < NCLS) out[(size_t)b * NCLS + n] = ev[jj] * inv;
    }
}

// ---------------------------------------------------------------------------
extern "C" void kernel_launch(void* const* d_in, const int* in_sizes, int n_in,
                              void* d_out, int out_size, void* d_ws, size_t ws_size,
                              hipStream_t stream) {
    const float* x      = (const float*)d_in[0];
    const float* conv_w = (const float*)d_in[1];
    const float* conv_b = (const float*)d_in[2];
    const float* pos    = (const float*)d_in[3];
    const float* cls    = (const float*)d_in[4];
    const float* ln1_s  = (const float*)d_in[5];
    const float* ln1_b  = (const float*)d_in[6];
    const float* ln2_s  = (const float*)d_in[7];
    const float* ln2_b  = (const float*)d_in[8];
    const float* w1     = (const float*)d_in[9];
    const float* b1     = (const float*)d_in[10];
    const float* w2     = (const float*)d_in[11];
    const float* b2     = (const float*)d_in[12];
    const float* hls    = (const float*)d_in[13];
    const float* hlb    = (const float*)d_in[14];
    const float* hw     = (const float*)d_in[15];
    const float* hbias  = (const float*)d_in[16];
    float* out = (float*)d_out;
    char* W = (char*)d_ws;

    // layout (bytes): t | POOL{Yp(4x18.9MB)+Yct(4x14.2MB) / Hid} | h_hi | C1f | C2 | w1t | w2t | Wt
    float*          t    = (float*)(W + 0ULL);
    unsigned short* Yph  = (unsigned short*)(W + 67174400ULL);
    unsigned short* Ypl  = (unsigned short*)(W + 67174400ULL + 18874368ULL);
    unsigned short* Ymh  = (unsigned short*)(W + 67174400ULL + 2 * 18874368ULL);
    unsigned short* Yml  = (unsigned short*)(W + 67174400ULL + 3 * 18874368ULL);
    unsigned short* Ycth = (unsigned short*)(W + 142671872ULL);
    unsigned short* Yctl = (unsigned short*)(W + 142671872ULL + 14155776ULL);
    unsigned short* Ysth = (unsigned short*)(W + 142671872ULL + 2 * 14155776ULL);
    unsigned short* Ystl = (unsigned short*)(W + 142671872ULL + 3 * 14155776ULL);
    unsigned short* Hid  = (unsigned short*)(W + 67174400ULL);   // aliases Yp/Yct (dead by then)
    unsigned short* hh   = (unsigned short*)(W + 201523200ULL);
    unsigned short* C1h  = (unsigned short*)(W + 235110400ULL);
    unsigned short* C1l  = (unsigned short*)(W + 235110400ULL + 663552ULL);
    unsigned short* S1h  = (unsigned short*)(W + 235110400ULL + 2 * 663552ULL);
    unsigned short* S1l  = (unsigned short*)(W + 235110400ULL + 3 * 663552ULL);
    unsigned short* C2h  = (unsigned short*)(W + 237764608ULL);
    unsigned short* C2l  = (unsigned short*)(W + 237764608ULL + 131072ULL);
    unsigned short* S2h  = (unsigned short*)(W + 237764608ULL + 2 * 131072ULL);
    unsigned short* S2l  = (unsigned short*)(W + 237764608ULL + 3 * 131072ULL);
    unsigned short* w1t  = (unsigned short*)(W + 238288896ULL);
    unsigned short* w2t  = (unsigned short*)(W + 241434624ULL);
    float*          Wt   = (float*)(W + 244580352ULL);

    hipLaunchKernelGGL(gen_dft2, dim3(1296), dim3(256), 0, stream, C1h, C1l, S1h, S1l, C2h, C2l, S2h, S2l);
    hipLaunchKernelGGL(transpose_w, dim3(768), dim3(256), 0, stream, conv_w, Wt);
    hipLaunchKernelGGL(conv_w1t, dim3(6144), dim3(256), 0, stream, w1, w1t);
    hipLaunchKernelGGL(conv_w2t, dim3(6144), dim3(256), 0, stream, w2, w2t);
    hipLaunchKernelGGL(cls_init, dim3(BATCH), dim3(256), 0, stream, cls, pos, t);
    hipLaunchKernelGGL(patch_embed, dim3(4, GHN, BATCH), dim3(256), 0, stream, x, Wt, conv_b, pos, t);

    for (int l = 0; l < NLAYER; l++) {
        hipLaunchKernelGGL(ln1fold, dim3(144, BATCH), dim3(256), 0, stream,
                           t, ln1_s + l * DIM, ln1_b + l * DIM, Yph, Ypl, Ymh, Yml);
        hipLaunchKernelGGL(gemm_splitT, dim3(576, 3), dim3(256), 0, stream,
                           Yph, Ypl, C2h, C2l, Ycth, Yctl);
        hipLaunchKernelGGL(gemm_splitT, dim3(576, 3), dim3(256), 0, stream,
                           Ymh, Yml, S2h, S2l, Ysth, Ystl);
        hipLaunchKernelGGL(fft_big_dual, dim3(9, 3, BATCH), dim3(256), 0, stream,
                           C1h, C1l, S1h, S1l, Ycth, Yctl, Ysth, Ystl, t);
        hipLaunchKernelGGL(ln2_bf16, dim3(16400), dim3(256), 0, stream,
                           t, hh, ln2_s + l * DIM, ln2_b + l * DIM);
        hipLaunchKernelGGL(gemm_ffn1, dim3(1025, 16), dim3(256), 0, stream,
                           hh, w1t + (size_t)l * 262144, b1 + (size_t)l * HID, Hid);
        hipLaunchKernelGGL(gemm_ffn2, dim3(1025, 4), dim3(256), 0, stream,
                           Hid, w2t + (size_t)l * 262144, b2 + (size_t)l * DIM, t);
    }
    hipLaunchKernelGGL(head_kernel, dim3(BATCH), dim3(256), 0, stream, t, hls, hlb, hw, hbias, out);
}

// Round 3
// 3501.937 us; speedup vs baseline: 6.3590x; 1.1356x over previous
//
#include <hip/hip_runtime.h>
#include <math.h>

#define BATCH 64
#define CIN 3
#define IMH 512
#define IMW 512
#define PSZ 16
#define DIM 256
#define GHN 32
#define GWN 32
#define NTOK 1025
#define HID 1024
#define NLAYER 6
#define NCLS 1000
#define LN_EPS 1e-5f

// folded dims: token-fold 513 -> pad 576 ; dim-fold 129 -> pad 192
#define KF 576
#define MF 192
#define MROWS 65600   // 64*1025

typedef __attribute__((ext_vector_type(8))) short short8;
typedef __attribute__((ext_vector_type(4))) float f32x4;

#define MFMA16(acc, a, b) acc = __builtin_amdgcn_mfma_f32_16x16x32_bf16(a, b, acc, 0, 0, 0)

// ---------------------------------------------------------------------------
__device__ inline unsigned short rne_bf16(float x) {
    unsigned u = __float_as_uint(x);
    return (unsigned short)((u + 0x7FFF + ((u >> 16) & 1)) >> 16);
}
__device__ inline void split_bf16(float x, unsigned short& hi, unsigned short& lo) {
    unsigned short h = rne_bf16(x);
    hi = h;
    float hf = __uint_as_float((unsigned)h << 16);
    lo = rne_bf16(x - hf);
}
__device__ inline float wave_sum(float v) {
#pragma unroll
    for (int off = 32; off; off >>= 1) v += __shfl_xor(v, off);
    return v;
}
// swizzled LDS tile: granule(row,g) at slot row*(mask+1) + (g ^ (row & mask))
__device__ inline short8 ld8(const unsigned short* lds, int row, int q, int mask) {
    return *(const short8*)(lds + (row * (mask + 1) + (q ^ (row & mask))) * 8);
}
// async global->LDS 16B (lds arg must be wave-uniform; HW adds lane*16)
__device__ inline void gl2lds16(const unsigned short* g, unsigned short* l) {
    __builtin_amdgcn_global_load_lds((const __attribute__((address_space(1))) unsigned int*)g,
                                     (__attribute__((address_space(3))) unsigned int*)l, 16, 0, 0);
}
// 64 rows x 64 bf16 (8 granules/row), mask 7: 2 instr/wave
__device__ inline void a_stage64(unsigned short* lds, const unsigned short* g, int lda, int tid) {
    int lane = tid & 63, w = tid >> 6;
#pragma unroll
    for (int s = 0; s < 2; s++) {
        int slot = w * 128 + s * 64;
        int sl = slot + lane;
        int row = sl >> 3, gc = (sl & 7) ^ (row & 7);
        gl2lds16(g + (size_t)row * lda + gc * 8, lds + slot * 8);
    }
}
// 64 rows x 32 bf16 (4 granules/row), mask 3: 1 instr/wave
__device__ inline void a_stage32(unsigned short* lds, const unsigned short* g, int lda, int tid) {
    int lane = tid & 63, w = tid >> 6;
    int slot = w * 64;
    int sl = slot + lane;
    int row = sl >> 2, gc = (sl & 3) ^ (row & 3);
    gl2lds16(g + (size_t)row * lda + gc * 8, lds + slot * 8);
}
// 128 rows x 64 bf16, mask 7: 4 instr/wave; row clamped (M-tail)
__device__ inline void a_stage128(unsigned short* lds, const unsigned short* g, int lda, int tid, int maxrow) {
    int lane = tid & 63, w = tid >> 6;
#pragma unroll
    for (int s = 0; s < 4; s++) {
        int slot = w * 256 + s * 64;
        int sl = slot + lane;
        int row = sl >> 3, gc = (sl & 7) ^ (row & 7);
        if (row > maxrow) row = maxrow;
        gl2lds16(g + (size_t)row * lda + gc * 8, lds + slot * 8);
    }
}

// ---------------------------------------------------------------------------
__global__ __launch_bounds__(256) void gen_dft2(unsigned short* C1h, unsigned short* C1l,
                                                unsigned short* S1h, unsigned short* S1l,
                                                unsigned short* C2h, unsigned short* C2l,
                                                unsigned short* S2h, unsigned short* S2l) {
    int idx = blockIdx.x * 256 + threadIdx.x;
    if (idx < KF * KF) {
        int k = idx / KF, n = idx - k * KF;
        float c = 0.f, s = 0.f;
        if (k <= 512 && n <= 512) {
            int r = (k * n) % 1025;
            double ang = 6.283185307179586476925287 * (double)r / 1025.0;
            c = (float)cos(ang); s = (float)sin(ang);
        }
        unsigned short h, l;
        split_bf16(c, h, l); C1h[idx] = h; C1l[idx] = l;
        split_bf16(s, h, l); S1h[idx] = h; S1l[idx] = l;
    }
    if (idx < 256 * 256) {
        int k = idx >> 8, n = idx & 255;
        int r = (k * n) & 255;
        double ang = 6.283185307179586476925287 * (double)r / 256.0;
        float c = (float)cos(ang), s = (float)sin(ang);
        unsigned short h, l;
        split_bf16(c, h, l); C2h[idx] = h; C2l[idx] = l;
        split_bf16(s, h, l); S2h[idx] = h; S2l[idx] = l;
    }
}

// wp hi/lo: conv_w is already [d=256][k=768] with k = c*256+p*16+q
__global__ __launch_bounds__(256) void conv_wp(const float* __restrict__ w,
                                               unsigned short* __restrict__ wph, unsigned short* __restrict__ wpl) {
    int idx = blockIdx.x * 256 + threadIdx.x;
    unsigned short h, l;
    split_bf16(w[idx], h, l);
    wph[idx] = h; wpl[idx] = l;
}
// w1t[l][n:1024][k:256]
__global__ __launch_bounds__(256) void conv_w1t(const float* __restrict__ w1, unsigned short* __restrict__ w1t) {
    int idx = blockIdx.x * 256 + threadIdx.x;
    int l = idx / 262144, rem = idx - l * 262144;
    int n = rem >> 8, k = rem & 255;
    w1t[idx] = rne_bf16(w1[(size_t)l * 262144 + (size_t)k * 1024 + n]);
}
// w2t[l][n:256][k:1024]
__global__ __launch_bounds__(256) void conv_w2t(const float* __restrict__ w2, unsigned short* __restrict__ w2t) {
    int idx = blockIdx.x * 256 + threadIdx.x;
    int l = idx / 262144, rem = idx - l * 262144;
    int n = rem >> 10, k = rem & 1023;
    w2t[idx] = rne_bf16(w2[(size_t)l * 262144 + (size_t)k * 256 + n]);
}

// ---------------------------------------------------------------------------
__global__ __launch_bounds__(256) void cls_init(const float* __restrict__ cls, const float* __restrict__ pos,
                                                float* __restrict__ t) {
    int b = blockIdx.x, tid = threadIdx.x;
    t[(size_t)b * NTOK * DIM + tid] = cls[tid] + pos[tid];
}

// ---------------------------------------------------------------------------
// repack x -> xp[m=b*1024+gh*32+gw][k=c*256+p*16+q], LO=0: hi part, LO=1: lo part
template<int LO>
__global__ __launch_bounds__(256) void repack_x(const float* __restrict__ x, unsigned short* __restrict__ xp) {
    int lin4 = blockIdx.x * 256 + threadIdx.x;
    long e0 = (long)lin4 * 4;
    int col = (int)(e0 & 511), row = (int)((e0 >> 9) & 511);
    int bc = (int)(e0 >> 18);
    int b = bc / 3, c = bc - b * 3;
    float4 v = *(const float4*)(x + e0);
    int gh = row >> 4, p = row & 15, gw = col >> 4, q = col & 15;
    size_t off = ((size_t)((b << 10) + (gh << 5) + gw)) * 768 + c * 256 + p * 16 + q;
    ushort4 o;
    unsigned short h, l;
    split_bf16(v.x, h, l); o.x = LO ? l : h;
    split_bf16(v.y, h, l); o.y = LO ? l : h;
    split_bf16(v.z, h, l); o.z = LO ? l : h;
    split_bf16(v.w, h, l); o.w = LO ? l : h;
    *(ushort4*)(xp + off) = o;
}

// ---------------------------------------------------------------------------
// patch GEMM, 128x128 tile. MODE0: t = xh*(wh+wl) + cb + pos ; MODE1: t += xl*wh
template<int MODE>
__global__ __launch_bounds__(256) void gemm_patch(const unsigned short* __restrict__ A,
                                                  const unsigned short* __restrict__ Bh,
                                                  const unsigned short* __restrict__ Bl,
                                                  const float* __restrict__ cb, const float* __restrict__ pos,
                                                  float* __restrict__ t) {
    __shared__ __align__(16) unsigned short sA[8192], sBh[8192], sBl[8192];
    int m0 = blockIdx.x * 128, n0 = blockIdx.y * 128;
    int tid = threadIdx.x, lane = tid & 63, w = tid >> 6;
    int wr = (w >> 1) * 64, wc = (w & 1) * 64;
    f32x4 z = {0.f, 0.f, 0.f, 0.f};
    f32x4 acc[4][4] = {{z, z, z, z}, {z, z, z, z}, {z, z, z, z}, {z, z, z, z}};
    for (int k0 = 0; k0 < 768; k0 += 64) {
        a_stage128(sA, A + (size_t)m0 * 768 + k0, 768, tid, 127);
        a_stage128(sBh, Bh + (size_t)n0 * 768 + k0, 768, tid, 127);
        if (MODE == 0) a_stage128(sBl, Bl + (size_t)n0 * 768 + k0, 768, tid, 127);
        __syncthreads();
#pragma unroll
        for (int kc = 0; kc < 2; kc++) {
            int q = (lane >> 4) + kc * 4;
            short8 a8[4], bh8[4], bl8[4];
#pragma unroll
            for (int i = 0; i < 4; i++) {
                a8[i] = ld8(sA, wr + i * 16 + (lane & 15), q, 7);
                bh8[i] = ld8(sBh, wc + i * 16 + (lane & 15), q, 7);
                if (MODE == 0) bl8[i] = ld8(sBl, wc + i * 16 + (lane & 15), q, 7);
            }
#pragma unroll
            for (int i = 0; i < 4; i++)
#pragma unroll
                for (int j = 0; j < 4; j++) {
                    MFMA16(acc[i][j], a8[i], bh8[j]);
                    if (MODE == 0) MFMA16(acc[i][j], a8[i], bl8[j]);
                }
        }
        __syncthreads();
    }
    int q4 = (lane >> 4) * 4;
#pragma unroll
    for (int i = 0; i < 4; i++) {
        int r = m0 + wr + i * 16 + q4;
#pragma unroll
        for (int j = 0; j < 4; j++) {
            int c = n0 + wc + j * 16 + (lane & 15);
#pragma unroll
            for (int g = 0; g < 4; g++) {
                int rr = r + g;
                int b = rr >> 10, p = rr & 1023;
                size_t dst = ((size_t)b * NTOK + 1 + p) * 256 + c;
                if (MODE == 0)
                    t[dst] = acc[i][j][g] + cb[c] + pos[(size_t)(1 + p) * 256 + c];
                else
                    t[dst] += acc[i][j][g];
            }
        }
    }
}

// ---------------------------------------------------------------------------
// LN rows n' and 1025-n', emit Yh+ = hA+hB, Yh- = hA-hB as bf16 hi/lo.
__global__ __launch_bounds__(256) void ln1fold(const float* __restrict__ t,
                                               const float* __restrict__ s, const float* __restrict__ bb,
                                               unsigned short* __restrict__ Yph, unsigned short* __restrict__ Ypl,
                                               unsigned short* __restrict__ Ymh, unsigned short* __restrict__ Yml) {
    int tid = threadIdx.x, lane = tid & 63, w = tid >> 6;
    int b = blockIdx.y;
    int np = blockIdx.x * 4 + w;
    size_t ybase = ((size_t)b * KF + np) * 256 + lane * 4;
    if (np >= 513) {
        ushort4 z = make_ushort4(0, 0, 0, 0);
        *(ushort4*)(Yph + ybase) = z; *(ushort4*)(Ypl + ybase) = z;
        *(ushort4*)(Ymh + ybase) = z; *(ushort4*)(Yml + ybase) = z;
        return;
    }
    const float* tb = t + (size_t)b * NTOK * DIM;
    float4 va = *(const float4*)(tb + (size_t)np * 256 + lane * 4);
    float sa = wave_sum(va.x + va.y + va.z + va.w) * (1.f / 256.f);
    float dax = va.x - sa, day = va.y - sa, daz = va.z - sa, daw = va.w - sa;
    float qa = wave_sum(dax * dax + day * day + daz * daz + daw * daw);
    float ra = rsqrtf(qa * (1.f / 256.f) + LN_EPS);
    float4 s4 = *(const float4*)(s + lane * 4);
    float4 b4 = *(const float4*)(bb + lane * 4);
    float hax = dax * ra * s4.x + b4.x, hay = day * ra * s4.y + b4.y;
    float haz = daz * ra * s4.z + b4.z, haw = daw * ra * s4.w + b4.w;
    float hbx = 0.f, hby = 0.f, hbz = 0.f, hbw = 0.f;
    if (np >= 1) {
        float4 vb = *(const float4*)(tb + (size_t)(NTOK - np) * 256 + lane * 4);
        float sb = wave_sum(vb.x + vb.y + vb.z + vb.w) * (1.f / 256.f);
        float dbx = vb.x - sb, dby = vb.y - sb, dbz = vb.z - sb, dbw = vb.w - sb;
        float qb = wave_sum(dbx * dbx + dby * dby + dbz * dbz + dbw * dbw);
        float rb = rsqrtf(qb * (1.f / 256.f) + LN_EPS);
        hbx = dbx * rb * s4.x + b4.x; hby = dby * rb * s4.y + b4.y;
        hbz = dbz * rb * s4.z + b4.z; hbw = dbw * rb * s4.w + b4.w;
    }
    ushort4 ph, pl, mh, ml;
    split_bf16(hax + hbx, ph.x, pl.x); split_bf16(hay + hby, ph.y, pl.y);
    split_bf16(haz + hbz, ph.z, pl.z); split_bf16(haw + hbw, ph.w, pl.w);
    split_bf16(hax - hbx, mh.x, ml.x); split_bf16(hay - hby, mh.y, ml.y);
    split_bf16(haz - hbz, mh.z, ml.z); split_bf16(haw - hbw, mh.w, ml.w);
    *(ushort4*)(Yph + ybase) = ph; *(ushort4*)(Ypl + ybase) = pl;
    *(ushort4*)(Ymh + ybase) = mh; *(ushort4*)(Yml + ybase) = ml;
}

// ---------------------------------------------------------------------------
__global__ __launch_bounds__(256) void ln2_bf16(const float* __restrict__ t, unsigned short* __restrict__ hh,
                                                const float* __restrict__ s, const float* __restrict__ bb) {
    int wave = threadIdx.x >> 6, lane = threadIdx.x & 63;
    int m = blockIdx.x * 4 + wave;
    const float* row = t + (size_t)m * DIM;
    float4 v = *(const float4*)(row + lane * 4);
    float mean = wave_sum(v.x + v.y + v.z + v.w) * (1.f / 256.f);
    float dx = v.x - mean, dy = v.y - mean, dz = v.z - mean, dw = v.w - mean;
    float sq = wave_sum(dx * dx + dy * dy + dz * dz + dw * dw);
    float rstd = rsqrtf(sq * (1.f / 256.f) + LN_EPS);
    float4 s4 = *(const float4*)(s + lane * 4);
    float4 b4 = *(const float4*)(bb + lane * 4);
    ushort4 o;
    o.x = rne_bf16(dx * rstd * s4.x + b4.x);
    o.y = rne_bf16(dy * rstd * s4.y + b4.y);
    o.z = rne_bf16(dz * rstd * s4.z + b4.z);
    o.w = rne_bf16(dw * rstd * s4.w + b4.w);
    *(ushort4*)(hh + (size_t)m * DIM + lane * 4) = o;
}

// ---------------------------------------------------------------------------
// Split-bf16 GEMM (3-pass), A[M][256], B[n][256], transposed+split output
// O[b][c:192][kp:576] hi/lo. grid(576,3). 64x64 tile, async staging.
__global__ __launch_bounds__(256) void gemm_splitT(
    const unsigned short* __restrict__ Ahi, const unsigned short* __restrict__ Alo,
    const unsigned short* __restrict__ Bhi, const unsigned short* __restrict__ Blo,
    unsigned short* __restrict__ Ohi, unsigned short* __restrict__ Olo) {
    __shared__ __align__(16) unsigned short sAh[4096], sAl[4096], sBh[4096], sBl[4096];
    int m0 = blockIdx.x * 64, n0 = blockIdx.y * 64;
    int tid = threadIdx.x, lane = tid & 63, w = tid >> 6;
    int wr = (w >> 1) * 32, wc = (w & 1) * 32;
    f32x4 z = {0.f, 0.f, 0.f, 0.f};
    f32x4 acc[2][2] = {{z, z}, {z, z}};
    for (int k0 = 0; k0 < 256; k0 += 64) {
        a_stage64(sAh, Ahi + (size_t)m0 * 256 + k0, 256, tid);
        a_stage64(sAl, Alo + (size_t)m0 * 256 + k0, 256, tid);
        a_stage64(sBh, Bhi + (size_t)n0 * 256 + k0, 256, tid);
        a_stage64(sBl, Blo + (size_t)n0 * 256 + k0, 256, tid);
        __syncthreads();
#pragma unroll
        for (int kc = 0; kc < 2; kc++) {
            int q = (lane >> 4) + kc * 4;
            short8 ah[2], al[2], bh[2], bl[2];
#pragma unroll
            for (int i = 0; i < 2; i++) {
                int r1 = wr + i * 16 + (lane & 15);
                ah[i] = ld8(sAh, r1, q, 7); al[i] = ld8(sAl, r1, q, 7);
                int r2 = wc + i * 16 + (lane & 15);
                bh[i] = ld8(sBh, r2, q, 7); bl[i] = ld8(sBl, r2, q, 7);
            }
#pragma unroll
            for (int i = 0; i < 2; i++)
#pragma unroll
                for (int j = 0; j < 2; j++) {
                    MFMA16(acc[i][j], ah[i], bh[j]);
                    MFMA16(acc[i][j], ah[i], bl[j]);
                    MFMA16(acc[i][j], al[i], bh[j]);
                }
        }
        __syncthreads();
    }
    int q4 = (lane >> 4) * 4;
#pragma unroll
    for (int i = 0; i < 2; i++) {
        int r = m0 + wr + i * 16 + q4;
        int bidx = r / KF, kp = r - bidx * KF;
#pragma unroll
        for (int j = 0; j < 2; j++) {
            int c = n0 + wc + j * 16 + (lane & 15);
            ushort4 oh, ol;
            split_bf16(acc[i][j][0], oh.x, ol.x);
            split_bf16(acc[i][j][1], oh.y, ol.y);
            split_bf16(acc[i][j][2], oh.z, ol.z);
            split_bf16(acc[i][j][3], oh.w, ol.w);
            size_t off = ((size_t)bidx * MF + c) * KF + kp;
            *(ushort4*)(Ohi + off) = oh;
            *(ushort4*)(Olo + off) = ol;
        }
    }
}

// ---------------------------------------------------------------------------
// Dual split GEMM + butterfly, 64x64 tile, async staging. grid(9,3,64).
__global__ __launch_bounds__(256) void fft_big_dual(
    const unsigned short* __restrict__ C1h, const unsigned short* __restrict__ C1l,
    const unsigned short* __restrict__ S1h, const unsigned short* __restrict__ S1l,
    const unsigned short* __restrict__ Ych, const unsigned short* __restrict__ Ycl,
    const unsigned short* __restrict__ Ysh, const unsigned short* __restrict__ Ysl,
    float* __restrict__ t) {
    __shared__ __align__(16) unsigned short sC1h[2048], sC1l[2048], sS1h[2048], sS1l[2048];
    __shared__ __align__(16) unsigned short sYch[2048], sYcl[2048], sYsh[2048], sYsl[2048];
    int k0m = blockIdx.x * 64, n0 = blockIdx.y * 64, b = blockIdx.z;
    int tid = threadIdx.x, lane = tid & 63, w = tid >> 6;
    int wr = (w >> 1) * 32, wc = (w & 1) * 32;
    const unsigned short* ych = Ych + (size_t)b * MF * KF;
    const unsigned short* ycl = Ycl + (size_t)b * MF * KF;
    const unsigned short* ysh = Ysh + (size_t)b * MF * KF;
    const unsigned short* ysl = Ysl + (size_t)b * MF * KF;
    f32x4 z = {0.f, 0.f, 0.f, 0.f};
    f32x4 U[2][2] = {{z, z}, {z, z}}, V[2][2] = {{z, z}, {z, z}};
    for (int kk0 = 0; kk0 < KF; kk0 += 32) {
        a_stage32(sC1h, C1h + (size_t)k0m * KF + kk0, KF, tid);
        a_stage32(sC1l, C1l + (size_t)k0m * KF + kk0, KF, tid);
        a_stage32(sS1h, S1h + (size_t)k0m * KF + kk0, KF, tid);
        a_stage32(sS1l, S1l + (size_t)k0m * KF + kk0, KF, tid);
        a_stage32(sYch, ych + (size_t)n0 * KF + kk0, KF, tid);
        a_stage32(sYcl, ycl + (size_t)n0 * KF + kk0, KF, tid);
        a_stage32(sYsh, ysh + (size_t)n0 * KF + kk0, KF, tid);
        a_stage32(sYsl, ysl + (size_t)n0 * KF + kk0, KF, tid);
        __syncthreads();
        int q = lane >> 4;
        short8 c1h[2], c1l[2], s1h[2], s1l[2], ych8[2], ycl8[2], ysh8[2], ysl8[2];
#pragma unroll
        for (int i = 0; i < 2; i++) {
            int r1 = wr + i * 16 + (lane & 15);
            c1h[i] = ld8(sC1h, r1, q, 3); c1l[i] = ld8(sC1l, r1, q, 3);
            s1h[i] = ld8(sS1h, r1, q, 3); s1l[i] = ld8(sS1l, r1, q, 3);
            int r2 = wc + i * 16 + (lane & 15);
            ych8[i] = ld8(sYch, r2, q, 3); ycl8[i] = ld8(sYcl, r2, q, 3);
            ysh8[i] = ld8(sYsh, r2, q, 3); ysl8[i] = ld8(sYsl, r2, q, 3);
        }
#pragma unroll
        for (int i = 0; i < 2; i++)
#pragma unroll
            for (int j = 0; j < 2; j++) {
                MFMA16(U[i][j], c1h[i], ych8[j]);
                MFMA16(U[i][j], c1h[i], ycl8[j]);
                MFMA16(U[i][j], c1l[i], ych8[j]);
                MFMA16(V[i][j], s1h[i], ysh8[j]);
                MFMA16(V[i][j], s1h[i], ysl8[j]);
                MFMA16(V[i][j], s1l[i], ysh8[j]);
            }
        __syncthreads();
    }
    float* tb = t + (size_t)b * NTOK * DIM;
    int q4 = (lane >> 4) * 4;
#pragma unroll
    for (int i = 0; i < 2; i++) {
        int kk = k0m + wr + i * 16 + q4;
#pragma unroll
        for (int j = 0; j < 2; j++) {
            int mm = n0 + wc + j * 16 + (lane & 15);
            if (mm > 128) continue;
#pragma unroll
            for (int g = 0; g < 4; g++) {
                int k = kk + g;
                if (k > 512) continue;
                float u = U[i][j][g], v = V[i][j][g];
                tb[(size_t)k * 256 + mm] += u - v;
                if (mm >= 1 && mm <= 127) tb[(size_t)k * 256 + 256 - mm] += u + v;
                if (k >= 1) {
                    tb[(size_t)(NTOK - k) * 256 + mm] += u + v;
                    if (mm >= 1 && mm <= 127) tb[(size_t)(NTOK - k) * 256 + 256 - mm] += u - v;
                }
            }
        }
    }
}

// ---------------------------------------------------------------------------
// FFN1: Hid = leaky(h @ w1 + b1). 128x128 tile, grid(513,8). A:[65600][256], B:[1024][256].
__global__ __launch_bounds__(256) void gemm_ffn1(
    const unsigned short* __restrict__ A, const unsigned short* __restrict__ Bt,
    const float* __restrict__ b1, unsigned short* __restrict__ Hid) {
    __shared__ __align__(16) unsigned short sA[8192], sB[8192];
    int m0 = blockIdx.x * 128, n0 = blockIdx.y * 128;
    int tid = threadIdx.x, lane = tid & 63, w = tid >> 6;
    int wr = (w >> 1) * 64, wc = (w & 1) * 64;
    int maxrow = MROWS - 1 - m0; if (maxrow > 127) maxrow = 127;
    f32x4 z = {0.f, 0.f, 0.f, 0.f};
    f32x4 acc[4][4] = {{z, z, z, z}, {z, z, z, z}, {z, z, z, z}, {z, z, z, z}};
    for (int k0 = 0; k0 < 256; k0 += 64) {
        a_stage128(sA, A + (size_t)m0 * 256 + k0, 256, tid, maxrow);
        a_stage128(sB, Bt + (size_t)n0 * 256 + k0, 256, tid, 127);
        __syncthreads();
#pragma unroll
        for (int kc = 0; kc < 2; kc++) {
            int q = (lane >> 4) + kc * 4;
            short8 a8[4], b8[4];
#pragma unroll
            for (int i = 0; i < 4; i++) {
                a8[i] = ld8(sA, wr + i * 16 + (lane & 15), q, 7);
                b8[i] = ld8(sB, wc + i * 16 + (lane & 15), q, 7);
            }
#pragma unroll
            for (int i = 0; i < 4; i++)
#pragma unroll
                for (int j = 0; j < 4; j++) MFMA16(acc[i][j], a8[i], b8[j]);
        }
        __syncthreads();
    }
    int q4 = (lane >> 4) * 4;
#pragma unroll
    for (int i = 0; i < 4; i++) {
        int r = m0 + wr + i * 16 + q4;
#pragma unroll
        for (int j = 0; j < 4; j++) {
            int c = n0 + wc + j * 16 + (lane & 15);
            float bv = b1[c];
#pragma unroll
            for (int g = 0; g < 4; g++) {
                int rr = r + g;
                if (rr < MROWS) {
                    float val = acc[i][j][g] + bv;
                    val = val > 0.f ? val : 0.01f * val;
                    Hid[(size_t)rr * 1024 + c] = rne_bf16(val);
                }
            }
        }
    }
}

// ---------------------------------------------------------------------------
// FFN2: t += Hid @ w2 + b2. 128x128 tile, grid(513,2). A:[65600][1024], B:[256][1024].
__global__ __launch_bounds__(256) void gemm_ffn2(
    const unsigned short* __restrict__ A, const unsigned short* __restrict__ Bt,
    const float* __restrict__ b2, float* __restrict__ t) {
    __shared__ __align__(16) unsigned short sA[8192], sB[8192];
    int m0 = blockIdx.x * 128, n0 = blockIdx.y * 128;
    int tid = threadIdx.x, lane = tid & 63, w = tid >> 6;
    int wr = (w >> 1) * 64, wc = (w & 1) * 64;
    int maxrow = MROWS - 1 - m0; if (maxrow > 127) maxrow = 127;
    f32x4 z = {0.f, 0.f, 0.f, 0.f};
    f32x4 acc[4][4] = {{z, z, z, z}, {z, z, z, z}, {z, z, z, z}, {z, z, z, z}};
    for (int k0 = 0; k0 < 1024; k0 += 64) {
        a_stage128(sA, A + (size_t)m0 * 1024 + k0, 1024, tid, maxrow);
        a_stage128(sB, Bt + (size_t)n0 * 1024 + k0, 1024, tid, 127);
        __syncthreads();
#pragma unroll
        for (int kc = 0; kc < 2; kc++) {
            int q = (lane >> 4) + kc * 4;
            short8 a8[4], b8[4];
#pragma unroll
            for (int i = 0; i < 4; i++) {
                a8[i] = ld8(sA, wr + i * 16 + (lane & 15), q, 7);
                b8[i] = ld8(sB, wc + i * 16 + (lane & 15), q, 7);
            }
#pragma unroll
            for (int i = 0; i < 4; i++)
#pragma unroll
                for (int j = 0; j < 4; j++) MFMA16(acc[i][j], a8[i], b8[j]);
        }
        __syncthreads();
    }
    int q4 = (lane >> 4) * 4;
#pragma unroll
    for (int i = 0; i < 4; i++) {
        int r = m0 + wr + i * 16 + q4;
#pragma unroll
        for (int j = 0; j < 4; j++) {
            int c = n0 + wc + j * 16 + (lane & 15);
            float bv = b2[c];
#pragma unroll
            for (int g = 0; g < 4; g++) {
                int rr = r + g;
                if (rr < MROWS) t[(size_t)rr * 256 + c] += acc[i][j][g] + bv;
            }
        }
    }
}

// ---------------------------------------------------------------------------
__global__ __launch_bounds__(256) void head_kernel(const float* __restrict__ t,
                                                   const float* __restrict__ hs, const float* __restrict__ hb,
                                                   const float* __restrict__ hw, const float* __restrict__ hbias,
                                                   float* __restrict__ out) {
    __shared__ float red[256];
    __shared__ float lnv[256];
    int b = blockIdx.x, tid = threadIdx.x;
    const float* tb = t + (size_t)b * NTOK * DIM;
    float s = 0.f;
    for (int m = 0; m < NTOK; m++) s += tb[m * DIM + tid];
    s *= (1.f / 1025.f);
    red[tid] = s;
    __syncthreads();
    for (int off = 128; off; off >>= 1) {
        if (tid < off) red[tid] += red[tid + off];
        __syncthreads();
    }
    float mean = red[0] * (1.f / 256.f);
    __syncthreads();
    float d = s - mean;
    red[tid] = d * d;
    __syncthreads();
    for (int off = 128; off; off >>= 1) {
        if (tid < off) red[tid] += red[tid + off];
        __syncthreads();
    }
    float rstd = rsqrtf(red[0] * (1.f / 256.f) + LN_EPS);
    __syncthreads();
    lnv[tid] = d * rstd * hs[tid] + hb[tid];
    __syncthreads();
    float lo[4];
#pragma unroll
    for (int jj = 0; jj < 4; jj++) {
        int n = tid + jj * 256;
        float a = -1e30f;
        if (n < NCLS) {
            a = hbias[n];
            for (int dd = 0; dd < DIM; dd++) a += lnv[dd] * hw[dd * NCLS + n];
        }
        lo[jj] = a;
    }
    float mx = fmaxf(fmaxf(lo[0], lo[1]), fmaxf(lo[2], lo[3]));
    red[tid] = mx;
    __syncthreads();
    for (int off = 128; off; off >>= 1) {
        if (tid < off) red[tid] = fmaxf(red[tid], red[tid + off]);
        __syncthreads();
    }
    float gmax = red[0];
    __syncthreads();
    float ev[4];
    float es = 0.f;
#pragma unroll
    for (int jj = 0; jj < 4; jj++) {
        int n = tid + jj * 256;
        ev[jj] = 0.f;
        if (n < NCLS) {
            ev[jj] = expf(lo[jj] - gmax);
            es += ev[jj];
        }
    }
    red[tid] = es;
    __syncthreads();
    for (int off = 128; off; off >>= 1) {
        if (tid < off) red[tid] += red[tid + off];
        __syncthreads();
    }
    float inv = 1.f / red[0];
#pragma unroll
    for (int jj = 0; jj < 4; jj++) {
        int n = tid + jj * 256;
        if (n < NCLS) out[(size_t)b * NCLS + n] = ev[jj] * inv;
    }
}

// ---------------------------------------------------------------------------
extern "C" void kernel_launch(void* const* d_in, const int* in_sizes, int n_in,
                              void* d_out, int out_size, void* d_ws, size_t ws_size,
                              hipStream_t stream) {
    const float* x      = (const float*)d_in[0];
    const float* conv_w = (const float*)d_in[1];
    const float* conv_b = (const float*)d_in[2];
    const float* pos    = (const float*)d_in[3];
    const float* cls    = (const float*)d_in[4];
    const float* ln1_s  = (const float*)d_in[5];
    const float* ln1_b  = (const float*)d_in[6];
    const float* ln2_s  = (const float*)d_in[7];
    const float* ln2_b  = (const float*)d_in[8];
    const float* w1     = (const float*)d_in[9];
    const float* b1     = (const float*)d_in[10];
    const float* w2     = (const float*)d_in[11];
    const float* b2     = (const float*)d_in[12];
    const float* hls    = (const float*)d_in[13];
    const float* hlb    = (const float*)d_in[14];
    const float* hw     = (const float*)d_in[15];
    const float* hbias  = (const float*)d_in[16];
    float* out = (float*)d_out;
    char* W = (char*)d_ws;

    // layout (bytes), pool is time-multiplexed:
    //   t:    [0, 67174400)
    //   pool: [67174400, 235110400)  size 167,936,000
    //     xp   @ pool+0        (100,663,296)      — patch phase
    //     Yp   @ pool+0        (75,497,472)       — layer phase A
    //     Yct  @ pool+75497472 (56,623,104)       — layer phase A
    //     Hid  @ pool+0        (134,348,800)      — layer phase B
    //     hh   @ pool+134348800 (33,587,200)      — disjoint from Yp/Yct/Hid
    //   C1 grp @ 235110400 (4x663552) | C2 grp @ 237764608 (4x131072)
    //   w1t @ 238288896 | w2t @ 241434624 | wp @ 244580352 (hi), 244973568 (lo)
    float*          t    = (float*)(W + 0ULL);
    char*           pool = W + 67174400ULL;
    unsigned short* xp   = (unsigned short*)(pool);
    unsigned short* Yph  = (unsigned short*)(pool);
    unsigned short* Ypl  = (unsigned short*)(pool + 18874368ULL);
    unsigned short* Ymh  = (unsigned short*)(pool + 2 * 18874368ULL);
    unsigned short* Yml  = (unsigned short*)(pool + 3 * 18874368ULL);
    unsigned short* Ycth = (unsigned short*)(pool + 75497472ULL);
    unsigned short* Yctl = (unsigned short*)(pool + 75497472ULL + 14155776ULL);
    unsigned short* Ysth = (unsigned short*)(pool + 75497472ULL + 2 * 14155776ULL);
    unsigned short* Ystl = (unsigned short*)(pool + 75497472ULL + 3 * 14155776ULL);
    unsigned short* Hid  = (unsigned short*)(pool);
    unsigned short* hh   = (unsigned short*)(pool + 134348800ULL);
    unsigned short* C1h  = (unsigned short*)(W + 235110400ULL);
    unsigned short* C1l  = (unsigned short*)(W + 235110400ULL + 663552ULL);
    unsigned short* S1h  = (unsigned short*)(W + 235110400ULL + 2 * 663552ULL);
    unsigned short* S1l  = (unsigned short*)(W + 235110400ULL + 3 * 663552ULL);
    unsigned short* C2h  = (unsigned short*)(W + 237764608ULL);
    unsigned short* C2l  = (unsigned short*)(W + 237764608ULL + 131072ULL);
    unsigned short* S2h  = (unsigned short*)(W + 237764608ULL + 2 * 131072ULL);
    unsigned short* S2l  = (unsigned short*)(W + 237764608ULL + 3 * 131072ULL);
    unsigned short* w1t  = (unsigned short*)(W + 238288896ULL);
    unsigned short* w2t  = (unsigned short*)(W + 241434624ULL);
    unsigned short* wph  = (unsigned short*)(W + 244580352ULL);
    unsigned short* wpl  = (unsigned short*)(W + 244973568ULL);

    gen_dft2<<<dim3(1296), dim3(256), 0, stream>>>(C1h, C1l, S1h, S1l, C2h, C2l, S2h, S2l);
    conv_wp<<<dim3(768), dim3(256), 0, stream>>>(conv_w, wph, wpl);
    conv_w1t<<<dim3(6144), dim3(256), 0, stream>>>(w1, w1t);
    conv_w2t<<<dim3(6144), dim3(256), 0, stream>>>(w2, w2t);
    cls_init<<<dim3(BATCH), dim3(256), 0, stream>>>(cls, pos, t);

    // patch embed: two split passes (xp buffer reused for hi then lo)
    repack_x<0><<<dim3(49152), dim3(256), 0, stream>>>(x, xp);
    gemm_patch<0><<<dim3(512, 2), dim3(256), 0, stream>>>(xp, wph, wpl, conv_b, pos, t);
    repack_x<1><<<dim3(49152), dim3(256), 0, stream>>>(x, xp);
    gemm_patch<1><<<dim3(512, 2), dim3(256), 0, stream>>>(xp, wph, wpl, conv_b, pos, t);

    for (int l = 0; l < NLAYER; l++) {
        ln1fold<<<dim3(144, BATCH), dim3(256), 0, stream>>>(
            t, ln1_s + l * DIM, ln1_b + l * DIM, Yph, Ypl, Ymh, Yml);
        gemm_splitT<<<dim3(576, 3), dim3(256), 0, stream>>>(Yph, Ypl, C2h, C2l, Ycth, Yctl);
        gemm_splitT<<<dim3(576, 3), dim3(256), 0, stream>>>(Ymh, Yml, S2h, S2l, Ysth, Ystl);
        fft_big_dual<<<dim3(9, 3, BATCH), dim3(256), 0, stream>>>(
            C1h, C1l, S1h, S1l, Ycth, Yctl, Ysth, Ystl, t);
        ln2_bf16<<<dim3(16400), dim3(256), 0, stream>>>(t, hh, ln2_s + l * DIM, ln2_b + l * DIM);
        gemm_ffn1<<<dim3(513, 8), dim3(256), 0, stream>>>(
            hh, w1t + (size_t)l * 262144, b1 + (size_t)l * HID, Hid);
        gemm_ffn2<<<dim3(513, 2), dim3(256), 0, stream>>>(
            Hid, w2t + (size_t)l * 262144, b2 + (size_t)l * DIM, t);
    }
    head_kernel<<<dim3(BATCH), dim3(256), 0, stream>>>(t, hls, hlb, hw, hbias, out);
}

// Round 4
// 3239.388 us; speedup vs baseline: 6.8743x; 1.0810x over previous
//
#include <hip/hip_runtime.h>
#include <math.h>

#define BATCH 64
#define CIN 3
#define IMH 512
#define IMW 512
#define PSZ 16
#define DIM 256
#define GHN 32
#define GWN 32
#define NTOK 1025
#define HID 1024
#define NLAYER 6
#define NCLS 1000
#define LN_EPS 1e-5f

// folded dims: token-fold 513 -> pad 576 ; dim-fold 129 -> pad 144
#define KF 576
#define KR 640           // A rows padded for 128-row tiles (5 x 128)
#define MF 144
#define NFLAT 9216       // 64 * MF
#define MROWS 65600      // 64*1025

typedef __attribute__((ext_vector_type(8))) short short8;
typedef __attribute__((ext_vector_type(4))) float f32x4;

#define MFMA16(acc, a, b) acc = __builtin_amdgcn_mfma_f32_16x16x32_bf16(a, b, acc, 0, 0, 0)

// ---------------------------------------------------------------------------
__device__ inline unsigned short rne_bf16(float x) {
    unsigned u = __float_as_uint(x);
    return (unsigned short)((u + 0x7FFF + ((u >> 16) & 1)) >> 16);
}
__device__ inline void split_bf16(float x, unsigned short& hi, unsigned short& lo) {
    unsigned short h = rne_bf16(x);
    hi = h;
    float hf = __uint_as_float((unsigned)h << 16);
    lo = rne_bf16(x - hf);
}
__device__ inline float wave_sum(float v) {
#pragma unroll
    for (int off = 32; off; off >>= 1) v += __shfl_xor(v, off);
    return v;
}
// 64-wide tiles (8 granules/row): perm = g ^ (row&7)  -> 2-way banks (free)
__device__ inline short8 ld8x64(const unsigned short* lds, int row, int q) {
    return *(const short8*)(lds + (row * 8 + (q ^ (row & 7))) * 8);
}
// 32-wide tiles (4 granules/row): perm = g ^ ((row>>1)&3) -> 2-way banks (free)
__device__ inline short8 ld8x32(const unsigned short* lds, int row, int q) {
    return *(const short8*)(lds + (row * 4 + (q ^ ((row >> 1) & 3))) * 8);
}
// async global->LDS 16B (lds arg wave-uniform; HW adds lane*16)
__device__ inline void gl2lds16(const unsigned short* g, unsigned short* l) {
    __builtin_amdgcn_global_load_lds((const __attribute__((address_space(1))) unsigned int*)g,
                                     (__attribute__((address_space(3))) unsigned int*)l, 16, 0, 0);
}
// stage 128 rows x 64 bf16 (mask-7 swizzle); row clamped for M-tail
__device__ inline void a_stage128(unsigned short* lds, const unsigned short* g, int lda, int tid, int maxrow) {
    int lane = tid & 63, w = tid >> 6;
#pragma unroll
    for (int s = 0; s < 4; s++) {
        int slot = w * 256 + s * 64;
        int sl = slot + lane;
        int row = sl >> 3, gc = (sl & 7) ^ (row & 7);
        if (row > maxrow) row = maxrow;
        gl2lds16(g + (size_t)row * lda + gc * 8, lds + slot * 8);
    }
}
// stage 128 rows x 32 bf16 (mask-3 shifted swizzle)
__device__ inline void a_stage128x32(unsigned short* lds, const unsigned short* g, int lda, int tid) {
    int lane = tid & 63, w = tid >> 6;
#pragma unroll
    for (int s = 0; s < 2; s++) {
        int slot = s * 256 + w * 64;
        int sl = slot + lane;
        int row = sl >> 2, gc = (sl & 3) ^ ((row >> 1) & 3);
        gl2lds16(g + (size_t)row * lda + gc * 8, lds + slot * 8);
    }
}
// stage 64 rows x 32 bf16
__device__ inline void a_stage64x32(unsigned short* lds, const unsigned short* g, int lda, int tid) {
    int lane = tid & 63, w = tid >> 6;
    int slot = w * 64;
    int sl = slot + lane;
    int row = sl >> 2, gc = (sl & 3) ^ ((row >> 1) & 3);
    gl2lds16(g + (size_t)row * lda + gc * 8, lds + slot * 8);
}
// stage 144 rows x 32 bf16 (576 slots: 2 full passes + wave0 partial)
__device__ inline void a_stage144x32(unsigned short* lds, const unsigned short* g, int lda, int tid) {
    int lane = tid & 63, w = tid >> 6;
#pragma unroll
    for (int s = 0; s < 2; s++) {
        int slot = s * 256 + w * 64;
        int sl = slot + lane;
        int row = sl >> 2, gc = (sl & 3) ^ ((row >> 1) & 3);
        gl2lds16(g + (size_t)row * lda + gc * 8, lds + slot * 8);
    }
    if (w == 0) {
        int slot = 512;
        int sl = slot + lane;
        int row = sl >> 2, gc = (sl & 3) ^ ((row >> 1) & 3);
        gl2lds16(g + (size_t)row * lda + gc * 8, lds + slot * 8);
    }
}

// ---------------------------------------------------------------------------
// DFT matrices bf16 hi/lo. C1/S1: [640][576] zero-padded past 512 (rows & cols).
__global__ __launch_bounds__(256) void gen_dft2(unsigned short* C1h, unsigned short* C1l,
                                                unsigned short* S1h, unsigned short* S1l,
                                                unsigned short* C2h, unsigned short* C2l,
                                                unsigned short* S2h, unsigned short* S2l) {
    int idx = blockIdx.x * 256 + threadIdx.x;
    if (idx < KR * KF) {
        int k = idx / KF, n = idx - k * KF;
        float c = 0.f, s = 0.f;
        if (k <= 512 && n <= 512) {
            int r = (k * n) % 1025;
            double ang = 6.283185307179586476925287 * (double)r / 1025.0;
            c = (float)cos(ang); s = (float)sin(ang);
        }
        unsigned short h, l;
        split_bf16(c, h, l); C1h[idx] = h; C1l[idx] = l;
        split_bf16(s, h, l); S1h[idx] = h; S1l[idx] = l;
    }
    if (idx < 256 * 256) {
        int k = idx >> 8, n = idx & 255;
        int r = (k * n) & 255;
        double ang = 6.283185307179586476925287 * (double)r / 256.0;
        float c = (float)cos(ang), s = (float)sin(ang);
        unsigned short h, l;
        split_bf16(c, h, l); C2h[idx] = h; C2l[idx] = l;
        split_bf16(s, h, l); S2h[idx] = h; S2l[idx] = l;
    }
}

// wp hi/lo: conv_w already [d=256][k=768], k = c*256+p*16+q
__global__ __launch_bounds__(256) void conv_wp(const float* __restrict__ w,
                                               unsigned short* __restrict__ wph, unsigned short* __restrict__ wpl) {
    int idx = blockIdx.x * 256 + threadIdx.x;
    unsigned short h, l;
    split_bf16(w[idx], h, l);
    wph[idx] = h; wpl[idx] = l;
}
__global__ __launch_bounds__(256) void conv_w1t(const float* __restrict__ w1, unsigned short* __restrict__ w1t) {
    int idx = blockIdx.x * 256 + threadIdx.x;
    int l = idx / 262144, rem = idx - l * 262144;
    int n = rem >> 8, k = rem & 255;
    w1t[idx] = rne_bf16(w1[(size_t)l * 262144 + (size_t)k * 1024 + n]);
}
__global__ __launch_bounds__(256) void conv_w2t(const float* __restrict__ w2, unsigned short* __restrict__ w2t) {
    int idx = blockIdx.x * 256 + threadIdx.x;
    int l = idx / 262144, rem = idx - l * 262144;
    int n = rem >> 10, k = rem & 1023;
    w2t[idx] = rne_bf16(w2[(size_t)l * 262144 + (size_t)k * 256 + n]);
}

// ---------------------------------------------------------------------------
__global__ __launch_bounds__(256) void cls_init(const float* __restrict__ cls, const float* __restrict__ pos,
                                                float* __restrict__ t) {
    int b = blockIdx.x, tid = threadIdx.x;
    t[(size_t)b * NTOK * DIM + tid] = cls[tid] + pos[tid];
}

// ---------------------------------------------------------------------------
// Fused patch embed: reads x directly, splits hi/lo in-register, 3-pass MFMA.
// M=65536 patches, N=256 dims, K=768. 128x128 tile, grid(512,2).
__global__ __launch_bounds__(256) void patch_fused(const float* __restrict__ x,
                                                   const unsigned short* __restrict__ wph,
                                                   const unsigned short* __restrict__ wpl,
                                                   const float* __restrict__ cb, const float* __restrict__ pos,
                                                   float* __restrict__ t) {
    __shared__ __align__(16) unsigned short sAh[8192], sAl[8192], sBh[8192], sBl[8192];
    int m0 = blockIdx.x * 128, n0 = blockIdx.y * 128;
    int tid = threadIdx.x, lane = tid & 63, w = tid >> 6;
    int wr = (w >> 1) * 64, wc = (w & 1) * 64;
    f32x4 z = {0.f, 0.f, 0.f, 0.f};
    f32x4 acc[4][4] = {{z, z, z, z}, {z, z, z, z}, {z, z, z, z}, {z, z, z, z}};
    for (int k0 = 0; k0 < 768; k0 += 64) {
        // A: 128 patches x 64 k-elems from x, converted to hi/lo
#pragma unroll
        for (int s = 0; s < 8; s++) {
            int lin = s * 1024 + tid * 4;
            int row = lin >> 6, kc = lin & 63;
            int m = m0 + row;
            int bb = m >> 10, gh = (m >> 5) & 31, gw = m & 31;
            int k = k0 + kc;
            int c = k >> 8, pp = (k >> 4) & 15, q = k & 15;
            const float* gp = x + (size_t)bb * 786432 + c * 262144 + gh * 8192 + pp * 512 + gw * 16 + q;
            float4 v = *(const float4*)gp;
            ushort4 oh, ol;
            split_bf16(v.x, oh.x, ol.x); split_bf16(v.y, oh.y, ol.y);
            split_bf16(v.z, oh.z, ol.z); split_bf16(v.w, oh.w, ol.w);
            int g = kc >> 3, half = (kc >> 2) & 1;
            int addr = (row * 8 + (g ^ (row & 7))) * 8 + half * 4;
            *(ushort4*)(sAh + addr) = oh;
            *(ushort4*)(sAl + addr) = ol;
        }
        a_stage128(sBh, wph + (size_t)n0 * 768 + k0, 768, tid, 127);
        a_stage128(sBl, wpl + (size_t)n0 * 768 + k0, 768, tid, 127);
        __syncthreads();
#pragma unroll
        for (int kc2 = 0; kc2 < 2; kc2++) {
            int q = (lane >> 4) + kc2 * 4;
            short8 ah[4], al[4], bh8[4], bl8[4];
#pragma unroll
            for (int i = 0; i < 4; i++) {
                ah[i] = ld8x64(sAh, wr + i * 16 + (lane & 15), q);
                al[i] = ld8x64(sAl, wr + i * 16 + (lane & 15), q);
                bh8[i] = ld8x64(sBh, wc + i * 16 + (lane & 15), q);
                bl8[i] = ld8x64(sBl, wc + i * 16 + (lane & 15), q);
            }
#pragma unroll
            for (int i = 0; i < 4; i++)
#pragma unroll
                for (int j = 0; j < 4; j++) {
                    MFMA16(acc[i][j], ah[i], bh8[j]);
                    MFMA16(acc[i][j], ah[i], bl8[j]);
                    MFMA16(acc[i][j], al[i], bh8[j]);
                }
        }
        __syncthreads();
    }
    int q4 = (lane >> 4) * 4;
#pragma unroll
    for (int i = 0; i < 4; i++) {
        int r = m0 + wr + i * 16 + q4;
#pragma unroll
        for (int j = 0; j < 4; j++) {
            int c = n0 + wc + j * 16 + (lane & 15);
#pragma unroll
            for (int g = 0; g < 4; g++) {
                int rr = r + g;
                int bb = rr >> 10, tok = 1 + (rr & 1023);
                t[((size_t)bb * NTOK + tok) * 256 + c] =
                    acc[i][j][g] + cb[c] + pos[(size_t)tok * 256 + c];
            }
        }
    }
}

// ---------------------------------------------------------------------------
// LN rows n' and 1025-n', emit Yh+ = hA+hB, Yh- = hA-hB as bf16 hi/lo.
__global__ __launch_bounds__(256) void ln1fold(const float* __restrict__ t,
                                               const float* __restrict__ s, const float* __restrict__ bb,
                                               unsigned short* __restrict__ Yph, unsigned short* __restrict__ Ypl,
                                               unsigned short* __restrict__ Ymh, unsigned short* __restrict__ Yml) {
    int tid = threadIdx.x, lane = tid & 63, w = tid >> 6;
    int b = blockIdx.y;
    int np = blockIdx.x * 4 + w;
    size_t ybase = ((size_t)b * KF + np) * 256 + lane * 4;
    if (np >= 513) {
        ushort4 z = make_ushort4(0, 0, 0, 0);
        *(ushort4*)(Yph + ybase) = z; *(ushort4*)(Ypl + ybase) = z;
        *(ushort4*)(Ymh + ybase) = z; *(ushort4*)(Yml + ybase) = z;
        return;
    }
    const float* tb = t + (size_t)b * NTOK * DIM;
    float4 va = *(const float4*)(tb + (size_t)np * 256 + lane * 4);
    float sa = wave_sum(va.x + va.y + va.z + va.w) * (1.f / 256.f);
    float dax = va.x - sa, day = va.y - sa, daz = va.z - sa, daw = va.w - sa;
    float qa = wave_sum(dax * dax + day * day + daz * daz + daw * daw);
    float ra = rsqrtf(qa * (1.f / 256.f) + LN_EPS);
    float4 s4 = *(const float4*)(s + lane * 4);
    float4 b4 = *(const float4*)(bb + lane * 4);
    float hax = dax * ra * s4.x + b4.x, hay = day * ra * s4.y + b4.y;
    float haz = daz * ra * s4.z + b4.z, haw = daw * ra * s4.w + b4.w;
    float hbx = 0.f, hby = 0.f, hbz = 0.f, hbw = 0.f;
    if (np >= 1) {
        float4 vb = *(const float4*)(tb + (size_t)(NTOK - np) * 256 + lane * 4);
        float sb = wave_sum(vb.x + vb.y + vb.z + vb.w) * (1.f / 256.f);
        float dbx = vb.x - sb, dby = vb.y - sb, dbz = vb.z - sb, dbw = vb.w - sb;
        float qb = wave_sum(dbx * dbx + dby * dby + dbz * dbz + dbw * dbw);
        float rb = rsqrtf(qb * (1.f / 256.f) + LN_EPS);
        hbx = dbx * rb * s4.x + b4.x; hby = dby * rb * s4.y + b4.y;
        hbz = dbz * rb * s4.z + b4.z; hbw = dbw * rb * s4.w + b4.w;
    }
    ushort4 ph, pl, mh, ml;
    split_bf16(hax + hbx, ph.x, pl.x); split_bf16(hay + hby, ph.y, pl.y);
    split_bf16(haz + hbz, ph.z, pl.z); split_bf16(haw + hbw, ph.w, pl.w);
    split_bf16(hax - hbx, mh.x, ml.x); split_bf16(hay - hby, mh.y, ml.y);
    split_bf16(haz - hbz, mh.z, ml.z); split_bf16(haw - hbw, mh.w, ml.w);
    *(ushort4*)(Yph + ybase) = ph; *(ushort4*)(Ypl + ybase) = pl;
    *(ushort4*)(Ymh + ybase) = mh; *(ushort4*)(Yml + ybase) = ml;
}

// ---------------------------------------------------------------------------
__global__ __launch_bounds__(256) void ln2_bf16(const float* __restrict__ t, unsigned short* __restrict__ hh,
                                                const float* __restrict__ s, const float* __restrict__ bb) {
    int wave = threadIdx.x >> 6, lane = threadIdx.x & 63;
    int m = blockIdx.x * 4 + wave;
    const float* row = t + (size_t)m * DIM;
    float4 v = *(const float4*)(row + lane * 4);
    float mean = wave_sum(v.x + v.y + v.z + v.w) * (1.f / 256.f);
    float dx = v.x - mean, dy = v.y - mean, dz = v.z - mean, dw = v.w - mean;
    float sq = wave_sum(dx * dx + dy * dy + dz * dz + dw * dw);
    float rstd = rsqrtf(sq * (1.f / 256.f) + LN_EPS);
    float4 s4 = *(const float4*)(s + lane * 4);
    float4 b4 = *(const float4*)(bb + lane * 4);
    ushort4 o;
    o.x = rne_bf16(dx * rstd * s4.x + b4.x);
    o.y = rne_bf16(dy * rstd * s4.y + b4.y);
    o.z = rne_bf16(dz * rstd * s4.z + b4.z);
    o.w = rne_bf16(dw * rstd * s4.w + b4.w);
    *(ushort4*)(hh + (size_t)m * DIM + lane * 4) = o;
}

// ---------------------------------------------------------------------------
// Split-bf16 GEMM (3-pass): A[36864][256] (Y±), B=C2-rows[0..143][256].
// Output transposed+split O[b][c:144][kp:576] hi/lo. Tile 128x144 (full N),
// BK=32, grid(288). Wave partition: 4 waves x (32 rows x 144 cols).
__global__ __launch_bounds__(256) void gemm_splitT(
    const unsigned short* __restrict__ Ahi, const unsigned short* __restrict__ Alo,
    const unsigned short* __restrict__ Bhi, const unsigned short* __restrict__ Blo,
    unsigned short* __restrict__ Ohi, unsigned short* __restrict__ Olo) {
    __shared__ __align__(16) unsigned short sAh[4096], sAl[4096], sBh[4608], sBl[4608];
    int m0 = blockIdx.x * 128;
    int tid = threadIdx.x, lane = tid & 63, w = tid >> 6;
    int wr = w * 32;
    f32x4 z = {0.f, 0.f, 0.f, 0.f};
    f32x4 acc[2][9];
#pragma unroll
    for (int i = 0; i < 2; i++)
#pragma unroll
        for (int j = 0; j < 9; j++) acc[i][j] = z;
    for (int k0 = 0; k0 < 256; k0 += 32) {
        a_stage128x32(sAh, Ahi + (size_t)m0 * 256 + k0, 256, tid);
        a_stage128x32(sAl, Alo + (size_t)m0 * 256 + k0, 256, tid);
        a_stage144x32(sBh, Bhi + k0, 256, tid);
        a_stage144x32(sBl, Blo + k0, 256, tid);
        __syncthreads();
        int q = lane >> 4;
        short8 ah[2], al[2];
#pragma unroll
        for (int i = 0; i < 2; i++) {
            int r = wr + i * 16 + (lane & 15);
            ah[i] = ld8x32(sAh, r, q); al[i] = ld8x32(sAl, r, q);
        }
#pragma unroll
        for (int j = 0; j < 9; j++) {
            int rb = j * 16 + (lane & 15);
            short8 bh = ld8x32(sBh, rb, q), bl = ld8x32(sBl, rb, q);
#pragma unroll
            for (int i = 0; i < 2; i++) {
                MFMA16(acc[i][j], ah[i], bh);
                MFMA16(acc[i][j], ah[i], bl);
                MFMA16(acc[i][j], al[i], bh);
            }
        }
        __syncthreads();
    }
    int q4 = (lane >> 4) * 4;
#pragma unroll
    for (int i = 0; i < 2; i++) {
        int r = m0 + wr + i * 16 + q4;
        int bidx = r / KF, kp = r - bidx * KF;   // r multiple of 4, no 576-crossing in g
#pragma unroll
        for (int j = 0; j < 9; j++) {
            int c = j * 16 + (lane & 15);
            ushort4 oh, ol;
            split_bf16(acc[i][j][0], oh.x, ol.x);
            split_bf16(acc[i][j][1], oh.y, ol.y);
            split_bf16(acc[i][j][2], oh.z, ol.z);
            split_bf16(acc[i][j][3], oh.w, ol.w);
            size_t off = ((size_t)bidx * MF + c) * KF + kp;
            *(ushort4*)(Ohi + off) = oh;
            *(ushort4*)(Olo + off) = ol;
        }
    }
}

// ---------------------------------------------------------------------------
// Dual split GEMM + butterfly. A: C1/S1 [640][576]; B: Yc/Ys flat [9216][576].
// Tile 128(k-rows) x 64(flat cols), BK=32, grid(5,144).
__global__ __launch_bounds__(256) void fft_big_dual(
    const unsigned short* __restrict__ C1h, const unsigned short* __restrict__ C1l,
    const unsigned short* __restrict__ S1h, const unsigned short* __restrict__ S1l,
    const unsigned short* __restrict__ Ych, const unsigned short* __restrict__ Ycl,
    const unsigned short* __restrict__ Ysh, const unsigned short* __restrict__ Ysl,
    float* __restrict__ t) {
    __shared__ __align__(16) unsigned short sC1h[4096], sC1l[4096], sS1h[4096], sS1l[4096];
    __shared__ __align__(16) unsigned short sYch[2048], sYcl[2048], sYsh[2048], sYsl[2048];
    int k0m = blockIdx.x * 128, n0 = blockIdx.y * 64;
    int tid = threadIdx.x, lane = tid & 63, w = tid >> 6;
    int wr = (w >> 1) * 64, wc = (w & 1) * 32;
    f32x4 z = {0.f, 0.f, 0.f, 0.f};
    f32x4 U[4][2], V[4][2];
#pragma unroll
    for (int i = 0; i < 4; i++)
#pragma unroll
        for (int j = 0; j < 2; j++) { U[i][j] = z; V[i][j] = z; }
    for (int kk0 = 0; kk0 < KF; kk0 += 32) {
        a_stage128x32(sC1h, C1h + (size_t)k0m * KF + kk0, KF, tid);
        a_stage128x32(sC1l, C1l + (size_t)k0m * KF + kk0, KF, tid);
        a_stage128x32(sS1h, S1h + (size_t)k0m * KF + kk0, KF, tid);
        a_stage128x32(sS1l, S1l + (size_t)k0m * KF + kk0, KF, tid);
        a_stage64x32(sYch, Ych + (size_t)n0 * KF + kk0, KF, tid);
        a_stage64x32(sYcl, Ycl + (size_t)n0 * KF + kk0, KF, tid);
        a_stage64x32(sYsh, Ysh + (size_t)n0 * KF + kk0, KF, tid);
        a_stage64x32(sYsl, Ysl + (size_t)n0 * KF + kk0, KF, tid);
        __syncthreads();
        int q = lane >> 4;
        short8 bch[2], bcl[2], bsh[2], bsl[2];
#pragma unroll
        for (int j = 0; j < 2; j++) {
            int r2 = wc + j * 16 + (lane & 15);
            bch[j] = ld8x32(sYch, r2, q); bcl[j] = ld8x32(sYcl, r2, q);
            bsh[j] = ld8x32(sYsh, r2, q); bsl[j] = ld8x32(sYsl, r2, q);
        }
#pragma unroll
        for (int i = 0; i < 4; i++) {
            int r1 = wr + i * 16 + (lane & 15);
            short8 ach = ld8x32(sC1h, r1, q), acl = ld8x32(sC1l, r1, q);
            short8 ash = ld8x32(sS1h, r1, q), asl = ld8x32(sS1l, r1, q);
#pragma unroll
            for (int j = 0; j < 2; j++) {
                MFMA16(U[i][j], ach, bch[j]);
                MFMA16(U[i][j], ach, bcl[j]);
                MFMA16(U[i][j], acl, bch[j]);
                MFMA16(V[i][j], ash, bsh[j]);
                MFMA16(V[i][j], ash, bsl[j]);
                MFMA16(V[i][j], asl, bsh[j]);
            }
        }
        __syncthreads();
    }
    int q4 = (lane >> 4) * 4;
#pragma unroll
    for (int j = 0; j < 2; j++) {
        int rcol = n0 + wc + j * 16 + (lane & 15);
        int b = rcol / MF, mm = rcol - b * MF;
        float* tb = t + (size_t)b * NTOK * DIM;
        if (mm > 128) continue;
#pragma unroll
        for (int i = 0; i < 4; i++) {
            int kk = k0m + wr + i * 16 + q4;
#pragma unroll
            for (int g = 0; g < 4; g++) {
                int k = kk + g;
                if (k > 512) continue;
                float u = U[i][j][g], v = V[i][j][g];
                tb[(size_t)k * 256 + mm] += u - v;
                if (mm >= 1 && mm <= 127) tb[(size_t)k * 256 + 256 - mm] += u + v;
                if (k >= 1) {
                    tb[(size_t)(NTOK - k) * 256 + mm] += u + v;
                    if (mm >= 1 && mm <= 127) tb[(size_t)(NTOK - k) * 256 + 256 - mm] += u - v;
                }
            }
        }
    }
}

// ---------------------------------------------------------------------------
// FFN1: Hid = leaky(h @ w1 + b1). 128x128 tile, grid(513,8).
__global__ __launch_bounds__(256) void gemm_ffn1(
    const unsigned short* __restrict__ A, const unsigned short* __restrict__ Bt,
    const float* __restrict__ b1, unsigned short* __restrict__ Hid) {
    __shared__ __align__(16) unsigned short sA[8192], sB[8192];
    int m0 = blockIdx.x * 128, n0 = blockIdx.y * 128;
    int tid = threadIdx.x, lane = tid & 63, w = tid >> 6;
    int wr = (w >> 1) * 64, wc = (w & 1) * 64;
    int maxrow = MROWS - 1 - m0; if (maxrow > 127) maxrow = 127;
    f32x4 z = {0.f, 0.f, 0.f, 0.f};
    f32x4 acc[4][4] = {{z, z, z, z}, {z, z, z, z}, {z, z, z, z}, {z, z, z, z}};
    for (int k0 = 0; k0 < 256; k0 += 64) {
        a_stage128(sA, A + (size_t)m0 * 256 + k0, 256, tid, maxrow);
        a_stage128(sB, Bt + (size_t)n0 * 256 + k0, 256, tid, 127);
        __syncthreads();
#pragma unroll
        for (int kc = 0; kc < 2; kc++) {
            int q = (lane >> 4) + kc * 4;
            short8 a8[4], b8[4];
#pragma unroll
            for (int i = 0; i < 4; i++) {
                a8[i] = ld8x64(sA, wr + i * 16 + (lane & 15), q);
                b8[i] = ld8x64(sB, wc + i * 16 + (lane & 15), q);
            }
#pragma unroll
            for (int i = 0; i < 4; i++)
#pragma unroll
                for (int j = 0; j < 4; j++) MFMA16(acc[i][j], a8[i], b8[j]);
        }
        __syncthreads();
    }
    int q4 = (lane >> 4) * 4;
#pragma unroll
    for (int i = 0; i < 4; i++) {
        int r = m0 + wr + i * 16 + q4;
#pragma unroll
        for (int j = 0; j < 4; j++) {
            int c = n0 + wc + j * 16 + (lane & 15);
            float bv = b1[c];
#pragma unroll
            for (int g = 0; g < 4; g++) {
                int rr = r + g;
                if (rr < MROWS) {
                    float val = acc[i][j][g] + bv;
                    val = val > 0.f ? val : 0.01f * val;
                    Hid[(size_t)rr * 1024 + c] = rne_bf16(val);
                }
            }
        }
    }
}

// ---------------------------------------------------------------------------
// FFN2: t += Hid @ w2 + b2. 128x128 tile, grid(513,2).
__global__ __launch_bounds__(256) void gemm_ffn2(
    const unsigned short* __restrict__ A, const unsigned short* __restrict__ Bt,
    const float* __restrict__ b2, float* __restrict__ t) {
    __shared__ __align__(16) unsigned short sA[8192], sB[8192];
    int m0 = blockIdx.x * 128, n0 = blockIdx.y * 128;
    int tid = threadIdx.x, lane = tid & 63, w = tid >> 6;
    int wr = (w >> 1) * 64, wc = (w & 1) * 64;
    int maxrow = MROWS - 1 - m0; if (maxrow > 127) maxrow = 127;
    f32x4 z = {0.f, 0.f, 0.f, 0.f};
    f32x4 acc[4][4] = {{z, z, z, z}, {z, z, z, z}, {z, z, z, z}, {z, z, z, z}};
    for (int k0 = 0; k0 < 1024; k0 += 64) {
        a_stage128(sA, A + (size_t)m0 * 1024 + k0, 1024, tid, maxrow);
        a_stage128(sB, Bt + (size_t)n0 * 1024 + k0, 1024, tid, 127);
        __syncthreads();
#pragma unroll
        for (int kc = 0; kc < 2; kc++) {
            int q = (lane >> 4) + kc * 4;
            short8 a8[4], b8[4];
#pragma unroll
            for (int i = 0; i < 4; i++) {
                a8[i] = ld8x64(sA, wr + i * 16 + (lane & 15), q);
                b8[i] = ld8x64(sB, wc + i * 16 + (lane & 15), q);
            }
#pragma unroll
            for (int i = 0; i < 4; i++)
#pragma unroll
                for (int j = 0; j < 4; j++) MFMA16(acc[i][j], a8[i], b8[j]);
        }
        __syncthreads();
    }
    int q4 = (lane >> 4) * 4;
#pragma unroll
    for (int i = 0; i < 4; i++) {
        int r = m0 + wr + i * 16 + q4;
#pragma unroll
        for (int j = 0; j < 4; j++) {
            int c = n0 + wc + j * 16 + (lane & 15);
            float bv = b2[c];
#pragma unroll
            for (int g = 0; g < 4; g++) {
                int rr = r + g;
                if (rr < MROWS) t[(size_t)rr * 256 + c] += acc[i][j][g] + bv;
            }
        }
    }
}

// ---------------------------------------------------------------------------
__global__ __launch_bounds__(256) void head_kernel(const float* __restrict__ t,
                                                   const float* __restrict__ hs, const float* __restrict__ hb,
                                                   const float* __restrict__ hw, const float* __restrict__ hbias,
                                                   float* __restrict__ out) {
    __shared__ float red[256];
    __shared__ float lnv[256];
    int b = blockIdx.x, tid = threadIdx.x;
    const float* tb = t + (size_t)b * NTOK * DIM;
    float s = 0.f;
    for (int m = 0; m < NTOK; m++) s += tb[m * DIM + tid];
    s *= (1.f / 1025.f);
    red[tid] = s;
    __syncthreads();
    for (int off = 128; off; off >>= 1) {
        if (tid < off) red[tid] += red[tid + off];
        __syncthreads();
    }
    float mean = red[0] * (1.f / 256.f);
    __syncthreads();
    float d = s - mean;
    red[tid] = d * d;
    __syncthreads();
    for (int off = 128; off; off >>= 1) {
        if (tid < off) red[tid] += red[tid + off];
        __syncthreads();
    }
    float rstd = rsqrtf(red[0] * (1.f / 256.f) + LN_EPS);
    __syncthreads();
    lnv[tid] = d * rstd * hs[tid] + hb[tid];
    __syncthreads();
    float lo[4];
#pragma unroll
    for (int jj = 0; jj < 4; jj++) {
        int n = tid + jj * 256;
        float a = -1e30f;
        if (n < NCLS) {
            a = hbias[n];
            for (int dd = 0; dd < DIM; dd++) a += lnv[dd] * hw[dd * NCLS + n];
        }
        lo[jj] = a;
    }
    float mx = fmaxf(fmaxf(lo[0], lo[1]), fmaxf(lo[2], lo[3]));
    red[tid] = mx;
    __syncthreads();
    for (int off = 128; off; off >>= 1) {
        if (tid < off) red[tid] = fmaxf(red[tid], red[tid + off]);
        __syncthreads();
    }
    float gmax = red[0];
    __syncthreads();
    float ev[4];
    float es = 0.f;
#pragma unroll
    for (int jj = 0; jj < 4; jj++) {
        int n = tid + jj * 256;
        ev[jj] = 0.f;
        if (n < NCLS) {
            ev[jj] = expf(lo[jj] - gmax);
            es += ev[jj];
        }
    }
    red[tid] = es;
    __syncthreads();
    for (int off = 128; off; off >>= 1) {
        if (tid < off) red[tid] += red[tid + off];
        __syncthreads();
    }
    float inv = 1.f / red[0];
#pragma unroll
    for (int jj = 0; jj < 4; jj++) {
        int n = tid + jj * 256;
        if (n < NCLS) out[(size_t)b * NCLS + n] = ev[jj] * inv;
    }
}

// ---------------------------------------------------------------------------
extern "C" void kernel_launch(void* const* d_in, const int* in_sizes, int n_in,
                              void* d_out, int out_size, void* d_ws, size_t ws_size,
                              hipStream_t stream) {
    const float* x      = (const float*)d_in[0];
    const float* conv_w = (const float*)d_in[1];
    const float* conv_b = (const float*)d_in[2];
    const float* pos    = (const float*)d_in[3];
    const float* cls    = (const float*)d_in[4];
    const float* ln1_s  = (const float*)d_in[5];
    const float* ln1_b  = (const float*)d_in[6];
    const float* ln2_s  = (const float*)d_in[7];
    const float* ln2_b  = (const float*)d_in[8];
    const float* w1     = (const float*)d_in[9];
    const float* b1     = (const float*)d_in[10];
    const float* w2     = (const float*)d_in[11];
    const float* b2     = (const float*)d_in[12];
    const float* hls    = (const float*)d_in[13];
    const float* hlb    = (const float*)d_in[14];
    const float* hw     = (const float*)d_in[15];
    const float* hbias  = (const float*)d_in[16];
    float* out = (float*)d_out;
    char* W = (char*)d_ws;

    // layout (bytes), pool time-multiplexed:
    //   t:    [0, 67,174,400)
    //   pool @ 67,174,400 (167,936,000):
    //     Yp (4 x 18,874,368 = 75,497,472)        — phase A
    //     Yct @ +75,497,472 (4 x 10,616,832)      — phase A  (ends +117,964,800)
    //     Hid @ +0 (134,348,800)                  — phase B
    //     hh  @ +134,348,800 (33,587,200)
    //   C1 grp @ 235,110,400 (4 x 737,280 = 640x576x2)
    //   C2 grp @ 238,059,520 (4 x 131,072)
    //   w1t @ 238,583,808 | w2t @ 241,729,536 | wph @ 244,875,264 | wpl @ 245,268,480
    float*          t    = (float*)(W + 0ULL);
    char*           pool = W + 67174400ULL;
    unsigned short* Yph  = (unsigned short*)(pool);
    unsigned short* Ypl  = (unsigned short*)(pool + 18874368ULL);
    unsigned short* Ymh  = (unsigned short*)(pool + 2 * 18874368ULL);
    unsigned short* Yml  = (unsigned short*)(pool + 3 * 18874368ULL);
    unsigned short* Ycth = (unsigned short*)(pool + 75497472ULL);
    unsigned short* Yctl = (unsigned short*)(pool + 75497472ULL + 10616832ULL);
    unsigned short* Ysth = (unsigned short*)(pool + 75497472ULL + 2 * 10616832ULL);
    unsigned short* Ystl = (unsigned short*)(pool + 75497472ULL + 3 * 10616832ULL);
    unsigned short* Hid  = (unsigned short*)(pool);
    unsigned short* hh   = (unsigned short*)(pool + 134348800ULL);
    unsigned short* C1h  = (unsigned short*)(W + 235110400ULL);
    unsigned short* C1l  = (unsigned short*)(W + 235110400ULL + 737280ULL);
    unsigned short* S1h  = (unsigned short*)(W + 235110400ULL + 2 * 737280ULL);
    unsigned short* S1l  = (unsigned short*)(W + 235110400ULL + 3 * 737280ULL);
    unsigned short* C2h  = (unsigned short*)(W + 238059520ULL);
    unsigned short* C2l  = (unsigned short*)(W + 238059520ULL + 131072ULL);
    unsigned short* S2h  = (unsigned short*)(W + 238059520ULL + 2 * 131072ULL);
    unsigned short* S2l  = (unsigned short*)(W + 238059520ULL + 3 * 131072ULL);
    unsigned short* w1t  = (unsigned short*)(W + 238583808ULL);
    unsigned short* w2t  = (unsigned short*)(W + 241729536ULL);
    unsigned short* wph  = (unsigned short*)(W + 244875264ULL);
    unsigned short* wpl  = (unsigned short*)(W + 245268480ULL);

    gen_dft2<<<dim3(1440), dim3(256), 0, stream>>>(C1h, C1l, S1h, S1l, C2h, C2l, S2h, S2l);
    conv_wp<<<dim3(768), dim3(256), 0, stream>>>(conv_w, wph, wpl);
    conv_w1t<<<dim3(6144), dim3(256), 0, stream>>>(w1, w1t);
    conv_w2t<<<dim3(6144), dim3(256), 0, stream>>>(w2, w2t);
    cls_init<<<dim3(BATCH), dim3(256), 0, stream>>>(cls, pos, t);
    patch_fused<<<dim3(512, 2), dim3(256), 0, stream>>>(x, wph, wpl, conv_b, pos, t);

    for (int l = 0; l < NLAYER; l++) {
        ln1fold<<<dim3(144, BATCH), dim3(256), 0, stream>>>(
            t, ln1_s + l * DIM, ln1_b + l * DIM, Yph, Ypl, Ymh, Yml);
        gemm_splitT<<<dim3(288), dim3(256), 0, stream>>>(Yph, Ypl, C2h, C2l, Ycth, Yctl);
        gemm_splitT<<<dim3(288), dim3(256), 0, stream>>>(Ymh, Yml, S2h, S2l, Ysth, Ystl);
        fft_big_dual<<<dim3(5, 144), dim3(256), 0, stream>>>(
            C1h, C1l, S1h, S1l, Ycth, Yctl, Ysth, Ystl, t);
        ln2_bf16<<<dim3(16400), dim3(256), 0, stream>>>(t, hh, ln2_s + l * DIM, ln2_b + l * DIM);
        gemm_ffn1<<<dim3(513, 8), dim3(256), 0, stream>>>(
            hh, w1t + (size_t)l * 262144, b1 + (size_t)l * HID, Hid);
        gemm_ffn2<<<dim3(513, 2), dim3(256), 0, stream>>>(
            Hid, w2t + (size_t)l * 262144, b2 + (size_t)l * DIM, t);
    }
    head_kernel<<<dim3(BATCH), dim3(256), 0, stream>>>(t, hls, hlb, hw, hbias, out);
}

// Round 5
// 3133.585 us; speedup vs baseline: 7.1065x; 1.0338x over previous
//
#include <hip/hip_runtime.h>
#include <math.h>

#define BATCH 64
#define CIN 3
#define IMH 512
#define IMW 512
#define PSZ 16
#define DIM 256
#define GHN 32
#define GWN 32
#define NTOK 1025
#define HID 1024
#define NLAYER 6
#define NCLS 1000
#define LN_EPS 1e-5f

// folded dims: token-fold 513 -> pad 576 ; dim-fold 129 -> pad 144
#define KF 576
#define KR 640           // A rows padded for 128-row tiles (5 x 128)
#define MF 144
#define NFLAT 9216       // 64 * MF
#define MROWS 65600      // 64*1025

typedef __attribute__((ext_vector_type(8))) short short8;
typedef __attribute__((ext_vector_type(4))) float f32x4;

#define MFMA16(acc, a, b) acc = __builtin_amdgcn_mfma_f32_16x16x32_bf16(a, b, acc, 0, 0, 0)

// ---------------------------------------------------------------------------
__device__ inline unsigned short rne_bf16(float x) {
    unsigned u = __float_as_uint(x);
    return (unsigned short)((u + 0x7FFF + ((u >> 16) & 1)) >> 16);
}
__device__ inline void split_bf16(float x, unsigned short& hi, unsigned short& lo) {
    unsigned short h = rne_bf16(x);
    hi = h;
    float hf = __uint_as_float((unsigned)h << 16);
    lo = rne_bf16(x - hf);
}
__device__ inline float wave_sum(float v) {
#pragma unroll
    for (int off = 32; off; off >>= 1) v += __shfl_xor(v, off);
    return v;
}
// 64-wide tiles (8 granules/row): perm = g ^ (row&7)  -> 2-way banks (free)
__device__ inline short8 ld8x64(const unsigned short* lds, int row, int q) {
    return *(const short8*)(lds + (row * 8 + (q ^ (row & 7))) * 8);
}
// 32-wide tiles (4 granules/row): perm = g ^ ((row>>1)&3) -> 2-way banks (free)
__device__ inline short8 ld8x32(const unsigned short* lds, int row, int q) {
    return *(const short8*)(lds + (row * 4 + (q ^ ((row >> 1) & 3))) * 8);
}
// async global->LDS 16B (lds arg wave-uniform; HW adds lane*16)
__device__ inline void gl2lds16(const unsigned short* g, unsigned short* l) {
    __builtin_amdgcn_global_load_lds((const __attribute__((address_space(1))) unsigned int*)g,
                                     (__attribute__((address_space(3))) unsigned int*)l, 16, 0, 0);
}
// stage 128 rows x 64 bf16 (mask-7 swizzle); row clamped for M-tail
__device__ inline void a_stage128(unsigned short* lds, const unsigned short* g, int lda, int tid, int maxrow) {
    int lane = tid & 63, w = tid >> 6;
#pragma unroll
    for (int s = 0; s < 4; s++) {
        int slot = w * 256 + s * 64;
        int sl = slot + lane;
        int row = sl >> 3, gc = (sl & 7) ^ (row & 7);
        if (row > maxrow) row = maxrow;
        gl2lds16(g + (size_t)row * lda + gc * 8, lds + slot * 8);
    }
}
// stage 128 rows x 32 bf16 (mask-3 shifted swizzle)
__device__ inline void a_stage128x32(unsigned short* lds, const unsigned short* g, int lda, int tid) {
    int lane = tid & 63, w = tid >> 6;
#pragma unroll
    for (int s = 0; s < 2; s++) {
        int slot = s * 256 + w * 64;
        int sl = slot + lane;
        int row = sl >> 2, gc = (sl & 3) ^ ((row >> 1) & 3);
        gl2lds16(g + (size_t)row * lda + gc * 8, lds + slot * 8);
    }
}
// stage 32 rows x 32 bf16 by ONE wave (2 instrs)
__device__ inline void a_stage32x32w(unsigned short* lds, const unsigned short* g, int lda, int lane) {
#pragma unroll
    for (int s = 0; s < 2; s++) {
        int sl = s * 64 + lane;
        int row = sl >> 2, gc = (sl & 3) ^ ((row >> 1) & 3);
        gl2lds16(g + (size_t)row * lda + gc * 8, lds + (s * 64) * 8);
    }
}
// stage 144 rows x 32 bf16 (576 slots: 2 full passes + wave0 partial)
__device__ inline void a_stage144x32(unsigned short* lds, const unsigned short* g, int lda, int tid) {
    int lane = tid & 63, w = tid >> 6;
#pragma unroll
    for (int s = 0; s < 2; s++) {
        int slot = s * 256 + w * 64;
        int sl = slot + lane;
        int row = sl >> 2, gc = (sl & 3) ^ ((row >> 1) & 3);
        gl2lds16(g + (size_t)row * lda + gc * 8, lds + slot * 8);
    }
    if (w == 0) {
        int slot = 512;
        int sl = slot + lane;
        int row = sl >> 2, gc = (sl & 3) ^ ((row >> 1) & 3);
        gl2lds16(g + (size_t)row * lda + gc * 8, lds + slot * 8);
    }
}

// ---------------------------------------------------------------------------
// DFT matrices bf16 hi/lo. C1/S1: [640][576] zero-padded past 512 (rows & cols).
__global__ __launch_bounds__(256) void gen_dft2(unsigned short* C1h, unsigned short* C1l,
                                                unsigned short* S1h, unsigned short* S1l,
                                                unsigned short* C2h, unsigned short* C2l,
                                                unsigned short* S2h, unsigned short* S2l) {
    int idx = blockIdx.x * 256 + threadIdx.x;
    if (idx < KR * KF) {
        int k = idx / KF, n = idx - k * KF;
        float c = 0.f, s = 0.f;
        if (k <= 512 && n <= 512) {
            int r = (k * n) % 1025;
            double ang = 6.283185307179586476925287 * (double)r / 1025.0;
            c = (float)cos(ang); s = (float)sin(ang);
        }
        unsigned short h, l;
        split_bf16(c, h, l); C1h[idx] = h; C1l[idx] = l;
        split_bf16(s, h, l); S1h[idx] = h; S1l[idx] = l;
    }
    if (idx < 256 * 256) {
        int k = idx >> 8, n = idx & 255;
        int r = (k * n) & 255;
        double ang = 6.283185307179586476925287 * (double)r / 256.0;
        float c = (float)cos(ang), s = (float)sin(ang);
        unsigned short h, l;
        split_bf16(c, h, l); C2h[idx] = h; C2l[idx] = l;
        split_bf16(s, h, l); S2h[idx] = h; S2l[idx] = l;
    }
}

// wp hi/lo: conv_w already [d=256][k=768], k = c*256+p*16+q
__global__ __launch_bounds__(256) void conv_wp(const float* __restrict__ w,
                                               unsigned short* __restrict__ wph, unsigned short* __restrict__ wpl) {
    int idx = blockIdx.x * 256 + threadIdx.x;
    unsigned short h, l;
    split_bf16(w[idx], h, l);
    wph[idx] = h; wpl[idx] = l;
}
__global__ __launch_bounds__(256) void conv_w1t(const float* __restrict__ w1, unsigned short* __restrict__ w1t) {
    int idx = blockIdx.x * 256 + threadIdx.x;
    int l = idx / 262144, rem = idx - l * 262144;
    int n = rem >> 8, k = rem & 255;
    w1t[idx] = rne_bf16(w1[(size_t)l * 262144 + (size_t)k * 1024 + n]);
}
__global__ __launch_bounds__(256) void conv_w2t(const float* __restrict__ w2, unsigned short* __restrict__ w2t) {
    int idx = blockIdx.x * 256 + threadIdx.x;
    int l = idx / 262144, rem = idx - l * 262144;
    int n = rem >> 10, k = rem & 1023;
    w2t[idx] = rne_bf16(w2[(size_t)l * 262144 + (size_t)k * 256 + n]);
}

// ---------------------------------------------------------------------------
__global__ __launch_bounds__(256) void cls_init(const float* __restrict__ cls, const float* __restrict__ pos,
                                                float* __restrict__ t) {
    int b = blockIdx.x, tid = threadIdx.x;
    t[(size_t)b * NTOK * DIM + tid] = cls[tid] + pos[tid];
}

// ---------------------------------------------------------------------------
// Fused patch embed: reads x directly, splits hi/lo in-register, 3-pass MFMA.
// M=65536 patches, N=256 dims, K=768. 128x128 tile, grid(512,2).
__global__ __launch_bounds__(256) void patch_fused(const float* __restrict__ x,
                                                   const unsigned short* __restrict__ wph,
                                                   const unsigned short* __restrict__ wpl,
                                                   const float* __restrict__ cb, const float* __restrict__ pos,
                                                   float* __restrict__ t) {
    __shared__ __align__(16) unsigned short sAh[8192], sAl[8192], sBh[8192], sBl[8192];
    int m0 = blockIdx.x * 128, n0 = blockIdx.y * 128;
    int tid = threadIdx.x, lane = tid & 63, w = tid >> 6;
    int wr = (w >> 1) * 64, wc = (w & 1) * 64;
    f32x4 z = {0.f, 0.f, 0.f, 0.f};
    f32x4 acc[4][4] = {{z, z, z, z}, {z, z, z, z}, {z, z, z, z}, {z, z, z, z}};
    for (int k0 = 0; k0 < 768; k0 += 64) {
        // A: 128 patches x 64 k-elems from x, converted to hi/lo
#pragma unroll
        for (int s = 0; s < 8; s++) {
            int lin = s * 1024 + tid * 4;
            int row = lin >> 6, kc = lin & 63;
            int m = m0 + row;
            int bb = m >> 10, gh = (m >> 5) & 31, gw = m & 31;
            int k = k0 + kc;
            int c = k >> 8, pp = (k >> 4) & 15, q = k & 15;
            const float* gp = x + (size_t)bb * 786432 + c * 262144 + gh * 8192 + pp * 512 + gw * 16 + q;
            float4 v = *(const float4*)gp;
            ushort4 oh, ol;
            split_bf16(v.x, oh.x, ol.x); split_bf16(v.y, oh.y, ol.y);
            split_bf16(v.z, oh.z, ol.z); split_bf16(v.w, oh.w, ol.w);
            int g = kc >> 3, half = (kc >> 2) & 1;
            int addr = (row * 8 + (g ^ (row & 7))) * 8 + half * 4;
            *(ushort4*)(sAh + addr) = oh;
            *(ushort4*)(sAl + addr) = ol;
        }
        a_stage128(sBh, wph + (size_t)n0 * 768 + k0, 768, tid, 127);
        a_stage128(sBl, wpl + (size_t)n0 * 768 + k0, 768, tid, 127);
        __syncthreads();
#pragma unroll
        for (int kc2 = 0; kc2 < 2; kc2++) {
            int q = (lane >> 4) + kc2 * 4;
            short8 ah[4], al[4], bh8[4], bl8[4];
#pragma unroll
            for (int i = 0; i < 4; i++) {
                ah[i] = ld8x64(sAh, wr + i * 16 + (lane & 15), q);
                al[i] = ld8x64(sAl, wr + i * 16 + (lane & 15), q);
                bh8[i] = ld8x64(sBh, wc + i * 16 + (lane & 15), q);
                bl8[i] = ld8x64(sBl, wc + i * 16 + (lane & 15), q);
            }
#pragma unroll
            for (int i = 0; i < 4; i++)
#pragma unroll
                for (int j = 0; j < 4; j++) {
                    MFMA16(acc[i][j], ah[i], bh8[j]);
                    MFMA16(acc[i][j], ah[i], bl8[j]);
                    MFMA16(acc[i][j], al[i], bh8[j]);
                }
        }
        __syncthreads();
    }
    int q4 = (lane >> 4) * 4;
#pragma unroll
    for (int i = 0; i < 4; i++) {
        int r = m0 + wr + i * 16 + q4;
#pragma unroll
        for (int j = 0; j < 4; j++) {
            int c = n0 + wc + j * 16 + (lane & 15);
#pragma unroll
            for (int g = 0; g < 4; g++) {
                int rr = r + g;
                int bb = rr >> 10, tok = 1 + (rr & 1023);
                t[((size_t)bb * NTOK + tok) * 256 + c] =
                    acc[i][j][g] + cb[c] + pos[(size_t)tok * 256 + c];
            }
        }
    }
}

// ---------------------------------------------------------------------------
// LN rows n' and 1025-n', emit Yh+ = hA+hB, Yh- = hA-hB as bf16 hi/lo.
__global__ __launch_bounds__(256) void ln1fold(const float* __restrict__ t,
                                               const float* __restrict__ s, const float* __restrict__ bb,
                                               unsigned short* __restrict__ Yph, unsigned short* __restrict__ Ypl,
                                               unsigned short* __restrict__ Ymh, unsigned short* __restrict__ Yml) {
    int tid = threadIdx.x, lane = tid & 63, w = tid >> 6;
    int b = blockIdx.y;
    int np = blockIdx.x * 4 + w;
    size_t ybase = ((size_t)b * KF + np) * 256 + lane * 4;
    if (np >= 513) {
        ushort4 z = make_ushort4(0, 0, 0, 0);
        *(ushort4*)(Yph + ybase) = z; *(ushort4*)(Ypl + ybase) = z;
        *(ushort4*)(Ymh + ybase) = z; *(ushort4*)(Yml + ybase) = z;
        return;
    }
    const float* tb = t + (size_t)b * NTOK * DIM;
    float4 va = *(const float4*)(tb + (size_t)np * 256 + lane * 4);
    float sa = wave_sum(va.x + va.y + va.z + va.w) * (1.f / 256.f);
    float dax = va.x - sa, day = va.y - sa, daz = va.z - sa, daw = va.w - sa;
    float qa = wave_sum(dax * dax + day * day + daz * daz + daw * daw);
    float ra = rsqrtf(qa * (1.f / 256.f) + LN_EPS);
    float4 s4 = *(const float4*)(s + lane * 4);
    float4 b4 = *(const float4*)(bb + lane * 4);
    float hax = dax * ra * s4.x + b4.x, hay = day * ra * s4.y + b4.y;
    float haz = daz * ra * s4.z + b4.z, haw = daw * ra * s4.w + b4.w;
    float hbx = 0.f, hby = 0.f, hbz = 0.f, hbw = 0.f;
    if (np >= 1) {
        float4 vb = *(const float4*)(tb + (size_t)(NTOK - np) * 256 + lane * 4);
        float sb = wave_sum(vb.x + vb.y + vb.z + vb.w) * (1.f / 256.f);
        float dbx = vb.x - sb, dby = vb.y - sb, dbz = vb.z - sb, dbw = vb.w - sb;
        float qb = wave_sum(dbx * dbx + dby * dby + dbz * dbz + dbw * dbw);
        float rb = rsqrtf(qb * (1.f / 256.f) + LN_EPS);
        hbx = dbx * rb * s4.x + b4.x; hby = dby * rb * s4.y + b4.y;
        hbz = dbz * rb * s4.z + b4.z; hbw = dbw * rb * s4.w + b4.w;
    }
    ushort4 ph, pl, mh, ml;
    split_bf16(hax + hbx, ph.x, pl.x); split_bf16(hay + hby, ph.y, pl.y);
    split_bf16(haz + hbz, ph.z, pl.z); split_bf16(haw + hbw, ph.w, pl.w);
    split_bf16(hax - hbx, mh.x, ml.x); split_bf16(hay - hby, mh.y, ml.y);
    split_bf16(haz - hbz, mh.z, ml.z); split_bf16(haw - hbw, mh.w, ml.w);
    *(ushort4*)(Yph + ybase) = ph; *(ushort4*)(Ypl + ybase) = pl;
    *(ushort4*)(Ymh + ybase) = mh; *(ushort4*)(Yml + ybase) = ml;
}

// ---------------------------------------------------------------------------
__global__ __launch_bounds__(256) void ln2_bf16(const float* __restrict__ t, unsigned short* __restrict__ hh,
                                                const float* __restrict__ s, const float* __restrict__ bb) {
    int wave = threadIdx.x >> 6, lane = threadIdx.x & 63;
    int m = blockIdx.x * 4 + wave;
    const float* row = t + (size_t)m * DIM;
    float4 v = *(const float4*)(row + lane * 4);
    float mean = wave_sum(v.x + v.y + v.z + v.w) * (1.f / 256.f);
    float dx = v.x - mean, dy = v.y - mean, dz = v.z - mean, dw = v.w - mean;
    float sq = wave_sum(dx * dx + dy * dy + dz * dz + dw * dw);
    float rstd = rsqrtf(sq * (1.f / 256.f) + LN_EPS);
    float4 s4 = *(const float4*)(s + lane * 4);
    float4 b4 = *(const float4*)(bb + lane * 4);
    ushort4 o;
    o.x = rne_bf16(dx * rstd * s4.x + b4.x);
    o.y = rne_bf16(dy * rstd * s4.y + b4.y);
    o.z = rne_bf16(dz * rstd * s4.z + b4.z);
    o.w = rne_bf16(dw * rstd * s4.w + b4.w);
    *(ushort4*)(hh + (size_t)m * DIM + lane * 4) = o;
}

// ---------------------------------------------------------------------------
// Split-bf16 GEMM (3-pass): A[36864][256] (Y±), B=C2-rows[0..143][256].
// Output transposed+split O[b][c:144][kp:576] hi/lo. Tile 128x144 (full N),
// BK=32, grid(288). Wave partition: 4 waves x (32 rows x 144 cols).
__global__ __launch_bounds__(256) void gemm_splitT(
    const unsigned short* __restrict__ Ahi, const unsigned short* __restrict__ Alo,
    const unsigned short* __restrict__ Bhi, const unsigned short* __restrict__ Blo,
    unsigned short* __restrict__ Ohi, unsigned short* __restrict__ Olo) {
    __shared__ __align__(16) unsigned short sAh[4096], sAl[4096], sBh[4608], sBl[4608];
    int m0 = blockIdx.x * 128;
    int tid = threadIdx.x, lane = tid & 63, w = tid >> 6;
    int wr = w * 32;
    f32x4 z = {0.f, 0.f, 0.f, 0.f};
    f32x4 acc[2][9];
#pragma unroll
    for (int i = 0; i < 2; i++)
#pragma unroll
        for (int j = 0; j < 9; j++) acc[i][j] = z;
    for (int k0 = 0; k0 < 256; k0 += 32) {
        a_stage128x32(sAh, Ahi + (size_t)m0 * 256 + k0, 256, tid);
        a_stage128x32(sAl, Alo + (size_t)m0 * 256 + k0, 256, tid);
        a_stage144x32(sBh, Bhi + k0, 256, tid);
        a_stage144x32(sBl, Blo + k0, 256, tid);
        __syncthreads();
        int q = lane >> 4;
        short8 ah[2], al[2];
#pragma unroll
        for (int i = 0; i < 2; i++) {
            int r = wr + i * 16 + (lane & 15);
            ah[i] = ld8x32(sAh, r, q); al[i] = ld8x32(sAl, r, q);
        }
#pragma unroll
        for (int j = 0; j < 9; j++) {
            int rb = j * 16 + (lane & 15);
            short8 bh = ld8x32(sBh, rb, q), bl = ld8x32(sBl, rb, q);
#pragma unroll
            for (int i = 0; i < 2; i++) {
                MFMA16(acc[i][j], ah[i], bh);
                MFMA16(acc[i][j], ah[i], bl);
                MFMA16(acc[i][j], al[i], bh);
            }
        }
        __syncthreads();
    }
    int q4 = (lane >> 4) * 4;
#pragma unroll
    for (int i = 0; i < 2; i++) {
        int r = m0 + wr + i * 16 + q4;
        int bidx = r / KF, kp = r - bidx * KF;   // r multiple of 4, no 576-crossing in g
#pragma unroll
        for (int j = 0; j < 9; j++) {
            int c = j * 16 + (lane & 15);
            ushort4 oh, ol;
            split_bf16(acc[i][j][0], oh.x, ol.x);
            split_bf16(acc[i][j][1], oh.y, ol.y);
            split_bf16(acc[i][j][2], oh.z, ol.z);
            split_bf16(acc[i][j][3], oh.w, ol.w);
            size_t off = ((size_t)bidx * MF + c) * KF + kp;
            *(ushort4*)(Ohi + off) = oh;
            *(ushort4*)(Olo + off) = ol;
        }
    }
}

// ---------------------------------------------------------------------------
// Dual split GEMM + butterfly. A: C1/S1 [640][576]; B: Yc/Ys flat [9216][576].
// Tile 128(k-rows) x 32(flat cols), BK=32, grid(5,288). LDS 40KB -> 4 blk/CU.
// Wave partition: 4 waves x 32 k-rows, all waves share the 32-col B tile.
__global__ __launch_bounds__(256) void fft_big_dual(
    const unsigned short* __restrict__ C1h, const unsigned short* __restrict__ C1l,
    const unsigned short* __restrict__ S1h, const unsigned short* __restrict__ S1l,
    const unsigned short* __restrict__ Ych, const unsigned short* __restrict__ Ycl,
    const unsigned short* __restrict__ Ysh, const unsigned short* __restrict__ Ysl,
    float* __restrict__ t) {
    __shared__ __align__(16) unsigned short sC1h[4096], sC1l[4096], sS1h[4096], sS1l[4096];
    __shared__ __align__(16) unsigned short sYch[1024], sYcl[1024], sYsh[1024], sYsl[1024];
    int k0m = blockIdx.x * 128, n0 = blockIdx.y * 32;
    int tid = threadIdx.x, lane = tid & 63, w = tid >> 6;
    int wr = w * 32;
    f32x4 z = {0.f, 0.f, 0.f, 0.f};
    f32x4 U[2][2], V[2][2];
#pragma unroll
    for (int i = 0; i < 2; i++)
#pragma unroll
        for (int j = 0; j < 2; j++) { U[i][j] = z; V[i][j] = z; }
    for (int kk0 = 0; kk0 < KF; kk0 += 32) {
        a_stage128x32(sC1h, C1h + (size_t)k0m * KF + kk0, KF, tid);
        a_stage128x32(sC1l, C1l + (size_t)k0m * KF + kk0, KF, tid);
        a_stage128x32(sS1h, S1h + (size_t)k0m * KF + kk0, KF, tid);
        a_stage128x32(sS1l, S1l + (size_t)k0m * KF + kk0, KF, tid);
        size_t yoff = (size_t)n0 * KF + kk0;
        if (w == 0)      a_stage32x32w(sYch, Ych + yoff, KF, lane);
        else if (w == 1) a_stage32x32w(sYcl, Ycl + yoff, KF, lane);
        else if (w == 2) a_stage32x32w(sYsh, Ysh + yoff, KF, lane);
        else             a_stage32x32w(sYsl, Ysl + yoff, KF, lane);
        __syncthreads();
        int q = lane >> 4;
        short8 bch[2], bcl[2], bsh[2], bsl[2];
#pragma unroll
        for (int j = 0; j < 2; j++) {
            int r2 = j * 16 + (lane & 15);
            bch[j] = ld8x32(sYch, r2, q); bcl[j] = ld8x32(sYcl, r2, q);
            bsh[j] = ld8x32(sYsh, r2, q); bsl[j] = ld8x32(sYsl, r2, q);
        }
#pragma unroll
        for (int i = 0; i < 2; i++) {
            int r1 = wr + i * 16 + (lane & 15);
            short8 ach = ld8x32(sC1h, r1, q), acl = ld8x32(sC1l, r1, q);
            short8 ash = ld8x32(sS1h, r1, q), asl = ld8x32(sS1l, r1, q);
#pragma unroll
            for (int j = 0; j < 2; j++) {
                MFMA16(U[i][j], ach, bch[j]);
                MFMA16(U[i][j], ach, bcl[j]);
                MFMA16(U[i][j], acl, bch[j]);
                MFMA16(V[i][j], ash, bsh[j]);
                MFMA16(V[i][j], ash, bsl[j]);
                MFMA16(V[i][j], asl, bsh[j]);
            }
        }
        __syncthreads();
    }
    int q4 = (lane >> 4) * 4;
#pragma unroll
    for (int j = 0; j < 2; j++) {
        int rcol = n0 + j * 16 + (lane & 15);
        int b = rcol / MF, mm = rcol - b * MF;
        float* tb = t + (size_t)b * NTOK * DIM;
        if (mm > 128) continue;
#pragma unroll
        for (int i = 0; i < 2; i++) {
            int kk = k0m + wr + i * 16 + q4;
#pragma unroll
            for (int g = 0; g < 4; g++) {
                int k = kk + g;
                if (k > 512) continue;
                float u = U[i][j][g], v = V[i][j][g];
                tb[(size_t)k * 256 + mm] += u - v;
                if (mm >= 1 && mm <= 127) tb[(size_t)k * 256 + 256 - mm] += u + v;
                if (k >= 1) {
                    tb[(size_t)(NTOK - k) * 256 + mm] += u + v;
                    if (mm >= 1 && mm <= 127) tb[(size_t)(NTOK - k) * 256 + 256 - mm] += u - v;
                }
            }
        }
    }
}

// ---------------------------------------------------------------------------
// FFN1: Hid = leaky(h @ w1 + b1). 128x128 tile, grid(513,8).
__global__ __launch_bounds__(256) void gemm_ffn1(
    const unsigned short* __restrict__ A, const unsigned short* __restrict__ Bt,
    const float* __restrict__ b1, unsigned short* __restrict__ Hid) {
    __shared__ __align__(16) unsigned short sA[8192], sB[8192];
    int m0 = blockIdx.x * 128, n0 = blockIdx.y * 128;
    int tid = threadIdx.x, lane = tid & 63, w = tid >> 6;
    int wr = (w >> 1) * 64, wc = (w & 1) * 64;
    int maxrow = MROWS - 1 - m0; if (maxrow > 127) maxrow = 127;
    f32x4 z = {0.f, 0.f, 0.f, 0.f};
    f32x4 acc[4][4] = {{z, z, z, z}, {z, z, z, z}, {z, z, z, z}, {z, z, z, z}};
    for (int k0 = 0; k0 < 256; k0 += 64) {
        a_stage128(sA, A + (size_t)m0 * 256 + k0, 256, tid, maxrow);
        a_stage128(sB, Bt + (size_t)n0 * 256 + k0, 256, tid, 127);
        __syncthreads();
#pragma unroll
        for (int kc = 0; kc < 2; kc++) {
            int q = (lane >> 4) + kc * 4;
            short8 a8[4], b8[4];
#pragma unroll
            for (int i = 0; i < 4; i++) {
                a8[i] = ld8x64(sA, wr + i * 16 + (lane & 15), q);
                b8[i] = ld8x64(sB, wc + i * 16 + (lane & 15), q);
            }
#pragma unroll
            for (int i = 0; i < 4; i++)
#pragma unroll
                for (int j = 0; j < 4; j++) MFMA16(acc[i][j], a8[i], b8[j]);
        }
        __syncthreads();
    }
    int q4 = (lane >> 4) * 4;
#pragma unroll
    for (int i = 0; i < 4; i++) {
        int r = m0 + wr + i * 16 + q4;
#pragma unroll
        for (int j = 0; j < 4; j++) {
            int c = n0 + wc + j * 16 + (lane & 15);
            float bv = b1[c];
#pragma unroll
            for (int g = 0; g < 4; g++) {
                int rr = r + g;
                if (rr < MROWS) {
                    float val = acc[i][j][g] + bv;
                    val = val > 0.f ? val : 0.01f * val;
                    Hid[(size_t)rr * 1024 + c] = rne_bf16(val);
                }
            }
        }
    }
}

// ---------------------------------------------------------------------------
// FFN2: t += Hid @ w2 + b2. 128x128 tile, grid(513,2).
__global__ __launch_bounds__(256) void gemm_ffn2(
    const unsigned short* __restrict__ A, const unsigned short* __restrict__ Bt,
    const float* __restrict__ b2, float* __restrict__ t) {
    __shared__ __align__(16) unsigned short sA[8192], sB[8192];
    int m0 = blockIdx.x * 128, n0 = blockIdx.y * 128;
    int tid = threadIdx.x, lane = tid & 63, w = tid >> 6;
    int wr = (w >> 1) * 64, wc = (w & 1) * 64;
    int maxrow = MROWS - 1 - m0; if (maxrow > 127) maxrow = 127;
    f32x4 z = {0.f, 0.f, 0.f, 0.f};
    f32x4 acc[4][4] = {{z, z, z, z}, {z, z, z, z}, {z, z, z, z}, {z, z, z, z}};
    for (int k0 = 0; k0 < 1024; k0 += 64) {
        a_stage128(sA, A + (size_t)m0 * 1024 + k0, 1024, tid, maxrow);
        a_stage128(sB, Bt + (size_t)n0 * 1024 + k0, 1024, tid, 127);
        __syncthreads();
#pragma unroll
        for (int kc = 0; kc < 2; kc++) {
            int q = (lane >> 4) + kc * 4;
            short8 a8[4], b8[4];
#pragma unroll
            for (int i = 0; i < 4; i++) {
                a8[i] = ld8x64(sA, wr + i * 16 + (lane & 15), q);
                b8[i] = ld8x64(sB, wc + i * 16 + (lane & 15), q);
            }
#pragma unroll
            for (int i = 0; i < 4; i++)
#pragma unroll
                for (int j = 0; j < 4; j++) MFMA16(acc[i][j], a8[i], b8[j]);
        }
        __syncthreads();
    }
    int q4 = (lane >> 4) * 4;
#pragma unroll
    for (int i = 0; i < 4; i++) {
        int r = m0 + wr + i * 16 + q4;
#pragma unroll
        for (int j = 0; j < 4; j++) {
            int c = n0 + wc + j * 16 + (lane & 15);
            float bv = b2[c];
#pragma unroll
            for (int g = 0; g < 4; g++) {
                int rr = r + g;
                if (rr < MROWS) t[(size_t)rr * 256 + c] += acc[i][j][g] + bv;
            }
        }
    }
}

// ---------------------------------------------------------------------------
__global__ __launch_bounds__(256) void head_kernel(const float* __restrict__ t,
                                                   const float* __restrict__ hs, const float* __restrict__ hb,
                                                   const float* __restrict__ hw, const float* __restrict__ hbias,
                                                   float* __restrict__ out) {
    __shared__ float red[256];
    __shared__ float lnv[256];
    int b = blockIdx.x, tid = threadIdx.x;
    const float* tb = t + (size_t)b * NTOK * DIM;
    float s = 0.f;
    for (int m = 0; m < NTOK; m++) s += tb[m * DIM + tid];
    s *= (1.f / 1025.f);
    red[tid] = s;
    __syncthreads();
    for (int off = 128; off; off >>= 1) {
        if (tid < off) red[tid] += red[tid + off];
        __syncthreads();
    }
    float mean = red[0] * (1.f / 256.f);
    __syncthreads();
    float d = s - mean;
    red[tid] = d * d;
    __syncthreads();
    for (int off = 128; off; off >>= 1) {
        if (tid < off) red[tid] += red[tid + off];
        __syncthreads();
    }
    float rstd = rsqrtf(red[0] * (1.f / 256.f) + LN_EPS);
    __syncthreads();
    lnv[tid] = d * rstd * hs[tid] + hb[tid];
    __syncthreads();
    float lo[4];
#pragma unroll
    for (int jj = 0; jj < 4; jj++) {
        int n = tid + jj * 256;
        float a = -1e30f;
        if (n < NCLS) {
            a = hbias[n];
            for (int dd = 0; dd < DIM; dd++) a += lnv[dd] * hw[dd * NCLS + n];
        }
        lo[jj] = a;
    }
    float mx = fmaxf(fmaxf(lo[0], lo[1]), fmaxf(lo[2], lo[3]));
    red[tid] = mx;
    __syncthreads();
    for (int off = 128; off; off >>= 1) {
        if (tid < off) red[tid] = fmaxf(red[tid], red[tid + off]);
        __syncthreads();
    }
    float gmax = red[0];
    __syncthreads();
    float ev[4];
    float es = 0.f;
#pragma unroll
    for (int jj = 0; jj < 4; jj++) {
        int n = tid + jj * 256;
        ev[jj] = 0.f;
        if (n < NCLS) {
            ev[jj] = expf(lo[jj] - gmax);
            es += ev[jj];
        }
    }
    red[tid] = es;
    __syncthreads();
    for (int off = 128; off; off >>= 1) {
        if (tid < off) red[tid] += red[tid + off];
        __syncthreads();
    }
    float inv = 1.f / red[0];
#pragma unroll
    for (int jj = 0; jj < 4; jj++) {
        int n = tid + jj * 256;
        if (n < NCLS) out[(size_t)b * NCLS + n] = ev[jj] * inv;
    }
}

// ---------------------------------------------------------------------------
extern "C" void kernel_launch(void* const* d_in, const int* in_sizes, int n_in,
                              void* d_out, int out_size, void* d_ws, size_t ws_size,
                              hipStream_t stream) {
    const float* x      = (const float*)d_in[0];
    const float* conv_w = (const float*)d_in[1];
    const float* conv_b = (const float*)d_in[2];
    const float* pos    = (const float*)d_in[3];
    const float* cls    = (const float*)d_in[4];
    const float* ln1_s  = (const float*)d_in[5];
    const float* ln1_b  = (const float*)d_in[6];
    const float* ln2_s  = (const float*)d_in[7];
    const float* ln2_b  = (const float*)d_in[8];
    const float* w1     = (const float*)d_in[9];
    const float* b1     = (const float*)d_in[10];
    const float* w2     = (const float*)d_in[11];
    const float* b2     = (const float*)d_in[12];
    const float* hls    = (const float*)d_in[13];
    const float* hlb    = (const float*)d_in[14];
    const float* hw     = (const float*)d_in[15];
    const float* hbias  = (const float*)d_in[16];
    float* out = (float*)d_out;
    char* W = (char*)d_ws;

    // layout (bytes), pool time-multiplexed:
    //   t:    [0, 67,174,400)
    //   pool @ 67,174,400 (167,936,000):
    //     Yp (4 x 18,874,368 = 75,497,472)        — phase A
    //     Yct @ +75,497,472 (4 x 10,616,832)      — phase A  (ends +117,964,800)
    //     Hid @ +0 (134,348,800)                  — phase B
    //     hh  @ +134,348,800 (33,587,200)
    //   C1 grp @ 235,110,400 (4 x 737,280 = 640x576x2)
    //   C2 grp @ 238,059,520 (4 x 131,072)
    //   w1t @ 238,583,808 | w2t @ 241,729,536 | wph @ 244,875,264 | wpl @ 245,268,480
    float*          t    = (float*)(W + 0ULL);
    char*           pool = W + 67174400ULL;
    unsigned short* Yph  = (unsigned short*)(pool);
    unsigned short* Ypl  = (unsigned short*)(pool + 18874368ULL);
    unsigned short* Ymh  = (unsigned short*)(pool + 2 * 18874368ULL);
    unsigned short* Yml  = (unsigned short*)(pool + 3 * 18874368ULL);
    unsigned short* Ycth = (unsigned short*)(pool + 75497472ULL);
    unsigned short* Yctl = (unsigned short*)(pool + 75497472ULL + 10616832ULL);
    unsigned short* Ysth = (unsigned short*)(pool + 75497472ULL + 2 * 10616832ULL);
    unsigned short* Ystl = (unsigned short*)(pool + 75497472ULL + 3 * 10616832ULL);
    unsigned short* Hid  = (unsigned short*)(pool);
    unsigned short* hh   = (unsigned short*)(pool + 134348800ULL);
    unsigned short* C1h  = (unsigned short*)(W + 235110400ULL);
    unsigned short* C1l  = (unsigned short*)(W + 235110400ULL + 737280ULL);
    unsigned short* S1h  = (unsigned short*)(W + 235110400ULL + 2 * 737280ULL);
    unsigned short* S1l  = (unsigned short*)(W + 235110400ULL + 3 * 737280ULL);
    unsigned short* C2h  = (unsigned short*)(W + 238059520ULL);
    unsigned short* C2l  = (unsigned short*)(W + 238059520ULL + 131072ULL);
    unsigned short* S2h  = (unsigned short*)(W + 238059520ULL + 2 * 131072ULL);
    unsigned short* S2l  = (unsigned short*)(W + 238059520ULL + 3 * 131072ULL);
    unsigned short* w1t  = (unsigned short*)(W + 238583808ULL);
    unsigned short* w2t  = (unsigned short*)(W + 241729536ULL);
    unsigned short* wph  = (unsigned short*)(W + 244875264ULL);
    unsigned short* wpl  = (unsigned short*)(W + 245268480ULL);

    gen_dft2<<<dim3(1440), dim3(256), 0, stream>>>(C1h, C1l, S1h, S1l, C2h, C2l, S2h, S2l);
    conv_wp<<<dim3(768), dim3(256), 0, stream>>>(conv_w, wph, wpl);
    conv_w1t<<<dim3(6144), dim3(256), 0, stream>>>(w1, w1t);
    conv_w2t<<<dim3(6144), dim3(256), 0, stream>>>(w2, w2t);
    cls_init<<<dim3(BATCH), dim3(256), 0, stream>>>(cls, pos, t);
    patch_fused<<<dim3(512, 2), dim3(256), 0, stream>>>(x, wph, wpl, conv_b, pos, t);

    for (int l = 0; l < NLAYER; l++) {
        ln1fold<<<dim3(144, BATCH), dim3(256), 0, stream>>>(
            t, ln1_s + l * DIM, ln1_b + l * DIM, Yph, Ypl, Ymh, Yml);
        gemm_splitT<<<dim3(288), dim3(256), 0, stream>>>(Yph, Ypl, C2h, C2l, Ycth, Yctl);
        gemm_splitT<<<dim3(288), dim3(256), 0, stream>>>(Ymh, Yml, S2h, S2l, Ysth, Ystl);
        fft_big_dual<<<dim3(5, 288), dim3(256), 0, stream>>>(
            C1h, C1l, S1h, S1l, Ycth, Yctl, Ysth, Ystl, t);
        ln2_bf16<<<dim3(16400), dim3(256), 0, stream>>>(t, hh, ln2_s + l * DIM, ln2_b + l * DIM);
        gemm_ffn1<<<dim3(513, 8), dim3(256), 0, stream>>>(
            hh, w1t + (size_t)l * 262144, b1 + (size_t)l * HID, Hid);
        gemm_ffn2<<<dim3(513, 2), dim3(256), 0, stream>>>(
            Hid, w2t + (size_t)l * 262144, b2 + (size_t)l * DIM, t);
    }
    head_kernel<<<dim3(BATCH), dim3(256), 0, stream>>>(t, hls, hlb, hw, hbias, out);
}

// Round 6
// 2981.695 us; speedup vs baseline: 7.4685x; 1.0509x over previous
//
#include <hip/hip_runtime.h>
#include <math.h>

#define BATCH 64
#define CIN 3
#define IMH 512
#define IMW 512
#define PSZ 16
#define DIM 256
#define GHN 32
#define GWN 32
#define NTOK 1025
#define HID 1024
#define NLAYER 6
#define NCLS 1000
#define LN_EPS 1e-5f

// folded dims: token-fold 513 -> pad 576 ; dim-fold 129 -> pad 144
#define KF 576
#define KR 640           // A rows padded for 128-row tiles (5 x 128)
#define MF 144
#define MROWS 65600      // 64*1025

typedef __attribute__((ext_vector_type(8))) short short8;
typedef __attribute__((ext_vector_type(4))) float f32x4;

#define MFMA16(acc, a, b) acc = __builtin_amdgcn_mfma_f32_16x16x32_bf16(a, b, acc, 0, 0, 0)

// ---------------------------------------------------------------------------
__device__ inline unsigned short rne_bf16(float x) {
    unsigned u = __float_as_uint(x);
    return (unsigned short)((u + 0x7FFF + ((u >> 16) & 1)) >> 16);
}
__device__ inline void split_bf16(float x, unsigned short& hi, unsigned short& lo) {
    unsigned short h = rne_bf16(x);
    hi = h;
    float hf = __uint_as_float((unsigned)h << 16);
    lo = rne_bf16(x - hf);
}
__device__ inline float wave_sum(float v) {
#pragma unroll
    for (int off = 32; off; off >>= 1) v += __shfl_xor(v, off);
    return v;
}
// 64-wide tiles (8 granules/row): perm = g ^ (row&7)  -> 2-way banks (free)
__device__ inline short8 ld8x64(const unsigned short* lds, int row, int q) {
    return *(const short8*)(lds + (row * 8 + (q ^ (row & 7))) * 8);
}
// 32-wide tiles (4 granules/row): perm = g ^ ((row>>1)&3) -> 2-way banks (free)
__device__ inline short8 ld8x32(const unsigned short* lds, int row, int q) {
    return *(const short8*)(lds + (row * 4 + (q ^ ((row >> 1) & 3))) * 8);
}
// async global->LDS 16B (lds arg wave-uniform; HW adds lane*16)
__device__ inline void gl2lds16(const unsigned short* g, unsigned short* l) {
    __builtin_amdgcn_global_load_lds((const __attribute__((address_space(1))) unsigned int*)g,
                                     (__attribute__((address_space(3))) unsigned int*)l, 16, 0, 0);
}
// stage 128 rows x 64 bf16 (mask-7 swizzle); row clamped for M-tail (256 thr)
__device__ inline void a_stage128(unsigned short* lds, const unsigned short* g, int lda, int tid, int maxrow) {
    int lane = tid & 63, w = tid >> 6;
#pragma unroll
    for (int s = 0; s < 4; s++) {
        int slot = w * 256 + s * 64;
        int sl = slot + lane;
        int row = sl >> 3, gc = (sl & 7) ^ (row & 7);
        if (row > maxrow) row = maxrow;
        gl2lds16(g + (size_t)row * lda + gc * 8, lds + slot * 8);
    }
}
// stage 144 rows x 32 bf16 (576 slots: 2 full passes + wave0 partial, 256 thr)
__device__ inline void a_stage144x32(unsigned short* lds, const unsigned short* g, int lda, int tid) {
    int lane = tid & 63, w = tid >> 6;
#pragma unroll
    for (int s = 0; s < 2; s++) {
        int slot = s * 256 + w * 64;
        int sl = slot + lane;
        int row = sl >> 2, gc = (sl & 3) ^ ((row >> 1) & 3);
        gl2lds16(g + (size_t)row * lda + gc * 8, lds + slot * 8);
    }
    if (w == 0) {
        int slot = 512;
        int sl = slot + lane;
        int row = sl >> 2, gc = (sl & 3) ^ ((row >> 1) & 3);
        gl2lds16(g + (size_t)row * lda + gc * 8, lds + slot * 8);
    }
}

// ---------------------------------------------------------------------------
// DFT matrices bf16 hi/lo. C1/S1: [640][576] zero-padded past 512 (rows & cols).
__global__ __launch_bounds__(256) void gen_dft2(unsigned short* C1h, unsigned short* C1l,
                                                unsigned short* S1h, unsigned short* S1l,
                                                unsigned short* C2h, unsigned short* C2l,
                                                unsigned short* S2h, unsigned short* S2l) {
    int idx = blockIdx.x * 256 + threadIdx.x;
    if (idx < KR * KF) {
        int k = idx / KF, n = idx - k * KF;
        float c = 0.f, s = 0.f;
        if (k <= 512 && n <= 512) {
            int r = (k * n) % 1025;
            double ang = 6.283185307179586476925287 * (double)r / 1025.0;
            c = (float)cos(ang); s = (float)sin(ang);
        }
        unsigned short h, l;
        split_bf16(c, h, l); C1h[idx] = h; C1l[idx] = l;
        split_bf16(s, h, l); S1h[idx] = h; S1l[idx] = l;
    }
    if (idx < 256 * 256) {
        int k = idx >> 8, n = idx & 255;
        int r = (k * n) & 255;
        double ang = 6.283185307179586476925287 * (double)r / 256.0;
        float c = (float)cos(ang), s = (float)sin(ang);
        unsigned short h, l;
        split_bf16(c, h, l); C2h[idx] = h; C2l[idx] = l;
        split_bf16(s, h, l); S2h[idx] = h; S2l[idx] = l;
    }
}

// wp hi/lo: conv_w already [d=256][k=768], k = c*256+p*16+q
__global__ __launch_bounds__(256) void conv_wp(const float* __restrict__ w,
                                               unsigned short* __restrict__ wph, unsigned short* __restrict__ wpl) {
    int idx = blockIdx.x * 256 + threadIdx.x;
    unsigned short h, l;
    split_bf16(w[idx], h, l);
    wph[idx] = h; wpl[idx] = l;
}
__global__ __launch_bounds__(256) void conv_w1t(const float* __restrict__ w1, unsigned short* __restrict__ w1t) {
    int idx = blockIdx.x * 256 + threadIdx.x;
    int l = idx / 262144, rem = idx - l * 262144;
    int n = rem >> 8, k = rem & 255;
    w1t[idx] = rne_bf16(w1[(size_t)l * 262144 + (size_t)k * 1024 + n]);
}
__global__ __launch_bounds__(256) void conv_w2t(const float* __restrict__ w2, unsigned short* __restrict__ w2t) {
    int idx = blockIdx.x * 256 + threadIdx.x;
    int l = idx / 262144, rem = idx - l * 262144;
    int n = rem >> 10, k = rem & 1023;
    w2t[idx] = rne_bf16(w2[(size_t)l * 262144 + (size_t)k * 256 + n]);
}

// ---------------------------------------------------------------------------
__global__ __launch_bounds__(256) void cls_init(const float* __restrict__ cls, const float* __restrict__ pos,
                                                float* __restrict__ t) {
    int b = blockIdx.x, tid = threadIdx.x;
    t[(size_t)b * NTOK * DIM + tid] = cls[tid] + pos[tid];
}

// ---------------------------------------------------------------------------
// Fused patch embed: reads x directly, splits hi/lo in-register, 3-pass MFMA.
// M=65536 patches, N=256 dims, K=768. 128x128 tile, grid(512,2).
__global__ __launch_bounds__(256) void patch_fused(const float* __restrict__ x,
                                                   const unsigned short* __restrict__ wph,
                                                   const unsigned short* __restrict__ wpl,
                                                   const float* __restrict__ cb, const float* __restrict__ pos,
                                                   float* __restrict__ t) {
    __shared__ __align__(16) unsigned short sAh[8192], sAl[8192], sBh[8192], sBl[8192];
    int m0 = blockIdx.x * 128, n0 = blockIdx.y * 128;
    int tid = threadIdx.x, lane = tid & 63, w = tid >> 6;
    int wr = (w >> 1) * 64, wc = (w & 1) * 64;
    f32x4 z = {0.f, 0.f, 0.f, 0.f};
    f32x4 acc[4][4] = {{z, z, z, z}, {z, z, z, z}, {z, z, z, z}, {z, z, z, z}};
    for (int k0 = 0; k0 < 768; k0 += 64) {
#pragma unroll
        for (int s = 0; s < 8; s++) {
            int lin = s * 1024 + tid * 4;
            int row = lin >> 6, kc = lin & 63;
            int m = m0 + row;
            int bb = m >> 10, gh = (m >> 5) & 31, gw = m & 31;
            int k = k0 + kc;
            int c = k >> 8, pp = (k >> 4) & 15, q = k & 15;
            const float* gp = x + (size_t)bb * 786432 + c * 262144 + gh * 8192 + pp * 512 + gw * 16 + q;
            float4 v = *(const float4*)gp;
            ushort4 oh, ol;
            split_bf16(v.x, oh.x, ol.x); split_bf16(v.y, oh.y, ol.y);
            split_bf16(v.z, oh.z, ol.z); split_bf16(v.w, oh.w, ol.w);
            int g = kc >> 3, half = (kc >> 2) & 1;
            int addr = (row * 8 + (g ^ (row & 7))) * 8 + half * 4;
            *(ushort4*)(sAh + addr) = oh;
            *(ushort4*)(sAl + addr) = ol;
        }
        a_stage128(sBh, wph + (size_t)n0 * 768 + k0, 768, tid, 127);
        a_stage128(sBl, wpl + (size_t)n0 * 768 + k0, 768, tid, 127);
        __syncthreads();
#pragma unroll
        for (int kc2 = 0; kc2 < 2; kc2++) {
            int q = (lane >> 4) + kc2 * 4;
            short8 ah[4], al[4], bh8[4], bl8[4];
#pragma unroll
            for (int i = 0; i < 4; i++) {
                ah[i] = ld8x64(sAh, wr + i * 16 + (lane & 15), q);
                al[i] = ld8x64(sAl, wr + i * 16 + (lane & 15), q);
                bh8[i] = ld8x64(sBh, wc + i * 16 + (lane & 15), q);
                bl8[i] = ld8x64(sBl, wc + i * 16 + (lane & 15), q);
            }
#pragma unroll
            for (int i = 0; i < 4; i++)
#pragma unroll
                for (int j = 0; j < 4; j++) {
                    MFMA16(acc[i][j], ah[i], bh8[j]);
                    MFMA16(acc[i][j], ah[i], bl8[j]);
                    MFMA16(acc[i][j], al[i], bh8[j]);
                }
        }
        __syncthreads();
    }
    int q4 = (lane >> 4) * 4;
#pragma unroll
    for (int i = 0; i < 4; i++) {
        int r = m0 + wr + i * 16 + q4;
#pragma unroll
        for (int j = 0; j < 4; j++) {
            int c = n0 + wc + j * 16 + (lane & 15);
#pragma unroll
            for (int g = 0; g < 4; g++) {
                int rr = r + g;
                int bb = rr >> 10, tok = 1 + (rr & 1023);
                t[((size_t)bb * NTOK + tok) * 256 + c] =
                    acc[i][j][g] + cb[c] + pos[(size_t)tok * 256 + c];
            }
        }
    }
}

// ---------------------------------------------------------------------------
// Per-token LN stats: stats[m] = (mean, rstd). One wave per token.
__global__ __launch_bounds__(256) void ln_stats(const float* __restrict__ t, float2* __restrict__ stats) {
    int wave = threadIdx.x >> 6, lane = threadIdx.x & 63;
    int m = blockIdx.x * 4 + wave;   // < 65600 exact
    const float* row = t + (size_t)m * DIM;
    float4 v = *(const float4*)(row + lane * 4);
    float mean = wave_sum(v.x + v.y + v.z + v.w) * (1.f / 256.f);
    float dx = v.x - mean, dy = v.y - mean, dz = v.z - mean, dw = v.w - mean;
    float sq = wave_sum(dx * dx + dy * dy + dz * dz + dw * dw);
    float rstd = rsqrtf(sq * (1.f / 256.f) + LN_EPS);
    if (lane == 0) stats[m] = make_float2(mean, rstd);
}

// ---------------------------------------------------------------------------
__global__ __launch_bounds__(256) void ln2_bf16(const float* __restrict__ t, unsigned short* __restrict__ hh,
                                                const float* __restrict__ s, const float* __restrict__ bb) {
    int wave = threadIdx.x >> 6, lane = threadIdx.x & 63;
    int m = blockIdx.x * 4 + wave;
    const float* row = t + (size_t)m * DIM;
    float4 v = *(const float4*)(row + lane * 4);
    float mean = wave_sum(v.x + v.y + v.z + v.w) * (1.f / 256.f);
    float dx = v.x - mean, dy = v.y - mean, dz = v.z - mean, dw = v.w - mean;
    float sq = wave_sum(dx * dx + dy * dy + dz * dz + dw * dw);
    float rstd = rsqrtf(sq * (1.f / 256.f) + LN_EPS);
    float4 s4 = *(const float4*)(s + lane * 4);
    float4 b4 = *(const float4*)(bb + lane * 4);
    ushort4 o;
    o.x = rne_bf16(dx * rstd * s4.x + b4.x);
    o.y = rne_bf16(dy * rstd * s4.y + b4.y);
    o.z = rne_bf16(dz * rstd * s4.z + b4.z);
    o.w = rne_bf16(dw * rstd * s4.w + b4.w);
    *(ushort4*)(hh + (size_t)m * DIM + lane * 4) = o;
}

// ---------------------------------------------------------------------------
// Fused LN1 + token-fold + split-bf16 GEMM (3-pass).
// A built in-register from t (normalize via stats, fold +/- by z), B = C2/S2 rows [0..143].
// Output transposed+split O[b][c:144][kp:576] hi/lo. Tile 128x144, BK=32, grid(288, 2).
__global__ __launch_bounds__(256) void fold_gemm(
    const float* __restrict__ tt, const float2* __restrict__ stats,
    const float* __restrict__ ls, const float* __restrict__ lb,
    const unsigned short* __restrict__ C2h, const unsigned short* __restrict__ C2l,
    const unsigned short* __restrict__ S2h, const unsigned short* __restrict__ S2l,
    unsigned short* __restrict__ Ycth, unsigned short* __restrict__ Yctl,
    unsigned short* __restrict__ Ysth, unsigned short* __restrict__ Ystl) {
    __shared__ __align__(16) unsigned short sAh[4096], sAl[4096], sBh[4608], sBl[4608];
    int m0 = blockIdx.x * 128;
    int zz = blockIdx.y;
    const unsigned short* Bh = zz ? S2h : C2h;
    const unsigned short* Bl = zz ? S2l : C2l;
    unsigned short* Oh = zz ? Ysth : Ycth;
    unsigned short* Ol = zz ? Ystl : Yctl;
    int tid = threadIdx.x, lane = tid & 63, w = tid >> 6;
    int wr = w * 32;
    f32x4 zf = {0.f, 0.f, 0.f, 0.f};
    f32x4 acc[2][9];
#pragma unroll
    for (int i = 0; i < 2; i++)
#pragma unroll
        for (int j = 0; j < 9; j++) acc[i][j] = zf;
    for (int k0 = 0; k0 < 256; k0 += 32) {
        // A: 128 rows x 32 dims built from t with LN + fold, split hi/lo
#pragma unroll
        for (int s = 0; s < 4; s++) {
            int sl = tid + s * 256;            // 0..1023
            int row = sl >> 3, g = sl & 7;     // row 0..127, float4-granule 0..7
            int r = m0 + row;
            int b = r / KF, np = r - b * KF;
            float4 hv = {0.f, 0.f, 0.f, 0.f};
            if (np <= 512) {
                int d0 = k0 + g * 4;
                float4 s4 = *(const float4*)(ls + d0);
                float4 b4 = *(const float4*)(lb + d0);
                int i1 = b * NTOK + np;
                float2 st1 = stats[i1];
                float4 va = *(const float4*)(tt + (size_t)i1 * 256 + d0);
                float hax = (va.x - st1.x) * st1.y * s4.x + b4.x;
                float hay = (va.y - st1.x) * st1.y * s4.y + b4.y;
                float haz = (va.z - st1.x) * st1.y * s4.z + b4.z;
                float haw = (va.w - st1.x) * st1.y * s4.w + b4.w;
                float hbx = 0.f, hby = 0.f, hbz = 0.f, hbw = 0.f;
                if (np >= 1) {
                    int i2 = b * NTOK + (NTOK - np);
                    float2 st2 = stats[i2];
                    float4 vb = *(const float4*)(tt + (size_t)i2 * 256 + d0);
                    hbx = (vb.x - st2.x) * st2.y * s4.x + b4.x;
                    hby = (vb.y - st2.x) * st2.y * s4.y + b4.y;
                    hbz = (vb.z - st2.x) * st2.y * s4.z + b4.z;
                    hbw = (vb.w - st2.x) * st2.y * s4.w + b4.w;
                }
                if (zz) { hv.x = hax - hbx; hv.y = hay - hby; hv.z = haz - hbz; hv.w = haw - hbw; }
                else    { hv.x = hax + hbx; hv.y = hay + hby; hv.z = haz + hbz; hv.w = haw + hbw; }
            }
            ushort4 oh, ol;
            split_bf16(hv.x, oh.x, ol.x); split_bf16(hv.y, oh.y, ol.y);
            split_bf16(hv.z, oh.z, ol.z); split_bf16(hv.w, oh.w, ol.w);
            int addr = (row * 4 + ((g >> 1) ^ ((row >> 1) & 3))) * 8 + (g & 1) * 4;
            *(ushort4*)(sAh + addr) = oh;
            *(ushort4*)(sAl + addr) = ol;
        }
        a_stage144x32(sBh, Bh + k0, 256, tid);
        a_stage144x32(sBl, Bl + k0, 256, tid);
        __syncthreads();
        int q = lane >> 4;
        short8 ah[2], al[2];
#pragma unroll
        for (int i = 0; i < 2; i++) {
            int r = wr + i * 16 + (lane & 15);
            ah[i] = ld8x32(sAh, r, q); al[i] = ld8x32(sAl, r, q);
        }
#pragma unroll
        for (int j = 0; j < 9; j++) {
            int rb = j * 16 + (lane & 15);
            short8 bh = ld8x32(sBh, rb, q), bl = ld8x32(sBl, rb, q);
#pragma unroll
            for (int i = 0; i < 2; i++) {
                MFMA16(acc[i][j], ah[i], bh);
                MFMA16(acc[i][j], ah[i], bl);
                MFMA16(acc[i][j], al[i], bh);
            }
        }
        __syncthreads();
    }
    int q4 = (lane >> 4) * 4;
#pragma unroll
    for (int i = 0; i < 2; i++) {
        int r = m0 + wr + i * 16 + q4;
        int bidx = r / KF, kp = r - bidx * KF;
#pragma unroll
        for (int j = 0; j < 9; j++) {
            int c = j * 16 + (lane & 15);
            ushort4 oh, ol;
            split_bf16(acc[i][j][0], oh.x, ol.x);
            split_bf16(acc[i][j][1], oh.y, ol.y);
            split_bf16(acc[i][j][2], oh.z, ol.z);
            split_bf16(acc[i][j][3], oh.w, ol.w);
            size_t off = ((size_t)bidx * MF + c) * KF + kp;
            *(ushort4*)(Oh + off) = oh;
            *(ushort4*)(Ol + off) = ol;
        }
    }
}

// ---------------------------------------------------------------------------
// Dual split GEMM + butterfly. A: C1/S1 [640][576]; B: Yc/Ys flat [9216][576].
// 512 threads (8 waves), tile 128(k-rows) x 64(flat cols), BK=32, grid(5,144).
// LDS 48KB -> 3 blk/CU = 24 waves/CU. Wave (w>>1)->k-quad, (w&1)->col-quad.
__global__ __launch_bounds__(512, 6) void fft_big_dual(
    const unsigned short* __restrict__ C1h, const unsigned short* __restrict__ C1l,
    const unsigned short* __restrict__ S1h, const unsigned short* __restrict__ S1l,
    const unsigned short* __restrict__ Ych, const unsigned short* __restrict__ Ycl,
    const unsigned short* __restrict__ Ysh, const unsigned short* __restrict__ Ysl,
    float* __restrict__ t) {
    __shared__ __align__(16) unsigned short sC1h[4096], sC1l[4096], sS1h[4096], sS1l[4096];
    __shared__ __align__(16) unsigned short sYch[2048], sYcl[2048], sYsh[2048], sYsl[2048];
    int k0m = blockIdx.x * 128, n0 = blockIdx.y * 64;
    int tid = threadIdx.x, lane = tid & 63, w = tid >> 6;
    int wr = (w >> 1) * 32, wc = (w & 1) * 32;
    f32x4 z = {0.f, 0.f, 0.f, 0.f};
    f32x4 U[2][2], V[2][2];
#pragma unroll
    for (int i = 0; i < 2; i++)
#pragma unroll
        for (int j = 0; j < 2; j++) { U[i][j] = z; V[i][j] = z; }
    for (int kk0 = 0; kk0 < KF; kk0 += 32) {
        // A: 4 matrices 128x32, one slot per thread each
        {
            int row = tid >> 2, gc = (tid & 3) ^ ((row >> 1) & 3);
            size_t ga = (size_t)k0m * KF + kk0 + (size_t)row * KF + gc * 8;
            unsigned short* lbase0 = sC1h + (size_t)(w * 64) * 8;
            unsigned short* lbase1 = sC1l + (size_t)(w * 64) * 8;
            unsigned short* lbase2 = sS1h + (size_t)(w * 64) * 8;
            unsigned short* lbase3 = sS1l + (size_t)(w * 64) * 8;
            gl2lds16(C1h + ga, lbase0);
            gl2lds16(C1l + ga, lbase1);
            gl2lds16(S1h + ga, lbase2);
            gl2lds16(S1l + ga, lbase3);
        }
        // Y: matrix chosen by w>>1, half by w&1 (each 2 calls of 64 slots)
        {
            int m = w >> 1, p = w & 1;
            const unsigned short* yg;
            unsigned short* yl;
            if (m == 0)      { yg = Ych; yl = sYch; }
            else if (m == 1) { yg = Ycl; yl = sYcl; }
            else if (m == 2) { yg = Ysh; yl = sYsh; }
            else             { yg = Ysl; yl = sYsl; }
            size_t gb = (size_t)n0 * KF + kk0;
#pragma unroll
            for (int s = 0; s < 2; s++) {
                int slot = p * 128 + s * 64;
                int sl = slot + lane;
                int row = sl >> 2, gc = (sl & 3) ^ ((row >> 1) & 3);
                gl2lds16(yg + gb + (size_t)row * KF + gc * 8, yl + slot * 8);
            }
        }
        __syncthreads();
        int q = lane >> 4;
        short8 bch[2], bcl[2], bsh[2], bsl[2];
#pragma unroll
        for (int j = 0; j < 2; j++) {
            int r2 = wc + j * 16 + (lane & 15);
            bch[j] = ld8x32(sYch, r2, q); bcl[j] = ld8x32(sYcl, r2, q);
            bsh[j] = ld8x32(sYsh, r2, q); bsl[j] = ld8x32(sYsl, r2, q);
        }
#pragma unroll
        for (int i = 0; i < 2; i++) {
            int r1 = wr + i * 16 + (lane & 15);
            short8 ach = ld8x32(sC1h, r1, q), acl = ld8x32(sC1l, r1, q);
            short8 ash = ld8x32(sS1h, r1, q), asl = ld8x32(sS1l, r1, q);
#pragma unroll
            for (int j = 0; j < 2; j++) {
                MFMA16(U[i][j], ach, bch[j]);
                MFMA16(U[i][j], ach, bcl[j]);
                MFMA16(U[i][j], acl, bch[j]);
                MFMA16(V[i][j], ash, bsh[j]);
                MFMA16(V[i][j], ash, bsl[j]);
                MFMA16(V[i][j], asl, bsh[j]);
            }
        }
        __syncthreads();
    }
    int q4 = (lane >> 4) * 4;
#pragma unroll
    for (int j = 0; j < 2; j++) {
        int rcol = n0 + wc + j * 16 + (lane & 15);
        int b = rcol / MF, mm = rcol - b * MF;
        float* tb = t + (size_t)b * NTOK * DIM;
        if (mm > 128) continue;
#pragma unroll
        for (int i = 0; i < 2; i++) {
            int kk = k0m + wr + i * 16 + q4;
#pragma unroll
            for (int g = 0; g < 4; g++) {
                int k = kk + g;
                if (k > 512) continue;
                float u = U[i][j][g], v = V[i][j][g];
                tb[(size_t)k * 256 + mm] += u - v;
                if (mm >= 1 && mm <= 127) tb[(size_t)k * 256 + 256 - mm] += u + v;
                if (k >= 1) {
                    tb[(size_t)(NTOK - k) * 256 + mm] += u + v;
                    if (mm >= 1 && mm <= 127) tb[(size_t)(NTOK - k) * 256 + 256 - mm] += u - v;
                }
            }
        }
    }
}

// ---------------------------------------------------------------------------
// FFN1: Hid = leaky(h @ w1 + b1). 128x128 tile, grid(513,8).
__global__ __launch_bounds__(256) void gemm_ffn1(
    const unsigned short* __restrict__ A, const unsigned short* __restrict__ Bt,
    const float* __restrict__ b1, unsigned short* __restrict__ Hid) {
    __shared__ __align__(16) unsigned short sA[8192], sB[8192];
    int m0 = blockIdx.x * 128, n0 = blockIdx.y * 128;
    int tid = threadIdx.x, lane = tid & 63, w = tid >> 6;
    int wr = (w >> 1) * 64, wc = (w & 1) * 64;
    int maxrow = MROWS - 1 - m0; if (maxrow > 127) maxrow = 127;
    f32x4 z = {0.f, 0.f, 0.f, 0.f};
    f32x4 acc[4][4] = {{z, z, z, z}, {z, z, z, z}, {z, z, z, z}, {z, z, z, z}};
    for (int k0 = 0; k0 < 256; k0 += 64) {
        a_stage128(sA, A + (size_t)m0 * 256 + k0, 256, tid, maxrow);
        a_stage128(sB, Bt + (size_t)n0 * 256 + k0, 256, tid, 127);
        __syncthreads();
#pragma unroll
        for (int kc = 0; kc < 2; kc++) {
            int q = (lane >> 4) + kc * 4;
            short8 a8[4], b8[4];
#pragma unroll
            for (int i = 0; i < 4; i++) {
                a8[i] = ld8x64(sA, wr + i * 16 + (lane & 15), q);
                b8[i] = ld8x64(sB, wc + i * 16 + (lane & 15), q);
            }
#pragma unroll
            for (int i = 0; i < 4; i++)
#pragma unroll
                for (int j = 0; j < 4; j++) MFMA16(acc[i][j], a8[i], b8[j]);
        }
        __syncthreads();
    }
    int q4 = (lane >> 4) * 4;
#pragma unroll
    for (int i = 0; i < 4; i++) {
        int r = m0 + wr + i * 16 + q4;
#pragma unroll
        for (int j = 0; j < 4; j++) {
            int c = n0 + wc + j * 16 + (lane & 15);
            float bv = b1[c];
#pragma unroll
            for (int g = 0; g < 4; g++) {
                int rr = r + g;
                if (rr < MROWS) {
                    float val = acc[i][j][g] + bv;
                    val = val > 0.f ? val : 0.01f * val;
                    Hid[(size_t)rr * 1024 + c] = rne_bf16(val);
                }
            }
        }
    }
}

// ---------------------------------------------------------------------------
// FFN2: t += Hid @ w2 + b2. 128x128 tile, grid(513,2).
__global__ __launch_bounds__(256) void gemm_ffn2(
    const unsigned short* __restrict__ A, const unsigned short* __restrict__ Bt,
    const float* __restrict__ b2, float* __restrict__ t) {
    __shared__ __align__(16) unsigned short sA[8192], sB[8192];
    int m0 = blockIdx.x * 128, n0 = blockIdx.y * 128;
    int tid = threadIdx.x, lane = tid & 63, w = tid >> 6;
    int wr = (w >> 1) * 64, wc = (w & 1) * 64;
    int maxrow = MROWS - 1 - m0; if (maxrow > 127) maxrow = 127;
    f32x4 z = {0.f, 0.f, 0.f, 0.f};
    f32x4 acc[4][4] = {{z, z, z, z}, {z, z, z, z}, {z, z, z, z}, {z, z, z, z}};
    for (int k0 = 0; k0 < 1024; k0 += 64) {
        a_stage128(sA, A + (size_t)m0 * 1024 + k0, 1024, tid, maxrow);
        a_stage128(sB, Bt + (size_t)n0 * 1024 + k0, 1024, tid, 127);
        __syncthreads();
#pragma unroll
        for (int kc = 0; kc < 2; kc++) {
            int q = (lane >> 4) + kc * 4;
            short8 a8[4], b8[4];
#pragma unroll
            for (int i = 0; i < 4; i++) {
                a8[i] = ld8x64(sA, wr + i * 16 + (lane & 15), q);
                b8[i] = ld8x64(sB, wc + i * 16 + (lane & 15), q);
            }
#pragma unroll
            for (int i = 0; i < 4; i++)
#pragma unroll
                for (int j = 0; j < 4; j++) MFMA16(acc[i][j], a8[i], b8[j]);
        }
        __syncthreads();
    }
    int q4 = (lane >> 4) * 4;
#pragma unroll
    for (int i = 0; i < 4; i++) {
        int r = m0 + wr + i * 16 + q4;
#pragma unroll
        for (int j = 0; j < 4; j++) {
            int c = n0 + wc + j * 16 + (lane & 15);
            float bv = b2[c];
#pragma unroll
            for (int g = 0; g < 4; g++) {
                int rr = r + g;
                if (rr < MROWS) t[(size_t)rr * 256 + c] += acc[i][j][g] + bv;
            }
        }
    }
}

// ---------------------------------------------------------------------------
__global__ __launch_bounds__(256) void head_kernel(const float* __restrict__ t,
                                                   const float* __restrict__ hs, const float* __restrict__ hb,
                                                   const float* __restrict__ hw, const float* __restrict__ hbias,
                                                   float* __restrict__ out) {
    __shared__ float red[256];
    __shared__ float lnv[256];
    int b = blockIdx.x, tid = threadIdx.x;
    const float* tb = t + (size_t)b * NTOK * DIM;
    float s = 0.f;
    for (int m = 0; m < NTOK; m++) s += tb[m * DIM + tid];
    s *= (1.f / 1025.f);
    red[tid] = s;
    __syncthreads();
    for (int off = 128; off; off >>= 1) {
        if (tid < off) red[tid] += red[tid + off];
        __syncthreads();
    }
    float mean = red[0] * (1.f / 256.f);
    __syncthreads();
    float d = s - mean;
    red[tid] = d * d;
    __syncthreads();
    for (int off = 128; off; off >>= 1) {
        if (tid < off) red[tid] += red[tid + off];
        __syncthreads();
    }
    float rstd = rsqrtf(red[0] * (1.f / 256.f) + LN_EPS);
    __syncthreads();
    lnv[tid] = d * rstd * hs[tid] + hb[tid];
    __syncthreads();
    float lo[4];
#pragma unroll
    for (int jj = 0; jj < 4; jj++) {
        int n = tid + jj * 256;
        float a = -1e30f;
        if (n < NCLS) {
            a = hbias[n];
            for (int dd = 0; dd < DIM; dd++) a += lnv[dd] * hw[dd * NCLS + n];
        }
        lo[jj] = a;
    }
    float mx = fmaxf(fmaxf(lo[0], lo[1]), fmaxf(lo[2], lo[3]));
    red[tid] = mx;
    __syncthreads();
    for (int off = 128; off; off >>= 1) {
        if (tid < off) red[tid] = fmaxf(red[tid], red[tid + off]);
        __syncthreads();
    }
    float gmax = red[0];
    __syncthreads();
    float ev[4];
    float es = 0.f;
#pragma unroll
    for (int jj = 0; jj < 4; jj++) {
        int n = tid + jj * 256;
        ev[jj] = 0.f;
        if (n < NCLS) {
            ev[jj] = expf(lo[jj] - gmax);
            es += ev[jj];
        }
    }
    red[tid] = es;
    __syncthreads();
    for (int off = 128; off; off >>= 1) {
        if (tid < off) red[tid] += red[tid + off];
        __syncthreads();
    }
    float inv = 1.f / red[0];
#pragma unroll
    for (int jj = 0; jj < 4; jj++) {
        int n = tid + jj * 256;
        if (n < NCLS) out[(size_t)b * NCLS + n] = ev[jj] * inv;
    }
}

// ---------------------------------------------------------------------------
extern "C" void kernel_launch(void* const* d_in, const int* in_sizes, int n_in,
                              void* d_out, int out_size, void* d_ws, size_t ws_size,
                              hipStream_t stream) {
    const float* x      = (const float*)d_in[0];
    const float* conv_w = (const float*)d_in[1];
    const float* conv_b = (const float*)d_in[2];
    const float* pos    = (const float*)d_in[3];
    const float* cls    = (const float*)d_in[4];
    const float* ln1_s  = (const float*)d_in[5];
    const float* ln1_b  = (const float*)d_in[6];
    const float* ln2_s  = (const float*)d_in[7];
    const float* ln2_b  = (const float*)d_in[8];
    const float* w1     = (const float*)d_in[9];
    const float* b1     = (const float*)d_in[10];
    const float* w2     = (const float*)d_in[11];
    const float* b2     = (const float*)d_in[12];
    const float* hls    = (const float*)d_in[13];
    const float* hlb    = (const float*)d_in[14];
    const float* hw     = (const float*)d_in[15];
    const float* hbias  = (const float*)d_in[16];
    float* out = (float*)d_out;
    char* W = (char*)d_ws;

    // layout (bytes), pool time-multiplexed:
    //   t:    [0, 67,174,400)
    //   pool @ 67,174,400 (167,936,000):
    //     Yct @ +75,497,472 (4 x 10,616,832)      — phase A  (ends +117,964,800)
    //     Hid @ +0 (134,348,800)                  — phase B
    //     hh  @ +134,348,800 (33,587,200)
    //   C1 grp @ 235,110,400 (4 x 737,280 = 640x576x2)
    //   C2 grp @ 238,059,520 (4 x 131,072)
    //   w1t @ 238,583,808 | w2t @ 241,729,536 | wph @ 244,875,264 | wpl @ 245,268,480
    //   stats @ 245,661,696 (65600 x 8B = 524,800)
    float*          t    = (float*)(W + 0ULL);
    char*           pool = W + 67174400ULL;
    unsigned short* Ycth = (unsigned short*)(pool + 75497472ULL);
    unsigned short* Yctl = (unsigned short*)(pool + 75497472ULL + 10616832ULL);
    unsigned short* Ysth = (unsigned short*)(pool + 75497472ULL + 2 * 10616832ULL);
    unsigned short* Ystl = (unsigned short*)(pool + 75497472ULL + 3 * 10616832ULL);
    unsigned short* Hid  = (unsigned short*)(pool);
    unsigned short* hh   = (unsigned short*)(pool + 134348800ULL);
    unsigned short* C1h  = (unsigned short*)(W + 235110400ULL);
    unsigned short* C1l  = (unsigned short*)(W + 235110400ULL + 737280ULL);
    unsigned short* S1h  = (unsigned short*)(W + 235110400ULL + 2 * 737280ULL);
    unsigned short* S1l  = (unsigned short*)(W + 235110400ULL + 3 * 737280ULL);
    unsigned short* C2h  = (unsigned short*)(W + 238059520ULL);
    unsigned short* C2l  = (unsigned short*)(W + 238059520ULL + 131072ULL);
    unsigned short* S2h  = (unsigned short*)(W + 238059520ULL + 2 * 131072ULL);
    unsigned short* S2l  = (unsigned short*)(W + 238059520ULL + 3 * 131072ULL);
    unsigned short* w1t  = (unsigned short*)(W + 238583808ULL);
    unsigned short* w2t  = (unsigned short*)(W + 241729536ULL);
    unsigned short* wph  = (unsigned short*)(W + 244875264ULL);
    unsigned short* wpl  = (unsigned short*)(W + 245268480ULL);
    float2*         stats = (float2*)(W + 245661696ULL);

    gen_dft2<<<dim3(1440), dim3(256), 0, stream>>>(C1h, C1l, S1h, S1l, C2h, C2l, S2h, S2l);
    conv_wp<<<dim3(768), dim3(256), 0, stream>>>(conv_w, wph, wpl);
    conv_w1t<<<dim3(6144), dim3(256), 0, stream>>>(w1, w1t);
    conv_w2t<<<dim3(6144), dim3(256), 0, stream>>>(w2, w2t);
    cls_init<<<dim3(BATCH), dim3(256), 0, stream>>>(cls, pos, t);
    patch_fused<<<dim3(512, 2), dim3(256), 0, stream>>>(x, wph, wpl, conv_b, pos, t);

    for (int l = 0; l < NLAYER; l++) {
        ln_stats<<<dim3(16400), dim3(256), 0, stream>>>(t, stats);
        fold_gemm<<<dim3(288, 2), dim3(256), 0, stream>>>(
            t, stats, ln1_s + l * DIM, ln1_b + l * DIM,
            C2h, C2l, S2h, S2l, Ycth, Yctl, Ysth, Ystl);
        fft_big_dual<<<dim3(5, 144), dim3(512), 0, stream>>>(
            C1h, C1l, S1h, S1l, Ycth, Yctl, Ysth, Ystl, t);
        ln2_bf16<<<dim3(16400), dim3(256), 0, stream>>>(t, hh, ln2_s + l * DIM, ln2_b + l * DIM);
        gemm_ffn1<<<dim3(513, 8), dim3(256), 0, stream>>>(
            hh, w1t + (size_t)l * 262144, b1 + (size_t)l * HID, Hid);
        gemm_ffn2<<<dim3(513, 2), dim3(256), 0, stream>>>(
            Hid, w2t + (size_t)l * 262144, b2 + (size_t)l * DIM, t);
    }
    head_kernel<<<dim3(BATCH), dim3(256), 0, stream>>>(t, hls, hlb, hw, hbias, out);
}